// Round 1
// baseline (3797.366 us; speedup 1.0000x reference)
//
#include <hip/hip_runtime.h>
#include <cstdint>

#define HB 128   // hidden size
#define NB 64    // graphs per batch
#define NE 1048576

// ---- init edge arrays ----
__global__ __launch_bounds__(256) void init_edges_k(const int* __restrict__ ei,
    int* __restrict__ row, int* __restrict__ col, float* __restrict__ m, int E) {
  int e = blockIdx.x * blockDim.x + threadIdx.x;
  if (e < E) { row[e] = ei[e]; col[e] = ei[E + e]; m[e] = 1.f; }
}

// ---- generic tiled matmul: out[N][128] = X[N][K] @ W[K][128] (+bias,relu) ----
// flags bit0: add bias, bit1: relu
__global__ __launch_bounds__(256) void matmul_k(const float* __restrict__ X,
    const float* __restrict__ W, const float* __restrict__ bias,
    float* __restrict__ out, int N, int K, int flags) {
  extern __shared__ float lw[];  // K*128 floats
  int tid = threadIdx.x;
  int nv = K * 32;  // float4 count
  for (int idx = tid; idx < nv; idx += 256)
    ((float4*)lw)[idx] = ((const float4*)W)[idx];
  __syncthreads();
  int tx = tid & 31, ty = tid >> 5;   // tx: 4-col group, ty: row lane (rows ty+8*rr)
  long rowbase = (long)blockIdx.x * 32;
  float acc[4][4] = {};
  const float* xp = X + (size_t)(rowbase + ty) * K;
  for (int k = 0; k < K; ++k) {
    float4 wv = ((float4*)lw)[k * 32 + tx];
    #pragma unroll
    for (int rr = 0; rr < 4; ++rr) {
      float xv = xp[(size_t)rr * 8 * K + k];
      acc[rr][0] += xv * wv.x; acc[rr][1] += xv * wv.y;
      acc[rr][2] += xv * wv.z; acc[rr][3] += xv * wv.w;
    }
  }
  float4 bv = make_float4(0.f, 0.f, 0.f, 0.f);
  if (flags & 1) bv = ((const float4*)bias)[tx];
  #pragma unroll
  for (int rr = 0; rr < 4; ++rr) {
    long r = rowbase + ty + rr * 8;
    float4 v;
    v.x = acc[rr][0] + bv.x; v.y = acc[rr][1] + bv.y;
    v.z = acc[rr][2] + bv.z; v.w = acc[rr][3] + bv.w;
    if (flags & 2) {
      v.x = fmaxf(v.x, 0.f); v.y = fmaxf(v.y, 0.f);
      v.z = fmaxf(v.z, 0.f); v.w = fmaxf(v.w, 0.f);
    }
    ((float4*)(out + (size_t)r * HB))[tx] = v;
  }
}

// ---- degree (masked in-edges per node) ----
__global__ __launch_bounds__(256) void deg_k(const int* __restrict__ col,
    const float* __restrict__ m, float* __restrict__ deg, int E) {
  int e = blockIdx.x * blockDim.x + threadIdx.x;
  if (e < E && m[e] != 0.f) atomicAdd(&deg[col[e]], 1.f);
}

__global__ __launch_bounds__(256) void dis_k(const float* __restrict__ deg,
    float* __restrict__ dis, int N) {
  int i = blockIdx.x * blockDim.x + threadIdx.x;
  if (i < N) dis[i] = rsqrtf(deg[i] + 1.f);
}

// ---- edge aggregation: agg[col] += hw[row] * dis[row]*dis[col] ----
// 32 threads per edge, float4 channels
__global__ __launch_bounds__(256) void agg_k(const float* __restrict__ hw,
    const int* __restrict__ row, const int* __restrict__ col,
    const float* __restrict__ m, const float* __restrict__ dis,
    float* __restrict__ agg, int E) {
  int gid = blockIdx.x * blockDim.x + threadIdx.x;
  int e = gid >> 5;
  if (e >= E) return;
  float mv = m[e];
  if (mv == 0.f) return;
  int r = row[e], c = col[e];
  float coef = dis[r] * dis[c];
  int ch = (gid & 31) * 4;
  float4 v = *(const float4*)(hw + (size_t)r * HB + ch);
  float* dst = agg + (size_t)c * HB + ch;
  atomicAdd(dst + 0, v.x * coef);
  atomicAdd(dst + 1, v.y * coef);
  atomicAdd(dst + 2, v.z * coef);
  atomicAdd(dst + 3, v.w * coef);
}

// ---- conv combine: agg += hw * dis^2 + bc ----
__global__ __launch_bounds__(256) void combine_k(float* __restrict__ agg,
    const float* __restrict__ hw, const float* __restrict__ dis,
    const float* __restrict__ bc, int N) {
  int gid = blockIdx.x * blockDim.x + threadIdx.x;
  int i = gid >> 5;
  if (i >= N) return;
  int ch = (gid & 31) * 4;
  float d2 = dis[i] * dis[i];
  float4 a = *(float4*)(agg + (size_t)i * HB + ch);
  float4 h = *(const float4*)(hw + (size_t)i * HB + ch);
  float4 b = *(const float4*)(bc + ch);
  a.x += h.x * d2 + b.x; a.y += h.y * d2 + b.y;
  a.z += h.z * d2 + b.z; a.w += h.w * d2 + b.w;
  *(float4*)(agg + (size_t)i * HB + ch) = a;
}

// ---- BN stats: per-channel sum & sumsq ----
__global__ __launch_bounds__(256) void bnstat_k(const float* __restrict__ h,
    float* __restrict__ stat, int N) {
  __shared__ float ls[256], lq[256];
  int tid = threadIdx.x, c = tid & 127;
  float s = 0.f, q = 0.f;
  for (long r = (long)blockIdx.x * 2 + (tid >> 7); r < N; r += (long)gridDim.x * 2) {
    float v = h[r * HB + c];
    s += v; q += v * v;
  }
  ls[tid] = s; lq[tid] = q;
  __syncthreads();
  if (tid < 128) {
    s = ls[tid] + ls[tid + 128];
    q = lq[tid] + lq[tid + 128];
    atomicAdd(&stat[c], s);
    atomicAdd(&stat[128 + c], q);
  }
}

__global__ __launch_bounds__(128) void bnfin_k(const float* __restrict__ stat,
    const float* __restrict__ g, const float* __restrict__ b,
    float* __restrict__ sc, int N) {
  int c = threadIdx.x;
  if (c < 128) {
    float mu = stat[c] / N, ms = stat[128 + c] / N;
    float var = ms - mu * mu;
    float a = g[c] * rsqrtf(var + 1e-5f);
    sc[c] = a;
    sc[128 + c] = b[c] - mu * a;
  }
}

// ---- BN apply (in place) + per-node dots with Ws1/Ws2 (one wave per node) ----
__global__ __launch_bounds__(256) void bnapply_score_k(float* __restrict__ h,
    const float* __restrict__ sc, const float* __restrict__ w1,
    const float* __restrict__ w2, float* __restrict__ selfs,
    float* __restrict__ t2, int N) {
  int gid = blockIdx.x * blockDim.x + threadIdx.x;
  int node = gid >> 6;
  if (node >= N) return;
  int lane = gid & 63, c = lane * 2;
  float2 v = *(float2*)(h + (size_t)node * HB + c);
  v.x = v.x * sc[c] + sc[128 + c];
  v.y = v.y * sc[c + 1] + sc[128 + c + 1];
  *(float2*)(h + (size_t)node * HB + c) = v;
  float s1 = v.x * w1[c] + v.y * w1[c + 1];
  float s2 = v.x * w2[c] + v.y * w2[c + 1];
  #pragma unroll
  for (int off = 32; off > 0; off >>= 1) {
    s1 += __shfl_xor(s1, off);
    s2 += __shfl_xor(s2, off);
  }
  if (lane == 0) { selfs[node] = s1; t2[node] = s2; }
}

// ---- scalar edge aggregation for SAG score ----
__global__ __launch_bounds__(256) void sagg_k(const int* __restrict__ row,
    const int* __restrict__ col, const float* __restrict__ m,
    const float* __restrict__ t2, float* __restrict__ sagg, int E) {
  int e = blockIdx.x * blockDim.x + threadIdx.x;
  if (e < E && m[e] != 0.f) atomicAdd(&sagg[col[e]], t2[row[e]]);
}

__global__ __launch_bounds__(256) void scorefin_k(const float* __restrict__ selfs,
    const float* __restrict__ sagg, const float* __restrict__ bs,
    float* __restrict__ score, int N) {
  int i = blockIdx.x * blockDim.x + threadIdx.x;
  if (i < N) score[i] = selfs[i] + sagg[i] + bs[0];
}

// ---- per-graph top-k (bitonic, desc score / asc index ties) + gather + inv ----
__global__ __launch_bounds__(256) void topk_gather_k(const float* __restrict__ score,
    const float* __restrict__ h, float* __restrict__ xout, int* __restrict__ inv,
    int n, int k) {
  __shared__ float ss[2048];
  __shared__ int si[2048];
  int g = blockIdx.x, tid = threadIdx.x;
  for (int i = tid; i < n; i += blockDim.x) { ss[i] = score[g * n + i]; si[i] = i; }
  __syncthreads();
  for (int ksz = 2; ksz <= n; ksz <<= 1) {
    for (int j = ksz >> 1; j > 0; j >>= 1) {
      for (int i = tid; i < n; i += blockDim.x) {
        int ixj = i ^ j;
        if (ixj > i) {
          float a = ss[i], b = ss[ixj];
          int ia = si[i], ib = si[ixj];
          // element at i should come after element at ixj in (desc score, asc idx)?
          bool after_i = (a < b) || (a == b && ia > ib);
          bool up = ((i & ksz) == 0);
          if (after_i == up) { ss[i] = b; ss[ixj] = a; si[i] = ib; si[ixj] = ia; }
        }
      }
      __syncthreads();
    }
  }
  for (int jj = tid; jj < n; jj += blockDim.x)
    inv[g * n + si[jj]] = (jj < k) ? (g * k + jj) : -1;
  for (int idx = tid; idx < k * HB; idx += blockDim.x) {
    int j = idx >> 7, c = idx & 127;
    int old = g * n + si[j];
    xout[((size_t)g * k + j) * HB + c] = h[(size_t)old * HB + c] * tanhf(ss[j]);
  }
}

// ---- edge re-index + mask ----
__global__ __launch_bounds__(256) void edge_update_k(int* __restrict__ row,
    int* __restrict__ col, float* __restrict__ m, const int* __restrict__ inv, int E) {
  int e = blockIdx.x * blockDim.x + threadIdx.x;
  if (e >= E) return;
  float mv = m[e];
  int r = row[e], c = col[e];
  int nr = inv[r], nc = inv[c];
  bool valid = (mv != 0.f) && (nr >= 0) && (nc >= 0);
  row[e] = valid ? nr : 0;
  col[e] = valid ? nc : 0;
  m[e] = valid ? 1.f : 0.f;
}

// ---- final mean pool ----
__global__ __launch_bounds__(128) void pool_k(const float* __restrict__ x,
    float* __restrict__ out, int n) {
  int g = blockIdx.x, c = threadIdx.x;
  float s = 0.f;
  for (int r = 0; r < n; ++r) s += x[((size_t)g * n + r) * HB + c];
  out[g * HB + c] = s / n;
}

extern "C" void kernel_launch(void* const* d_in, const int* in_sizes, int n_in,
                              void* d_out, int out_size, void* d_ws, size_t ws_size,
                              hipStream_t stream) {
  const float* x_in = (const float*)d_in[0];
  const int*   ei   = (const int*)d_in[1];
  const float* Wc1  = (const float*)d_in[3];
  const float* Wc   = (const float*)d_in[4];
  const float* bc   = (const float*)d_in[5];
  const float* Wf   = (const float*)d_in[6];
  const float* bf   = (const float*)d_in[7];
  const float* bng  = (const float*)d_in[8];
  const float* bnb  = (const float*)d_in[9];
  const float* Ws1  = (const float*)d_in[10];
  const float* Ws2  = (const float*)d_in[11];
  const float* bs   = (const float*)d_in[12];

  const int N0 = 131072, E = NE;
  char* p = (char*)d_ws;
  auto alloc = [&](size_t bytes) -> char* {
    char* r = p; p += (bytes + 255) & ~(size_t)255; return r;
  };
  float* A    = (float*)alloc((size_t)N0 * HB * 4);      // 64 MB: hw, then fc/bn output
  float* Bb   = (float*)alloc((size_t)N0 * HB * 4);      // 64 MB: agg / conv result
  float* Cc   = (float*)alloc((size_t)(N0 / 2) * HB * 4);// 32 MB: pooled x
  int*   row  = (int*)alloc((size_t)E * 4);
  int*   colv = (int*)alloc((size_t)E * 4);
  float* m    = (float*)alloc((size_t)E * 4);
  float* deg  = (float*)alloc((size_t)N0 * 4);
  float* dis  = (float*)alloc((size_t)N0 * 4);
  float* selfs= (float*)alloc((size_t)N0 * 4);
  float* t2v  = (float*)alloc((size_t)N0 * 4);
  float* sagg = (float*)alloc((size_t)N0 * 4);
  float* score= (float*)alloc((size_t)N0 * 4);
  int*   inv  = (int*)alloc((size_t)N0 * 4);
  float* stat = (float*)alloc(256 * 4);
  float* bnsc = (float*)alloc(256 * 4);

  init_edges_k<<<E / 256, 256, 0, stream>>>(ei, row, colv, m, E);

  int n = 2048, K = 7;
  const float* xcur = x_in;
  for (int i = 0; i < 4; ++i) {
    int N = NB * n, khalf = n >> 1;
    const float* W = (i == 0) ? Wc1 : (Wc + (size_t)(i - 1) * HB * HB);
    // hw = x @ W
    matmul_k<<<N / 32, 256, (size_t)K * HB * 4, stream>>>(xcur, W, nullptr, A, N, K, 0);
    // degrees / norms
    hipMemsetAsync(deg, 0, (size_t)N * 4, stream);
    deg_k<<<E / 256, 256, 0, stream>>>(colv, m, deg, E);
    dis_k<<<(N + 255) / 256, 256, 0, stream>>>(deg, dis, N);
    // edge aggregation
    hipMemsetAsync(Bb, 0, (size_t)N * HB * 4, stream);
    agg_k<<<E / 8, 256, 0, stream>>>(A, row, colv, m, dis, Bb, E);
    combine_k<<<N / 8, 256, 0, stream>>>(Bb, A, dis, bc + (size_t)i * HB, N);
    // fc + relu
    matmul_k<<<N / 32, 256, (size_t)HB * HB * 4, stream>>>(
        Bb, Wf + (size_t)i * HB * HB, bf + (size_t)i * HB, A, N, HB, 3);
    // batchnorm
    hipMemsetAsync(stat, 0, 256 * 4, stream);
    bnstat_k<<<512, 256, 0, stream>>>(A, stat, N);
    bnfin_k<<<1, 128, 0, stream>>>(stat, bng + (size_t)i * HB, bnb + (size_t)i * HB, bnsc, N);
    bnapply_score_k<<<N / 4, 256, 0, stream>>>(
        A, bnsc, Ws1 + (size_t)i * HB, Ws2 + (size_t)i * HB, selfs, t2v, N);
    // SAG score edge aggregation (scalar per edge)
    hipMemsetAsync(sagg, 0, (size_t)N * 4, stream);
    sagg_k<<<E / 256, 256, 0, stream>>>(row, colv, m, t2v, sagg, E);
    scorefin_k<<<(N + 255) / 256, 256, 0, stream>>>(selfs, sagg, bs + i, score, N);
    // top-k + gather + inverse index
    topk_gather_k<<<NB, 256, 0, stream>>>(score, A, Cc, inv, n, khalf);
    if (i < 3) edge_update_k<<<E / 256, 256, 0, stream>>>(row, colv, m, inv, E);
    xcur = Cc; K = HB; n = khalf;
  }
  pool_k<<<NB, 128, 0, stream>>>(Cc, (float*)d_out, n);
}

// Round 2
// 1668.860 us; speedup vs baseline: 2.2754x; 2.2754x over previous
//
#include <hip/hip_runtime.h>
#include <cstdint>

#define HB 128   // hidden size
#define NB 64    // graphs per batch
#define NE 1048576

// ---- init edge arrays ----
__global__ __launch_bounds__(256) void init_edges_k(const int* __restrict__ ei,
    int* __restrict__ row, int* __restrict__ col, int E) {
  int e = blockIdx.x * blockDim.x + threadIdx.x;
  if (e < E) { row[e] = ei[e]; col[e] = ei[E + e]; }
}

__global__ void set_int_k(int* p, int v) { *p = v; }

// ---- generic tiled matmul: out[N][128] = X[N][K] @ W[K][128] (+bias,relu) ----
// flags bit0: add bias, bit1: relu
__global__ __launch_bounds__(256) void matmul_k(const float* __restrict__ X,
    const float* __restrict__ W, const float* __restrict__ bias,
    float* __restrict__ out, int N, int K, int flags) {
  extern __shared__ float lw[];  // K*128 floats
  int tid = threadIdx.x;
  int nv = K * 32;  // float4 count
  for (int idx = tid; idx < nv; idx += 256)
    ((float4*)lw)[idx] = ((const float4*)W)[idx];
  __syncthreads();
  int tx = tid & 31, ty = tid >> 5;
  long rowbase = (long)blockIdx.x * 32;
  float acc[4][4] = {};
  const float* xp = X + (size_t)(rowbase + ty) * K;
  for (int k = 0; k < K; ++k) {
    float4 wv = ((float4*)lw)[k * 32 + tx];
    #pragma unroll
    for (int rr = 0; rr < 4; ++rr) {
      float xv = xp[(size_t)rr * 8 * K + k];
      acc[rr][0] += xv * wv.x; acc[rr][1] += xv * wv.y;
      acc[rr][2] += xv * wv.z; acc[rr][3] += xv * wv.w;
    }
  }
  float4 bv = make_float4(0.f, 0.f, 0.f, 0.f);
  if (flags & 1) bv = ((const float4*)bias)[tx];
  #pragma unroll
  for (int rr = 0; rr < 4; ++rr) {
    long r = rowbase + ty + rr * 8;
    float4 v;
    v.x = acc[rr][0] + bv.x; v.y = acc[rr][1] + bv.y;
    v.z = acc[rr][2] + bv.z; v.w = acc[rr][3] + bv.w;
    if (flags & 2) {
      v.x = fmaxf(v.x, 0.f); v.y = fmaxf(v.y, 0.f);
      v.z = fmaxf(v.z, 0.f); v.w = fmaxf(v.w, 0.f);
    }
    ((float4*)(out + (size_t)r * HB))[tx] = v;
  }
}

// ---- int degree histogram over compacted edges ----
__global__ __launch_bounds__(256) void hist_k(const int* __restrict__ col,
    const int* __restrict__ ecnt, int* __restrict__ degi) {
  int e = blockIdx.x * blockDim.x + threadIdx.x;
  if (e < *ecnt) atomicAdd(&degi[col[e]], 1);
}

__global__ __launch_bounds__(256) void dis_k(const int* __restrict__ degi,
    float* __restrict__ dis, int N) {
  int i = blockIdx.x * blockDim.x + threadIdx.x;
  if (i < N) dis[i] = rsqrtf((float)degi[i] + 1.f);
}

// ---- hierarchical exclusive scan: A (per-256 chunk), B (chunk sums), C (add base) ----
__global__ __launch_bounds__(256) void scanA_k(const int* __restrict__ degi,
    int* __restrict__ off, int* __restrict__ bsum) {
  __shared__ int s[256];
  int tid = threadIdx.x;
  int i = blockIdx.x * 256 + tid;
  int v = degi[i];
  s[tid] = v; __syncthreads();
  for (int o = 1; o < 256; o <<= 1) {
    int t = (tid >= o) ? s[tid - o] : 0;
    __syncthreads();
    s[tid] += t;
    __syncthreads();
  }
  off[i] = s[tid] - v;
  if (tid == 255) bsum[blockIdx.x] = s[255];
}

__global__ __launch_bounds__(512) void scanB_k(const int* __restrict__ bsum,
    int* __restrict__ bsumo, int nb) {
  __shared__ int s[512];
  int tid = threadIdx.x;
  int v = (tid < nb) ? bsum[tid] : 0;
  s[tid] = v; __syncthreads();
  for (int o = 1; o < 512; o <<= 1) {
    int t = (tid >= o) ? s[tid - o] : 0;
    __syncthreads();
    s[tid] += t;
    __syncthreads();
  }
  if (tid < nb) bsumo[tid] = s[tid] - v;
}

__global__ __launch_bounds__(256) void scanC_k(int* __restrict__ off,
    int* __restrict__ cursor, const int* __restrict__ bsumo,
    const int* __restrict__ ecnt, int N) {
  int i = blockIdx.x * 256 + threadIdx.x;
  if (i >= N) return;
  int v = off[i] + bsumo[i >> 8];
  off[i] = v; cursor[i] = v;
  if (i == N - 1) off[N] = *ecnt;
}

// ---- scatter edges into CSR (payload: row index + norm coefficient) ----
__global__ __launch_bounds__(256) void scatter_k(const int* __restrict__ row,
    const int* __restrict__ col, const int* __restrict__ ecnt,
    const float* __restrict__ dis, int* __restrict__ cursor,
    int* __restrict__ srow, float* __restrict__ snorm) {
  int e = blockIdx.x * blockDim.x + threadIdx.x;
  if (e >= *ecnt) return;
  int r = row[e], c = col[e];
  int p = atomicAdd(&cursor[c], 1);
  srow[p] = r;
  snorm[p] = dis[r] * dis[c];
}

// ---- CSR gather + self loop + bias: out_i = sum_e hw[srow]*snorm + hw_i*dis_i^2 + bc ----
__global__ __launch_bounds__(256) void gather_combine_k(const float* __restrict__ hw,
    const int* __restrict__ srow, const float* __restrict__ snorm,
    const int* __restrict__ off, const float* __restrict__ dis,
    const float* __restrict__ bc, float* __restrict__ out, int N) {
  int gid = blockIdx.x * blockDim.x + threadIdx.x;
  int node = gid >> 5;
  if (node >= N) return;
  int ch = (gid & 31) * 4;
  int s = off[node], e = off[node + 1];
  float4 acc = make_float4(0.f, 0.f, 0.f, 0.f);
  for (int j = s; j < e; ++j) {
    int r = srow[j];
    float nm = snorm[j];
    float4 v = *(const float4*)(hw + (size_t)r * HB + ch);
    acc.x += v.x * nm; acc.y += v.y * nm; acc.z += v.z * nm; acc.w += v.w * nm;
  }
  float d = dis[node], d2 = d * d;
  float4 h = *(const float4*)(hw + (size_t)node * HB + ch);
  float4 b = *(const float4*)(bc + ch);
  acc.x += h.x * d2 + b.x; acc.y += h.y * d2 + b.y;
  acc.z += h.z * d2 + b.z; acc.w += h.w * d2 + b.w;
  *(float4*)(out + (size_t)node * HB + ch) = acc;
}

// ---- BN stats: per-channel sum & sumsq ----
__global__ __launch_bounds__(256) void bnstat_k(const float* __restrict__ h,
    float* __restrict__ stat, int N) {
  __shared__ float ls[256], lq[256];
  int tid = threadIdx.x, c = tid & 127;
  float s = 0.f, q = 0.f;
  for (long r = (long)blockIdx.x * 2 + (tid >> 7); r < N; r += (long)gridDim.x * 2) {
    float v = h[r * HB + c];
    s += v; q += v * v;
  }
  ls[tid] = s; lq[tid] = q;
  __syncthreads();
  if (tid < 128) {
    s = ls[tid] + ls[tid + 128];
    q = lq[tid] + lq[tid + 128];
    atomicAdd(&stat[c], s);
    atomicAdd(&stat[128 + c], q);
  }
}

__global__ __launch_bounds__(128) void bnfin_k(const float* __restrict__ stat,
    const float* __restrict__ g, const float* __restrict__ b,
    float* __restrict__ sc, int N) {
  int c = threadIdx.x;
  if (c < 128) {
    float mu = stat[c] / N, ms = stat[128 + c] / N;
    float var = ms - mu * mu;
    float a = g[c] * rsqrtf(var + 1e-5f);
    sc[c] = a;
    sc[128 + c] = b[c] - mu * a;
  }
}

// ---- BN apply (in place) + per-node dots with Ws1/Ws2 (one wave per node) ----
__global__ __launch_bounds__(256) void bnapply_score_k(float* __restrict__ h,
    const float* __restrict__ sc, const float* __restrict__ w1,
    const float* __restrict__ w2, float* __restrict__ selfs,
    float* __restrict__ t2, int N) {
  int gid = blockIdx.x * blockDim.x + threadIdx.x;
  int node = gid >> 6;
  if (node >= N) return;
  int lane = gid & 63, c = lane * 2;
  float2 v = *(float2*)(h + (size_t)node * HB + c);
  v.x = v.x * sc[c] + sc[128 + c];
  v.y = v.y * sc[c + 1] + sc[128 + c + 1];
  *(float2*)(h + (size_t)node * HB + c) = v;
  float s1 = v.x * w1[c] + v.y * w1[c + 1];
  float s2 = v.x * w2[c] + v.y * w2[c + 1];
  #pragma unroll
  for (int off = 32; off > 0; off >>= 1) {
    s1 += __shfl_xor(s1, off);
    s2 += __shfl_xor(s2, off);
  }
  if (lane == 0) { selfs[node] = s1; t2[node] = s2; }
}

// ---- SAG score: selfs + CSR gather of t2 + bias ----
__global__ __launch_bounds__(256) void score_k(const float* __restrict__ selfs,
    const float* __restrict__ t2, const int* __restrict__ srow,
    const int* __restrict__ off, const float* __restrict__ bs,
    float* __restrict__ score, int N) {
  int i = blockIdx.x * blockDim.x + threadIdx.x;
  if (i >= N) return;
  float s = selfs[i] + bs[0];
  int e0 = off[i], e1 = off[i + 1];
  for (int j = e0; j < e1; ++j) s += t2[srow[j]];
  score[i] = s;
}

// ---- per-graph top-k (bitonic, desc score / asc index ties) + gather + inv ----
__global__ __launch_bounds__(256) void topk_gather_k(const float* __restrict__ score,
    const float* __restrict__ h, float* __restrict__ xout, int* __restrict__ inv,
    int n, int k) {
  __shared__ float ss[2048];
  __shared__ int si[2048];
  int g = blockIdx.x, tid = threadIdx.x;
  for (int i = tid; i < n; i += blockDim.x) { ss[i] = score[g * n + i]; si[i] = i; }
  __syncthreads();
  for (int ksz = 2; ksz <= n; ksz <<= 1) {
    for (int j = ksz >> 1; j > 0; j >>= 1) {
      for (int i = tid; i < n; i += blockDim.x) {
        int ixj = i ^ j;
        if (ixj > i) {
          float a = ss[i], b = ss[ixj];
          int ia = si[i], ib = si[ixj];
          bool after_i = (a < b) || (a == b && ia > ib);
          bool up = ((i & ksz) == 0);
          if (after_i == up) { ss[i] = b; ss[ixj] = a; si[i] = ib; si[ixj] = ia; }
        }
      }
      __syncthreads();
    }
  }
  for (int jj = tid; jj < n; jj += blockDim.x)
    inv[g * n + si[jj]] = (jj < k) ? (g * k + jj) : -1;
  for (int idx = tid; idx < k * HB; idx += blockDim.x) {
    int j = idx >> 7, c = idx & 127;
    int old = g * n + si[j];
    xout[((size_t)g * k + j) * HB + c] = h[(size_t)old * HB + c] * tanhf(ss[j]);
  }
}

// ---- edge re-index + compact ----
__global__ __launch_bounds__(256) void compact_k(const int* __restrict__ row,
    const int* __restrict__ col, const int* __restrict__ inv,
    const int* __restrict__ ecnt_old, int* __restrict__ nrow,
    int* __restrict__ ncol, int* __restrict__ ecnt_new) {
  int e = blockIdx.x * blockDim.x + threadIdx.x;
  if (e >= *ecnt_old) return;
  int r = row[e], c = col[e];
  int nr = inv[r], nc = inv[c];
  bool valid = (nr >= 0) && (nc >= 0);
  unsigned long long mask = __ballot(valid);
  if (valid) {
    int lane = threadIdx.x & 63;
    unsigned long long lt = ((unsigned long long)1 << lane) - 1;
    int leader = __ffsll((long long)mask) - 1;
    int base = 0;
    if (lane == leader) base = atomicAdd(ecnt_new, __popcll(mask));
    base = __shfl(base, leader);
    int pos = base + (int)__popcll(mask & lt);
    nrow[pos] = nr;
    ncol[pos] = nc;
  }
}

// ---- final mean pool ----
__global__ __launch_bounds__(128) void pool_k(const float* __restrict__ x,
    float* __restrict__ out, int n) {
  int g = blockIdx.x, c = threadIdx.x;
  float s = 0.f;
  for (int r = 0; r < n; ++r) s += x[((size_t)g * n + r) * HB + c];
  out[g * HB + c] = s / n;
}

extern "C" void kernel_launch(void* const* d_in, const int* in_sizes, int n_in,
                              void* d_out, int out_size, void* d_ws, size_t ws_size,
                              hipStream_t stream) {
  const float* x_in = (const float*)d_in[0];
  const int*   ei   = (const int*)d_in[1];
  const float* Wc1  = (const float*)d_in[3];
  const float* Wc   = (const float*)d_in[4];
  const float* bc   = (const float*)d_in[5];
  const float* Wf   = (const float*)d_in[6];
  const float* bf   = (const float*)d_in[7];
  const float* bng  = (const float*)d_in[8];
  const float* bnb  = (const float*)d_in[9];
  const float* Ws1  = (const float*)d_in[10];
  const float* Ws2  = (const float*)d_in[11];
  const float* bs   = (const float*)d_in[12];

  const int N0 = 131072, E = NE;
  char* p = (char*)d_ws;
  auto alloc = [&](size_t bytes) -> char* {
    char* r = p; p += (bytes + 255) & ~(size_t)255; return r;
  };
  float* A    = (float*)alloc((size_t)N0 * HB * 4);       // hw, then fc/bn output
  float* Bb   = (float*)alloc((size_t)N0 * HB * 4);       // conv result
  float* Cc   = (float*)alloc((size_t)(N0 / 2) * HB * 4); // pooled x; srow/snorm aliased
  int*   rowA = (int*)alloc((size_t)E * 4);
  int*   colA = (int*)alloc((size_t)E * 4);
  int*   rowB = (int*)alloc((size_t)E * 4);
  int*   colB = (int*)alloc((size_t)E * 4);
  int*   degi = (int*)alloc((size_t)N0 * 4);
  float* dis  = (float*)alloc((size_t)N0 * 4);
  float* selfs= (float*)alloc((size_t)N0 * 4);
  float* t2v  = (float*)alloc((size_t)N0 * 4);
  float* score= (float*)alloc((size_t)N0 * 4);
  int*   inv  = (int*)alloc((size_t)N0 * 4);
  int*   off  = (int*)alloc((size_t)(N0 + 1) * 4);
  int*   cursor = (int*)alloc((size_t)N0 * 4);
  int*   bsum = (int*)alloc(512 * 4);
  int*   bsumo= (int*)alloc(512 * 4);
  float* stat = (float*)alloc(256 * 4);
  float* bnsc = (float*)alloc(256 * 4);
  int*   ecnt = (int*)alloc(2 * 4);

  // srow/snorm alias the Cc region: dead between topk write (end of layer)
  // and scatter (mid-layer); all uses are stream-ordered before topk.
  int*   srow  = (int*)Cc;
  float* snorm = (float*)(Cc + (size_t)E);

  init_edges_k<<<E / 256, 256, 0, stream>>>(ei, rowA, colA, E);
  int* ecntCur = ecnt; int* ecntNxt = ecnt + 1;
  set_int_k<<<1, 1, 0, stream>>>(ecntCur, E);

  int* rowCur = rowA; int* colCur = colA;
  int* rowNxt = rowB; int* colNxt = colB;

  int n = 2048, K = 7;
  const float* xcur = x_in;
  const int EG = E / 256;  // edge-kernel grid (guarded by device count)
  for (int i = 0; i < 4; ++i) {
    int N = NB * n, khalf = n >> 1;
    const float* W = (i == 0) ? Wc1 : (Wc + (size_t)(i - 1) * HB * HB);
    // hw = x @ W
    matmul_k<<<N / 32, 256, (size_t)K * HB * 4, stream>>>(xcur, W, nullptr, A, N, K, 0);
    // CSR build: histogram -> scan -> scatter
    hipMemsetAsync(degi, 0, (size_t)N * 4, stream);
    hist_k<<<EG, 256, 0, stream>>>(colCur, ecntCur, degi);
    dis_k<<<(N + 255) / 256, 256, 0, stream>>>(degi, dis, N);
    scanA_k<<<N / 256, 256, 0, stream>>>(degi, off, bsum);
    scanB_k<<<1, 512, 0, stream>>>(bsum, bsumo, N / 256);
    scanC_k<<<N / 256, 256, 0, stream>>>(off, cursor, bsumo, ecntCur, N);
    scatter_k<<<EG, 256, 0, stream>>>(rowCur, colCur, ecntCur, dis, cursor, srow, snorm);
    // aggregation (gather) + self loop + bias
    gather_combine_k<<<N / 8, 256, 0, stream>>>(A, srow, snorm, off, dis,
                                                bc + (size_t)i * HB, Bb, N);
    // fc + relu
    matmul_k<<<N / 32, 256, (size_t)HB * HB * 4, stream>>>(
        Bb, Wf + (size_t)i * HB * HB, bf + (size_t)i * HB, A, N, HB, 3);
    // batchnorm
    hipMemsetAsync(stat, 0, 256 * 4, stream);
    bnstat_k<<<512, 256, 0, stream>>>(A, stat, N);
    bnfin_k<<<1, 128, 0, stream>>>(stat, bng + (size_t)i * HB, bnb + (size_t)i * HB, bnsc, N);
    bnapply_score_k<<<N / 4, 256, 0, stream>>>(
        A, bnsc, Ws1 + (size_t)i * HB, Ws2 + (size_t)i * HB, selfs, t2v, N);
    // SAG score via CSR gather
    score_k<<<(N + 255) / 256, 256, 0, stream>>>(selfs, t2v, srow, off, bs + i, score, N);
    // top-k + gather + inverse index (overwrites Cc; srow/snorm dead now)
    topk_gather_k<<<NB, 256, 0, stream>>>(score, A, Cc, inv, n, khalf);
    if (i < 3) {
      hipMemsetAsync(ecntNxt, 0, 4, stream);
      compact_k<<<EG, 256, 0, stream>>>(rowCur, colCur, inv, ecntCur, rowNxt, colNxt, ecntNxt);
      int* t;
      t = rowCur; rowCur = rowNxt; rowNxt = t;
      t = colCur; colCur = colNxt; colNxt = t;
      t = ecntCur; ecntCur = ecntNxt; ecntNxt = t;
    }
    xcur = Cc; K = HB; n = khalf;
  }
  pool_k<<<NB, 128, 0, stream>>>(Cc, (float*)d_out, n);
}

// Round 3
// 1550.079 us; speedup vs baseline: 2.4498x; 1.0766x over previous
//
#include <hip/hip_runtime.h>
#include <cstdint>

#define HB 128   // hidden size
#define NB 64    // graphs per batch
#define NE 1048576

// ---- init edge arrays ----
__global__ __launch_bounds__(256) void init_edges_k(const int* __restrict__ ei,
    int* __restrict__ row, int* __restrict__ col, int E) {
  int e = blockIdx.x * blockDim.x + threadIdx.x;
  if (e < E) { row[e] = ei[e]; col[e] = ei[E + e]; }
}

__global__ void set_int_k(int* p, int v) { *p = v; }

// ---- generic tiled matmul: out[N][128] = X[N][K] @ W[K][128] (+bias,relu) ----
// flags bit0: add bias, bit1: relu
__global__ __launch_bounds__(256) void matmul_k(const float* __restrict__ X,
    const float* __restrict__ W, const float* __restrict__ bias,
    float* __restrict__ out, int N, int K, int flags) {
  extern __shared__ float lw[];  // K*128 floats
  int tid = threadIdx.x;
  int nv = K * 32;  // float4 count
  for (int idx = tid; idx < nv; idx += 256)
    ((float4*)lw)[idx] = ((const float4*)W)[idx];
  __syncthreads();
  int tx = tid & 31, ty = tid >> 5;
  long rowbase = (long)blockIdx.x * 32;
  float acc[4][4] = {};
  const float* xp = X + (size_t)(rowbase + ty) * K;
  for (int k = 0; k < K; ++k) {
    float4 wv = ((float4*)lw)[k * 32 + tx];
    #pragma unroll
    for (int rr = 0; rr < 4; ++rr) {
      float xv = xp[(size_t)rr * 8 * K + k];
      acc[rr][0] += xv * wv.x; acc[rr][1] += xv * wv.y;
      acc[rr][2] += xv * wv.z; acc[rr][3] += xv * wv.w;
    }
  }
  float4 bv = make_float4(0.f, 0.f, 0.f, 0.f);
  if (flags & 1) bv = ((const float4*)bias)[tx];
  #pragma unroll
  for (int rr = 0; rr < 4; ++rr) {
    long r = rowbase + ty + rr * 8;
    float4 v;
    v.x = acc[rr][0] + bv.x; v.y = acc[rr][1] + bv.y;
    v.z = acc[rr][2] + bv.z; v.w = acc[rr][3] + bv.w;
    if (flags & 2) {
      v.x = fmaxf(v.x, 0.f); v.y = fmaxf(v.y, 0.f);
      v.z = fmaxf(v.z, 0.f); v.w = fmaxf(v.w, 0.f);
    }
    ((float4*)(out + (size_t)r * HB))[tx] = v;
  }
}

// ---- int degree histogram over compacted edges ----
__global__ __launch_bounds__(256) void hist_k(const int* __restrict__ col,
    const int* __restrict__ ecnt, int* __restrict__ degi) {
  int e = blockIdx.x * blockDim.x + threadIdx.x;
  if (e < *ecnt) atomicAdd(&degi[col[e]], 1);
}

__global__ __launch_bounds__(256) void dis_k(const int* __restrict__ degi,
    float* __restrict__ dis, int N) {
  int i = blockIdx.x * blockDim.x + threadIdx.x;
  if (i < N) dis[i] = rsqrtf((float)degi[i] + 1.f);
}

// ---- hierarchical exclusive scan: A (per-256 chunk), B (chunk sums), C (add base) ----
__global__ __launch_bounds__(256) void scanA_k(const int* __restrict__ degi,
    int* __restrict__ off, int* __restrict__ bsum) {
  __shared__ int s[256];
  int tid = threadIdx.x;
  int i = blockIdx.x * 256 + tid;
  int v = degi[i];
  s[tid] = v; __syncthreads();
  for (int o = 1; o < 256; o <<= 1) {
    int t = (tid >= o) ? s[tid - o] : 0;
    __syncthreads();
    s[tid] += t;
    __syncthreads();
  }
  off[i] = s[tid] - v;
  if (tid == 255) bsum[blockIdx.x] = s[255];
}

__global__ __launch_bounds__(512) void scanB_k(const int* __restrict__ bsum,
    int* __restrict__ bsumo, int nb) {
  __shared__ int s[512];
  int tid = threadIdx.x;
  int v = (tid < nb) ? bsum[tid] : 0;
  s[tid] = v; __syncthreads();
  for (int o = 1; o < 512; o <<= 1) {
    int t = (tid >= o) ? s[tid - o] : 0;
    __syncthreads();
    s[tid] += t;
    __syncthreads();
  }
  if (tid < nb) bsumo[tid] = s[tid] - v;
}

__global__ __launch_bounds__(256) void scanC_k(int* __restrict__ off,
    int* __restrict__ cursor, const int* __restrict__ bsumo,
    const int* __restrict__ ecnt, int N) {
  int i = blockIdx.x * 256 + threadIdx.x;
  if (i >= N) return;
  int v = off[i] + bsumo[i >> 8];
  off[i] = v; cursor[i] = v;
  if (i == N - 1) off[N] = *ecnt;
}

// ---- scatter edges into CSR (payload: row index + norm coefficient) ----
__global__ __launch_bounds__(256) void scatter_k(const int* __restrict__ row,
    const int* __restrict__ col, const int* __restrict__ ecnt,
    const float* __restrict__ dis, int* __restrict__ cursor,
    int* __restrict__ srow, float* __restrict__ snorm) {
  int e = blockIdx.x * blockDim.x + threadIdx.x;
  if (e >= *ecnt) return;
  int r = row[e], c = col[e];
  int p = atomicAdd(&cursor[c], 1);
  srow[p] = r;
  snorm[p] = dis[r] * dis[c];
}

// ---- CSR gather + self loop + bias: out_i = sum_e hw[srow]*snorm + hw_i*dis_i^2 + bc ----
__global__ __launch_bounds__(256) void gather_combine_k(const float* __restrict__ hw,
    const int* __restrict__ srow, const float* __restrict__ snorm,
    const int* __restrict__ off, const float* __restrict__ dis,
    const float* __restrict__ bc, float* __restrict__ out, int N) {
  int gid = blockIdx.x * blockDim.x + threadIdx.x;
  int node = gid >> 5;
  if (node >= N) return;
  int ch = (gid & 31) * 4;
  int s = off[node], e = off[node + 1];
  float4 acc = make_float4(0.f, 0.f, 0.f, 0.f);
  for (int j = s; j < e; ++j) {
    int r = srow[j];
    float nm = snorm[j];
    float4 v = *(const float4*)(hw + (size_t)r * HB + ch);
    acc.x += v.x * nm; acc.y += v.y * nm; acc.z += v.z * nm; acc.w += v.w * nm;
  }
  float d = dis[node], d2 = d * d;
  float4 h = *(const float4*)(hw + (size_t)node * HB + ch);
  float4 b = *(const float4*)(bc + ch);
  acc.x += h.x * d2 + b.x; acc.y += h.y * d2 + b.y;
  acc.z += h.z * d2 + b.z; acc.w += h.w * d2 + b.w;
  *(float4*)(out + (size_t)node * HB + ch) = acc;
}

// ---- BN stats: per-channel sum & sumsq ----
__global__ __launch_bounds__(256) void bnstat_k(const float* __restrict__ h,
    float* __restrict__ stat, int N) {
  __shared__ float ls[256], lq[256];
  int tid = threadIdx.x, c = tid & 127;
  float s = 0.f, q = 0.f;
  for (long r = (long)blockIdx.x * 2 + (tid >> 7); r < N; r += (long)gridDim.x * 2) {
    float v = h[r * HB + c];
    s += v; q += v * v;
  }
  ls[tid] = s; lq[tid] = q;
  __syncthreads();
  if (tid < 128) {
    s = ls[tid] + ls[tid + 128];
    q = lq[tid] + lq[tid + 128];
    atomicAdd(&stat[c], s);
    atomicAdd(&stat[128 + c], q);
  }
}

__global__ __launch_bounds__(128) void bnfin_k(const float* __restrict__ stat,
    const float* __restrict__ g, const float* __restrict__ b,
    float* __restrict__ sc, int N) {
  int c = threadIdx.x;
  if (c < 128) {
    float mu = stat[c] / N, ms = stat[128 + c] / N;
    float var = ms - mu * mu;
    float a = g[c] * rsqrtf(var + 1e-5f);
    sc[c] = a;
    sc[128 + c] = b[c] - mu * a;
  }
}

// ---- BN apply (in place) + per-node dots with Ws1/Ws2 (one wave per node) ----
__global__ __launch_bounds__(256) void bnapply_score_k(float* __restrict__ h,
    const float* __restrict__ sc, const float* __restrict__ w1,
    const float* __restrict__ w2, float* __restrict__ selfs,
    float* __restrict__ t2, int N) {
  int gid = blockIdx.x * blockDim.x + threadIdx.x;
  int node = gid >> 6;
  if (node >= N) return;
  int lane = gid & 63, c = lane * 2;
  float2 v = *(float2*)(h + (size_t)node * HB + c);
  v.x = v.x * sc[c] + sc[128 + c];
  v.y = v.y * sc[c + 1] + sc[128 + c + 1];
  *(float2*)(h + (size_t)node * HB + c) = v;
  float s1 = v.x * w1[c] + v.y * w1[c + 1];
  float s2 = v.x * w2[c] + v.y * w2[c + 1];
  #pragma unroll
  for (int off = 32; off > 0; off >>= 1) {
    s1 += __shfl_xor(s1, off);
    s2 += __shfl_xor(s2, off);
  }
  if (lane == 0) { selfs[node] = s1; t2[node] = s2; }
}

// ---- SAG score: selfs + CSR gather of t2 + bias ----
__global__ __launch_bounds__(256) void score_k(const float* __restrict__ selfs,
    const float* __restrict__ t2, const int* __restrict__ srow,
    const int* __restrict__ off, const float* __restrict__ bs,
    float* __restrict__ score, int N) {
  int i = blockIdx.x * blockDim.x + threadIdx.x;
  if (i >= N) return;
  float s = selfs[i] + bs[0];
  int e0 = off[i], e1 = off[i + 1];
  for (int j = e0; j < e1; ++j) s += t2[srow[j]];
  score[i] = s;
}

// ---- exact top-k by rank: rank_i = #{j: s_j>s_i || (s_j==s_i && j<i)} ----
// One block per graph; scores staged in LDS; j-loop is wave-uniform (broadcast).
__global__ __launch_bounds__(1024) void rank_topk_k(const float* __restrict__ score,
    int* __restrict__ inv, int* __restrict__ sel, float* __restrict__ scale,
    int n, int k) {
  extern __shared__ float ls[];  // n floats
  int g = blockIdx.x, tid = threadIdx.x;
  const float* sg = score + (size_t)g * n;
  for (int i = tid; i < n; i += 1024) ls[i] = sg[i];
  __syncthreads();
  // up to 2 elements per thread share one j-sweep
  int i0 = tid, i1 = tid + 1024;
  bool h0 = i0 < n, h1 = i1 < n;
  float s0 = h0 ? ls[i0] : 0.f, s1 = h1 ? ls[i1] : 0.f;
  int r0 = 0, r1 = 0;
  for (int jb = 0; jb < n; jb += 4) {
    float4 v = *(const float4*)(ls + jb);
    r0 += (v.x > s0) || (v.x == s0 && (jb + 0) < i0);
    r0 += (v.y > s0) || (v.y == s0 && (jb + 1) < i0);
    r0 += (v.z > s0) || (v.z == s0 && (jb + 2) < i0);
    r0 += (v.w > s0) || (v.w == s0 && (jb + 3) < i0);
    r1 += (v.x > s1) || (v.x == s1 && (jb + 0) < i1);
    r1 += (v.y > s1) || (v.y == s1 && (jb + 1) < i1);
    r1 += (v.z > s1) || (v.z == s1 && (jb + 2) < i1);
    r1 += (v.w > s1) || (v.w == s1 && (jb + 3) < i1);
  }
  if (h0) {
    if (r0 < k) {
      inv[(size_t)g * n + i0] = g * k + r0;
      sel[(size_t)g * k + r0] = g * n + i0;
      scale[(size_t)g * k + r0] = tanhf(s0);
    } else inv[(size_t)g * n + i0] = -1;
  }
  if (h1) {
    if (r1 < k) {
      inv[(size_t)g * n + i1] = g * k + r1;
      sel[(size_t)g * k + r1] = g * n + i1;
      scale[(size_t)g * k + r1] = tanhf(s1);
    } else inv[(size_t)g * n + i1] = -1;
  }
}

// ---- gather kept rows: xout[r] = h[sel[r]] * scale[r] ----
__global__ __launch_bounds__(256) void gather_x_k(const float* __restrict__ h,
    const int* __restrict__ sel, const float* __restrict__ scale,
    float* __restrict__ xout, int M) {
  int gid = blockIdx.x * blockDim.x + threadIdx.x;
  int r = gid >> 5;
  if (r >= M) return;
  int ch = (gid & 31) * 4;
  int old = sel[r];
  float sc = scale[r];
  float4 v = *(const float4*)(h + (size_t)old * HB + ch);
  v.x *= sc; v.y *= sc; v.z *= sc; v.w *= sc;
  *(float4*)(xout + (size_t)r * HB + ch) = v;
}

// ---- edge re-index + compact ----
__global__ __launch_bounds__(256) void compact_k(const int* __restrict__ row,
    const int* __restrict__ col, const int* __restrict__ inv,
    const int* __restrict__ ecnt_old, int* __restrict__ nrow,
    int* __restrict__ ncol, int* __restrict__ ecnt_new) {
  int e = blockIdx.x * blockDim.x + threadIdx.x;
  if (e >= *ecnt_old) return;
  int r = row[e], c = col[e];
  int nr = inv[r], nc = inv[c];
  bool valid = (nr >= 0) && (nc >= 0);
  unsigned long long mask = __ballot(valid);
  if (valid) {
    int lane = threadIdx.x & 63;
    unsigned long long lt = ((unsigned long long)1 << lane) - 1;
    int leader = __ffsll((long long)mask) - 1;
    int base = 0;
    if (lane == leader) base = atomicAdd(ecnt_new, __popcll(mask));
    base = __shfl(base, leader);
    int pos = base + (int)__popcll(mask & lt);
    nrow[pos] = nr;
    ncol[pos] = nc;
  }
}

// ---- final mean pool ----
__global__ __launch_bounds__(128) void pool_k(const float* __restrict__ x,
    float* __restrict__ out, int n) {
  int g = blockIdx.x, c = threadIdx.x;
  float s = 0.f;
  for (int r = 0; r < n; ++r) s += x[((size_t)g * n + r) * HB + c];
  out[g * HB + c] = s / n;
}

extern "C" void kernel_launch(void* const* d_in, const int* in_sizes, int n_in,
                              void* d_out, int out_size, void* d_ws, size_t ws_size,
                              hipStream_t stream) {
  const float* x_in = (const float*)d_in[0];
  const int*   ei   = (const int*)d_in[1];
  const float* Wc1  = (const float*)d_in[3];
  const float* Wc   = (const float*)d_in[4];
  const float* bc   = (const float*)d_in[5];
  const float* Wf   = (const float*)d_in[6];
  const float* bf   = (const float*)d_in[7];
  const float* bng  = (const float*)d_in[8];
  const float* bnb  = (const float*)d_in[9];
  const float* Ws1  = (const float*)d_in[10];
  const float* Ws2  = (const float*)d_in[11];
  const float* bs   = (const float*)d_in[12];

  const int N0 = 131072, E = NE;
  char* p = (char*)d_ws;
  auto alloc = [&](size_t bytes) -> char* {
    char* r = p; p += (bytes + 255) & ~(size_t)255; return r;
  };
  float* A    = (float*)alloc((size_t)N0 * HB * 4);       // hw, then fc/bn output
  float* Bb   = (float*)alloc((size_t)N0 * HB * 4);       // conv result
  float* Cc   = (float*)alloc((size_t)(N0 / 2) * HB * 4); // pooled x; srow/snorm aliased
  int*   rowA = (int*)alloc((size_t)E * 4);
  int*   colA = (int*)alloc((size_t)E * 4);
  int*   rowB = (int*)alloc((size_t)E * 4);
  int*   colB = (int*)alloc((size_t)E * 4);
  int*   degi = (int*)alloc((size_t)N0 * 4);
  float* dis  = (float*)alloc((size_t)N0 * 4);
  float* selfs= (float*)alloc((size_t)N0 * 4);
  float* t2v  = (float*)alloc((size_t)N0 * 4);
  float* score= (float*)alloc((size_t)N0 * 4);
  int*   inv  = (int*)alloc((size_t)N0 * 4);
  int*   off  = (int*)alloc((size_t)(N0 + 1) * 4);
  int*   cursor = (int*)alloc((size_t)N0 * 4);
  int*   sel  = (int*)alloc((size_t)(N0 / 2) * 4);
  float* scale= (float*)alloc((size_t)(N0 / 2) * 4);
  int*   bsum = (int*)alloc(512 * 4);
  int*   bsumo= (int*)alloc(512 * 4);
  float* stat = (float*)alloc(256 * 4);
  float* bnsc = (float*)alloc(256 * 4);
  int*   ecnt = (int*)alloc(2 * 4);

  // srow/snorm alias the Cc region: dead between gather_x write (end of layer)
  // and scatter (mid-layer); all uses are stream-ordered before gather_x.
  int*   srow  = (int*)Cc;
  float* snorm = (float*)(Cc + (size_t)E);

  init_edges_k<<<E / 256, 256, 0, stream>>>(ei, rowA, colA, E);
  int* ecntCur = ecnt; int* ecntNxt = ecnt + 1;
  set_int_k<<<1, 1, 0, stream>>>(ecntCur, E);

  int* rowCur = rowA; int* colCur = colA;
  int* rowNxt = rowB; int* colNxt = colB;

  int n = 2048, K = 7;
  const float* xcur = x_in;
  const int EG = E / 256;  // edge-kernel grid (guarded by device count)
  for (int i = 0; i < 4; ++i) {
    int N = NB * n, khalf = n >> 1;
    const float* W = (i == 0) ? Wc1 : (Wc + (size_t)(i - 1) * HB * HB);
    // hw = x @ W
    matmul_k<<<N / 32, 256, (size_t)K * HB * 4, stream>>>(xcur, W, nullptr, A, N, K, 0);
    // CSR build: histogram -> scan -> scatter
    hipMemsetAsync(degi, 0, (size_t)N * 4, stream);
    hist_k<<<EG, 256, 0, stream>>>(colCur, ecntCur, degi);
    dis_k<<<(N + 255) / 256, 256, 0, stream>>>(degi, dis, N);
    scanA_k<<<N / 256, 256, 0, stream>>>(degi, off, bsum);
    scanB_k<<<1, 512, 0, stream>>>(bsum, bsumo, N / 256);
    scanC_k<<<N / 256, 256, 0, stream>>>(off, cursor, bsumo, ecntCur, N);
    scatter_k<<<EG, 256, 0, stream>>>(rowCur, colCur, ecntCur, dis, cursor, srow, snorm);
    // aggregation (gather) + self loop + bias
    gather_combine_k<<<N / 8, 256, 0, stream>>>(A, srow, snorm, off, dis,
                                                bc + (size_t)i * HB, Bb, N);
    // fc + relu
    matmul_k<<<N / 32, 256, (size_t)HB * HB * 4, stream>>>(
        Bb, Wf + (size_t)i * HB * HB, bf + (size_t)i * HB, A, N, HB, 3);
    // batchnorm
    hipMemsetAsync(stat, 0, 256 * 4, stream);
    bnstat_k<<<512, 256, 0, stream>>>(A, stat, N);
    bnfin_k<<<1, 128, 0, stream>>>(stat, bng + (size_t)i * HB, bnb + (size_t)i * HB, bnsc, N);
    bnapply_score_k<<<N / 4, 256, 0, stream>>>(
        A, bnsc, Ws1 + (size_t)i * HB, Ws2 + (size_t)i * HB, selfs, t2v, N);
    // SAG score via CSR gather
    score_k<<<(N + 255) / 256, 256, 0, stream>>>(selfs, t2v, srow, off, bs + i, score, N);
    // exact top-k by rank (order + ties match jax.lax.top_k)
    rank_topk_k<<<NB, 1024, (size_t)n * 4, stream>>>(score, inv, sel, scale, n, khalf);
    // gather kept rows into Cc (srow/snorm dead now)
    gather_x_k<<<(NB * khalf) / 8, 256, 0, stream>>>(A, sel, scale, Cc, NB * khalf);
    if (i < 3) {
      hipMemsetAsync(ecntNxt, 0, 4, stream);
      compact_k<<<EG, 256, 0, stream>>>(rowCur, colCur, inv, ecntCur, rowNxt, colNxt, ecntNxt);
      int* t;
      t = rowCur; rowCur = rowNxt; rowNxt = t;
      t = colCur; colCur = colNxt; colNxt = t;
      t = ecntCur; ecntCur = ecntNxt; ecntNxt = t;
    }
    xcur = Cc; K = HB; n = khalf;
  }
  pool_k<<<NB, 128, 0, stream>>>(Cc, (float*)d_out, n);
}

// Round 4
// 1243.741 us; speedup vs baseline: 3.0532x; 1.2463x over previous
//
#include <hip/hip_runtime.h>
#include <cstdint>

#define HB 128   // hidden size
#define NB 64    // graphs per batch
#define NE 1048576
#define EG (NE / 256)   // 4096 blocks for edge-sized kernels

// ---- init edge arrays ----
__global__ __launch_bounds__(256) void init_edges_k(const int* __restrict__ ei,
    int* __restrict__ row, int* __restrict__ col, int E) {
  int e = blockIdx.x * blockDim.x + threadIdx.x;
  if (e < E) { row[e] = ei[e]; col[e] = ei[E + e]; }
}

__global__ __launch_bounds__(128) void init_goff_k(int* __restrict__ goff, int epg) {
  int g = threadIdx.x;
  if (g <= NB) goff[g] = g * epg;
}

// ---- generic tiled matmul: out[N][128] = X[N][K] @ W[K][128] (+bias,relu) ----
// flags bit0: add bias, bit1: relu
__global__ __launch_bounds__(256) void matmul_k(const float* __restrict__ X,
    const float* __restrict__ W, const float* __restrict__ bias,
    float* __restrict__ out, int N, int K, int flags) {
  extern __shared__ float lw[];  // K*128 floats
  int tid = threadIdx.x;
  int nv = K * 32;  // float4 count
  for (int idx = tid; idx < nv; idx += 256)
    ((float4*)lw)[idx] = ((const float4*)W)[idx];
  __syncthreads();
  int tx = tid & 31, ty = tid >> 5;
  long rowbase = (long)blockIdx.x * 32;
  float acc[4][4] = {};
  const float* xp = X + (size_t)(rowbase + ty) * K;
  for (int k = 0; k < K; ++k) {
    float4 wv = ((float4*)lw)[k * 32 + tx];
    #pragma unroll
    for (int rr = 0; rr < 4; ++rr) {
      float xv = xp[(size_t)rr * 8 * K + k];
      acc[rr][0] += xv * wv.x; acc[rr][1] += xv * wv.y;
      acc[rr][2] += xv * wv.z; acc[rr][3] += xv * wv.w;
    }
  }
  float4 bv = make_float4(0.f, 0.f, 0.f, 0.f);
  if (flags & 1) bv = ((const float4*)bias)[tx];
  #pragma unroll
  for (int rr = 0; rr < 4; ++rr) {
    long r = rowbase + ty + rr * 8;
    float4 v;
    v.x = acc[rr][0] + bv.x; v.y = acc[rr][1] + bv.y;
    v.z = acc[rr][2] + bv.z; v.w = acc[rr][3] + bv.w;
    if (flags & 2) {
      v.x = fmaxf(v.x, 0.f); v.y = fmaxf(v.y, 0.f);
      v.z = fmaxf(v.z, 0.f); v.w = fmaxf(v.w, 0.f);
    }
    ((float4*)(out + (size_t)r * HB))[tx] = v;
  }
}

// ---- fused per-graph CSR build: LDS hist -> dis -> LDS scan -> LDS-cursor scatter ----
// one block per graph; edges grouped by graph (order-preserving compact maintains this)
__global__ __launch_bounds__(1024) void csr_build_k(const int* __restrict__ row,
    const int* __restrict__ col, const int* __restrict__ goff,
    float* __restrict__ dis, int* __restrict__ off, int* __restrict__ srow,
    float* __restrict__ snorm, int n) {
  extern __shared__ int lds[];
  int* ldeg = lds;                 // n: degree -> then cursor (local excl offsets)
  int* lsa  = lds + n;             // n: scan ping
  int* lsb  = lds + 2 * n;         // n: scan pong
  float* ldis = (float*)(lds + 3 * n);  // n: rsqrt(deg+1)
  int g = blockIdx.x, tid = threadIdx.x;
  int e0 = goff[g], e1 = goff[g + 1];
  int base = g * n;
  for (int i = tid; i < n; i += 1024) ldeg[i] = 0;
  __syncthreads();
  for (int e = e0 + tid; e < e1; e += 1024) atomicAdd(&ldeg[col[e] - base], 1);
  __syncthreads();
  for (int i = tid; i < n; i += 1024) {
    int d = ldeg[i];
    ldis[i] = rsqrtf((float)d + 1.f);
    lsa[i] = d;
  }
  __syncthreads();
  // inclusive Hillis-Steele scan over n elements (ping-pong)
  int* src = lsa; int* dst = lsb;
  for (int o = 1; o < n; o <<= 1) {
    for (int i = tid; i < n; i += 1024) dst[i] = src[i] + ((i >= o) ? src[i - o] : 0);
    __syncthreads();
    int* t = src; src = dst; dst = t;
  }
  // exclusive offsets; publish global off/dis; init cursor
  for (int i = tid; i < n; i += 1024) {
    int d = ldeg[i];
    int ex = src[i] - d;
    off[base + i] = e0 + ex;
    ldeg[i] = ex;                 // cursor
    dis[base + i] = ldis[i];
  }
  if (tid == 0) off[base + n] = e1;  // benign duplicate with next block's off[base]
  __syncthreads();
  // scatter edges into CSR slots
  for (int e = e0 + tid; e < e1; e += 1024) {
    int r = row[e], c = col[e];
    int lc = c - base;
    int p = e0 + atomicAdd(&ldeg[lc], 1);
    srow[p] = r;
    snorm[p] = ldis[r - base] * ldis[lc];
  }
}

// ---- CSR gather + self loop + bias: out_i = sum_e hw[srow]*snorm + hw_i*dis_i^2 + bc ----
__global__ __launch_bounds__(256) void gather_combine_k(const float* __restrict__ hw,
    const int* __restrict__ srow, const float* __restrict__ snorm,
    const int* __restrict__ off, const float* __restrict__ dis,
    const float* __restrict__ bc, float* __restrict__ out, int N) {
  int gid = blockIdx.x * blockDim.x + threadIdx.x;
  int node = gid >> 5;
  if (node >= N) return;
  int ch = (gid & 31) * 4;
  int s = off[node], e = off[node + 1];
  float4 acc = make_float4(0.f, 0.f, 0.f, 0.f);
  for (int j = s; j < e; ++j) {
    int r = srow[j];
    float nm = snorm[j];
    float4 v = *(const float4*)(hw + (size_t)r * HB + ch);
    acc.x += v.x * nm; acc.y += v.y * nm; acc.z += v.z * nm; acc.w += v.w * nm;
  }
  float d = dis[node], d2 = d * d;
  float4 h = *(const float4*)(hw + (size_t)node * HB + ch);
  float4 b = *(const float4*)(bc + ch);
  acc.x += h.x * d2 + b.x; acc.y += h.y * d2 + b.y;
  acc.z += h.z * d2 + b.z; acc.w += h.w * d2 + b.w;
  *(float4*)(out + (size_t)node * HB + ch) = acc;
}

// ---- BN stats: per-channel sum & sumsq ----
__global__ __launch_bounds__(256) void bnstat_k(const float* __restrict__ h,
    float* __restrict__ stat, int N) {
  __shared__ float ls[256], lq[256];
  int tid = threadIdx.x, c = tid & 127;
  float s = 0.f, q = 0.f;
  for (long r = (long)blockIdx.x * 2 + (tid >> 7); r < N; r += (long)gridDim.x * 2) {
    float v = h[r * HB + c];
    s += v; q += v * v;
  }
  ls[tid] = s; lq[tid] = q;
  __syncthreads();
  if (tid < 128) {
    s = ls[tid] + ls[tid + 128];
    q = lq[tid] + lq[tid + 128];
    atomicAdd(&stat[c], s);
    atomicAdd(&stat[128 + c], q);
  }
}

__global__ __launch_bounds__(128) void bnfin_k(const float* __restrict__ stat,
    const float* __restrict__ g, const float* __restrict__ b,
    float* __restrict__ sc, int N) {
  int c = threadIdx.x;
  if (c < 128) {
    float mu = stat[c] / N, ms = stat[128 + c] / N;
    float var = ms - mu * mu;
    float a = g[c] * rsqrtf(var + 1e-5f);
    sc[c] = a;
    sc[128 + c] = b[c] - mu * a;
  }
}

// ---- BN apply (in place) + per-node dots with Ws1/Ws2 (one wave per node) ----
__global__ __launch_bounds__(256) void bnapply_score_k(float* __restrict__ h,
    const float* __restrict__ sc, const float* __restrict__ w1,
    const float* __restrict__ w2, float* __restrict__ selfs,
    float* __restrict__ t2, int N) {
  int gid = blockIdx.x * blockDim.x + threadIdx.x;
  int node = gid >> 6;
  if (node >= N) return;
  int lane = gid & 63, c = lane * 2;
  float2 v = *(float2*)(h + (size_t)node * HB + c);
  v.x = v.x * sc[c] + sc[128 + c];
  v.y = v.y * sc[c + 1] + sc[128 + c + 1];
  *(float2*)(h + (size_t)node * HB + c) = v;
  float s1 = v.x * w1[c] + v.y * w1[c + 1];
  float s2 = v.x * w2[c] + v.y * w2[c + 1];
  #pragma unroll
  for (int off = 32; off > 0; off >>= 1) {
    s1 += __shfl_xor(s1, off);
    s2 += __shfl_xor(s2, off);
  }
  if (lane == 0) { selfs[node] = s1; t2[node] = s2; }
}

// ---- SAG score: selfs + CSR gather of t2 + bias ----
__global__ __launch_bounds__(256) void score_k(const float* __restrict__ selfs,
    const float* __restrict__ t2, const int* __restrict__ srow,
    const int* __restrict__ off, const float* __restrict__ bs,
    float* __restrict__ score, int N) {
  int i = blockIdx.x * blockDim.x + threadIdx.x;
  if (i >= N) return;
  float s = selfs[i] + bs[0];
  int e0 = off[i], e1 = off[i + 1];
  for (int j = e0; j < e1; ++j) s += t2[srow[j]];
  score[i] = s;
}

// ---- exact top-k by rank: rank_i = #{j: s_j>s_i || (s_j==s_i && j<i)} ----
__global__ __launch_bounds__(1024) void rank_topk_k(const float* __restrict__ score,
    int* __restrict__ inv, int* __restrict__ sel, float* __restrict__ scale,
    int n, int k) {
  extern __shared__ float ls[];  // n floats
  int g = blockIdx.x, tid = threadIdx.x;
  const float* sg = score + (size_t)g * n;
  for (int i = tid; i < n; i += 1024) ls[i] = sg[i];
  __syncthreads();
  int i0 = tid, i1 = tid + 1024;
  bool h0 = i0 < n, h1 = i1 < n;
  float s0 = h0 ? ls[i0] : 0.f, s1 = h1 ? ls[i1] : 0.f;
  int r0 = 0, r1 = 0;
  for (int jb = 0; jb < n; jb += 4) {
    float4 v = *(const float4*)(ls + jb);
    r0 += (v.x > s0) || (v.x == s0 && (jb + 0) < i0);
    r0 += (v.y > s0) || (v.y == s0 && (jb + 1) < i0);
    r0 += (v.z > s0) || (v.z == s0 && (jb + 2) < i0);
    r0 += (v.w > s0) || (v.w == s0 && (jb + 3) < i0);
    r1 += (v.x > s1) || (v.x == s1 && (jb + 0) < i1);
    r1 += (v.y > s1) || (v.y == s1 && (jb + 1) < i1);
    r1 += (v.z > s1) || (v.z == s1 && (jb + 2) < i1);
    r1 += (v.w > s1) || (v.w == s1 && (jb + 3) < i1);
  }
  if (h0) {
    if (r0 < k) {
      inv[(size_t)g * n + i0] = g * k + r0;
      sel[(size_t)g * k + r0] = g * n + i0;
      scale[(size_t)g * k + r0] = tanhf(s0);
    } else inv[(size_t)g * n + i0] = -1;
  }
  if (h1) {
    if (r1 < k) {
      inv[(size_t)g * n + i1] = g * k + r1;
      sel[(size_t)g * k + r1] = g * n + i1;
      scale[(size_t)g * k + r1] = tanhf(s1);
    } else inv[(size_t)g * n + i1] = -1;
  }
}

// ---- gather kept rows: xout[r] = h[sel[r]] * scale[r] ----
__global__ __launch_bounds__(256) void gather_x_k(const float* __restrict__ h,
    const int* __restrict__ sel, const float* __restrict__ scale,
    float* __restrict__ xout, int M) {
  int gid = blockIdx.x * blockDim.x + threadIdx.x;
  int r = gid >> 5;
  if (r >= M) return;
  int ch = (gid & 31) * 4;
  int old = sel[r];
  float sc = scale[r];
  float4 v = *(const float4*)(h + (size_t)old * HB + ch);
  v.x *= sc; v.y *= sc; v.z *= sc; v.w *= sc;
  *(float4*)(xout + (size_t)r * HB + ch) = v;
}

// ---- order-preserving compact, pass A: per-block valid count ----
__global__ __launch_bounds__(256) void cmpA_k(const int* __restrict__ row,
    const int* __restrict__ col, const int* __restrict__ inv,
    const int* __restrict__ ecnt, int* __restrict__ bcnt) {
  int e = blockIdx.x * 256 + threadIdx.x;
  bool valid = false;
  if (e < *ecnt) {
    int nr = inv[row[e]], nc = inv[col[e]];
    valid = (nr >= 0) && (nc >= 0);
  }
  unsigned long long mask = __ballot(valid);
  __shared__ int ws[4];
  int lane = threadIdx.x & 63, wid = threadIdx.x >> 6;
  if (lane == 0) ws[wid] = __popcll(mask);
  __syncthreads();
  if (threadIdx.x == 0) bcnt[blockIdx.x] = ws[0] + ws[1] + ws[2] + ws[3];
}

// ---- pass B: exclusive scan of 4096 block counts (one block, 4/thread) ----
__global__ __launch_bounds__(1024) void cmpB_k(const int* __restrict__ bcnt,
    int* __restrict__ bbase, int* __restrict__ total) {
  __shared__ int s[1024];
  int tid = threadIdx.x;
  int v0 = bcnt[4 * tid], v1 = bcnt[4 * tid + 1];
  int v2 = bcnt[4 * tid + 2], v3 = bcnt[4 * tid + 3];
  int tsum = v0 + v1 + v2 + v3;
  s[tid] = tsum; __syncthreads();
  for (int o = 1; o < 1024; o <<= 1) {
    int t = (tid >= o) ? s[tid - o] : 0;
    __syncthreads();
    s[tid] += t;
    __syncthreads();
  }
  int base = s[tid] - tsum;
  bbase[4 * tid] = base;
  bbase[4 * tid + 1] = base + v0;
  bbase[4 * tid + 2] = base + v0 + v1;
  bbase[4 * tid + 3] = base + v0 + v1 + v2;
  if (tid == 1023) *total = s[1023];
}

// ---- pass C: scatter (order-preserving) + per-graph edge histogram ----
__global__ __launch_bounds__(256) void cmpC_k(const int* __restrict__ row,
    const int* __restrict__ col, const int* __restrict__ inv,
    const int* __restrict__ ecnt, const int* __restrict__ bbase,
    int* __restrict__ nrow, int* __restrict__ ncol, int* __restrict__ gcnt,
    int khalf) {
  int e = blockIdx.x * 256 + threadIdx.x;
  bool valid = false; int nr = 0, nc = 0;
  if (e < *ecnt) {
    nr = inv[row[e]]; nc = inv[col[e]];
    valid = (nr >= 0) && (nc >= 0);
  }
  unsigned long long mask = __ballot(valid);
  int lane = threadIdx.x & 63, wid = threadIdx.x >> 6;
  __shared__ int ws[4];
  __shared__ int lg[NB];
  if (threadIdx.x < NB) lg[threadIdx.x] = 0;
  if (lane == 0) ws[wid] = __popcll(mask);
  __syncthreads();
  if (threadIdx.x == 0) {
    int a = ws[0], b = ws[1], c2 = ws[2];
    ws[0] = 0; ws[1] = a; ws[2] = a + b; ws[3] = a + b + c2;
  }
  __syncthreads();
  if (valid) {
    unsigned long long lt = ((unsigned long long)1 << lane) - 1;
    int pos = bbase[blockIdx.x] + ws[wid] + (int)__popcll(mask & lt);
    nrow[pos] = nr;
    ncol[pos] = nc;
    atomicAdd(&lg[nc / khalf], 1);
  }
  __syncthreads();
  if (threadIdx.x < NB && lg[threadIdx.x]) atomicAdd(&gcnt[threadIdx.x], lg[threadIdx.x]);
}

// ---- scan 64 graph counts -> goff[65] ----
__global__ void gscan_k(const int* __restrict__ gcnt, int* __restrict__ goff) {
  if (threadIdx.x == 0) {
    int s = 0;
    for (int g = 0; g < NB; ++g) { goff[g] = s; s += gcnt[g]; }
    goff[NB] = s;
  }
}

// ---- final mean pool ----
__global__ __launch_bounds__(128) void pool_k(const float* __restrict__ x,
    float* __restrict__ out, int n) {
  int g = blockIdx.x, c = threadIdx.x;
  float s = 0.f;
  for (int r = 0; r < n; ++r) s += x[((size_t)g * n + r) * HB + c];
  out[g * HB + c] = s / n;
}

extern "C" void kernel_launch(void* const* d_in, const int* in_sizes, int n_in,
                              void* d_out, int out_size, void* d_ws, size_t ws_size,
                              hipStream_t stream) {
  const float* x_in = (const float*)d_in[0];
  const int*   ei   = (const int*)d_in[1];
  const float* Wc1  = (const float*)d_in[3];
  const float* Wc   = (const float*)d_in[4];
  const float* bc   = (const float*)d_in[5];
  const float* Wf   = (const float*)d_in[6];
  const float* bf   = (const float*)d_in[7];
  const float* bng  = (const float*)d_in[8];
  const float* bnb  = (const float*)d_in[9];
  const float* Ws1  = (const float*)d_in[10];
  const float* Ws2  = (const float*)d_in[11];
  const float* bs   = (const float*)d_in[12];

  const int N0 = 131072, E = NE;
  char* p = (char*)d_ws;
  auto alloc = [&](size_t bytes) -> char* {
    char* r = p; p += (bytes + 255) & ~(size_t)255; return r;
  };
  float* A    = (float*)alloc((size_t)N0 * HB * 4);       // hw, then fc/bn output
  float* Bb   = (float*)alloc((size_t)N0 * HB * 4);       // conv result
  float* Cc   = (float*)alloc((size_t)(N0 / 2) * HB * 4); // pooled x; srow/snorm aliased
  int*   rowA = (int*)alloc((size_t)E * 4);
  int*   colA = (int*)alloc((size_t)E * 4);
  int*   rowB = (int*)alloc((size_t)E * 4);
  int*   colB = (int*)alloc((size_t)E * 4);
  float* dis  = (float*)alloc((size_t)N0 * 4);
  float* selfs= (float*)alloc((size_t)N0 * 4);
  float* t2v  = (float*)alloc((size_t)N0 * 4);
  float* score= (float*)alloc((size_t)N0 * 4);
  int*   inv  = (int*)alloc((size_t)N0 * 4);
  int*   off  = (int*)alloc((size_t)(N0 + 1) * 4);
  int*   sel  = (int*)alloc((size_t)(N0 / 2) * 4);
  float* scale= (float*)alloc((size_t)(N0 / 2) * 4);
  int*   bcnt = (int*)alloc((size_t)EG * 4);
  int*   bbase= (int*)alloc((size_t)EG * 4);
  int*   gcnt = (int*)alloc(NB * 4);
  int*   goffA= (int*)alloc((NB + 1) * 4);
  int*   goffB= (int*)alloc((NB + 1) * 4);
  float* stat = (float*)alloc(256 * 4);
  float* bnsc = (float*)alloc(256 * 4);

  // srow/snorm alias the Cc region: dead between gather_x write (end of layer)
  // and csr_build scatter (mid-layer); all uses stream-ordered before gather_x.
  int*   srow  = (int*)Cc;
  float* snorm = (float*)(Cc + (size_t)E);

  init_edges_k<<<E / 256, 256, 0, stream>>>(ei, rowA, colA, E);
  init_goff_k<<<1, 128, 0, stream>>>(goffA, E / NB);

  int* rowCur = rowA; int* colCur = colA;
  int* rowNxt = rowB; int* colNxt = colB;
  int* goffCur = goffA; int* goffNxt = goffB;

  int n = 2048, K = 7;
  const float* xcur = x_in;
  for (int i = 0; i < 4; ++i) {
    int N = NB * n, khalf = n >> 1;
    const float* W = (i == 0) ? Wc1 : (Wc + (size_t)(i - 1) * HB * HB);
    // hw = x @ W
    matmul_k<<<N / 32, 256, (size_t)K * HB * 4, stream>>>(xcur, W, nullptr, A, N, K, 0);
    // fused per-graph CSR build (LDS-only atomics)
    csr_build_k<<<NB, 1024, (size_t)16 * n, stream>>>(
        rowCur, colCur, goffCur, dis, off, srow, snorm, n);
    // aggregation (gather) + self loop + bias
    gather_combine_k<<<N / 8, 256, 0, stream>>>(A, srow, snorm, off, dis,
                                                bc + (size_t)i * HB, Bb, N);
    // fc + relu
    matmul_k<<<N / 32, 256, (size_t)HB * HB * 4, stream>>>(
        Bb, Wf + (size_t)i * HB * HB, bf + (size_t)i * HB, A, N, HB, 3);
    // batchnorm
    hipMemsetAsync(stat, 0, 256 * 4, stream);
    bnstat_k<<<512, 256, 0, stream>>>(A, stat, N);
    bnfin_k<<<1, 128, 0, stream>>>(stat, bng + (size_t)i * HB, bnb + (size_t)i * HB, bnsc, N);
    bnapply_score_k<<<N / 4, 256, 0, stream>>>(
        A, bnsc, Ws1 + (size_t)i * HB, Ws2 + (size_t)i * HB, selfs, t2v, N);
    // SAG score via CSR gather
    score_k<<<(N + 255) / 256, 256, 0, stream>>>(selfs, t2v, srow, off, bs + i, score, N);
    // exact top-k by rank (order + ties match jax.lax.top_k)
    rank_topk_k<<<NB, 1024, (size_t)n * 4, stream>>>(score, inv, sel, scale, n, khalf);
    // gather kept rows into Cc (srow/snorm dead now)
    gather_x_k<<<(NB * khalf) / 8, 256, 0, stream>>>(A, sel, scale, Cc, NB * khalf);
    if (i < 3) {
      // order-preserving compact (edges stay grouped by graph)
      cmpA_k<<<EG, 256, 0, stream>>>(rowCur, colCur, inv, goffCur + NB, bcnt);
      cmpB_k<<<1, 1024, 0, stream>>>(bcnt, bbase, goffNxt + NB);
      hipMemsetAsync(gcnt, 0, NB * 4, stream);
      cmpC_k<<<EG, 256, 0, stream>>>(rowCur, colCur, inv, goffCur + NB, bbase,
                                     rowNxt, colNxt, gcnt, khalf);
      gscan_k<<<1, 64, 0, stream>>>(gcnt, goffNxt);
      int* t;
      t = rowCur; rowCur = rowNxt; rowNxt = t;
      t = colCur; colCur = colNxt; colNxt = t;
      t = goffCur; goffCur = goffNxt; goffNxt = t;
    }
    xcur = Cc; K = HB; n = khalf;
  }
  pool_k<<<NB, 128, 0, stream>>>(Cc, (float*)d_out, n);
}

// Round 6
// 980.904 us; speedup vs baseline: 3.8713x; 1.2680x over previous
//
#include <hip/hip_runtime.h>
#include <cstdint>

#define HB 128   // hidden size
#define NB 64    // graphs per batch
#define NE 1048576
#define EG (NE / 256)   // 4096 blocks for edge-sized kernels

// ---- init edge arrays ----
__global__ __launch_bounds__(256) void init_edges_k(const int* __restrict__ ei,
    int* __restrict__ row, int* __restrict__ col, int E) {
  int e = blockIdx.x * blockDim.x + threadIdx.x;
  if (e < E) { row[e] = ei[e]; col[e] = ei[E + e]; }
}

__global__ __launch_bounds__(128) void init_goff_k(int* __restrict__ goff, int epg) {
  int g = threadIdx.x;
  if (g <= NB) goff[g] = g * epg;
}

// ---- small-K matmul: out[N][128] = X[N][K(stride KS)] @ W[K][128] (+bias) ----
__global__ __launch_bounds__(256) void matmulK_k(const float* __restrict__ X,
    const float* __restrict__ W, const float* __restrict__ bias,
    float* __restrict__ out, int N, int K, int KS, int flags) {
  extern __shared__ float lw[];  // K*128 floats
  int tid = threadIdx.x;
  int nv = K * 32;
  for (int idx = tid; idx < nv; idx += 256)
    ((float4*)lw)[idx] = ((const float4*)W)[idx];
  __syncthreads();
  int tx = tid & 31, ty = tid >> 5;
  long rowbase = (long)blockIdx.x * 32;
  float acc[4][4] = {};
  const float* xp = X + (size_t)(rowbase + ty) * KS;
  for (int k = 0; k < K; ++k) {
    float4 wv = ((float4*)lw)[k * 32 + tx];
    #pragma unroll
    for (int rr = 0; rr < 4; ++rr) {
      float xv = xp[(size_t)rr * 8 * KS + k];
      acc[rr][0] += xv * wv.x; acc[rr][1] += xv * wv.y;
      acc[rr][2] += xv * wv.z; acc[rr][3] += xv * wv.w;
    }
  }
  float4 bv = make_float4(0.f, 0.f, 0.f, 0.f);
  if (flags & 1) bv = ((const float4*)bias)[tx];
  #pragma unroll
  for (int rr = 0; rr < 4; ++rr) {
    long r = rowbase + ty + rr * 8;
    float4 v;
    v.x = acc[rr][0] + bv.x; v.y = acc[rr][1] + bv.y;
    v.z = acc[rr][2] + bv.z; v.w = acc[rr][3] + bv.w;
    if (flags & 2) {
      v.x = fmaxf(v.x, 0.f); v.y = fmaxf(v.y, 0.f);
      v.z = fmaxf(v.z, 0.f); v.w = fmaxf(v.w, 0.f);
    }
    ((float4*)(out + (size_t)r * HB))[tx] = v;
  }
}

// ---- K=128 GEMM: out[N][128] = X[N][128] @ W[128][128] (+bias,relu) ----
// 64-row tile, double-buffered LDS X, W slices in registers (L2-resident).
__global__ __launch_bounds__(256) void gemm128_k(const float* __restrict__ X,
    const float* __restrict__ W, const float* __restrict__ bias,
    float* __restrict__ out, int N, int flags) {
  __shared__ float Xs[2][64][8];
  int tid = threadIdx.x;
  int tx = tid & 31;   // cols 4*tx .. 4*tx+3
  int ty = tid >> 5;   // rows ty + 8*r, r=0..7
  long rowbase = (long)blockIdx.x * 64;
  float4 acc[8];
  #pragma unroll
  for (int r = 0; r < 8; ++r) acc[r] = make_float4(0.f, 0.f, 0.f, 0.f);
  int lr = tid >> 1, lq = (tid & 1) * 4;  // loader row / k-quad
  if (tid < 128)
    *(float4*)&Xs[0][lr][lq] = *(const float4*)(X + (rowbase + lr) * 128 + lq);
  __syncthreads();
  for (int kc = 0; kc < 16; ++kc) {
    int cur = kc & 1;
    if (kc < 15 && tid < 128)
      *(float4*)&Xs[cur ^ 1][lr][lq] =
          *(const float4*)(X + (rowbase + lr) * 128 + (kc + 1) * 8 + lq);
    float4 wreg[8];
    #pragma unroll
    for (int k = 0; k < 8; ++k)
      wreg[k] = *(const float4*)(W + (size_t)(kc * 8 + k) * 128 + 4 * tx);
    #pragma unroll
    for (int kk = 0; kk < 8; kk += 4) {
      float4 xreg[8];
      #pragma unroll
      for (int r = 0; r < 8; ++r)
        xreg[r] = *(const float4*)&Xs[cur][ty + 8 * r][kk];
      #pragma unroll
      for (int k = 0; k < 4; ++k) {
        #pragma unroll
        for (int r = 0; r < 8; ++r) {
          float xv = ((const float*)&xreg[r])[k];
          float4 wv = wreg[kk + k];
          acc[r].x += xv * wv.x; acc[r].y += xv * wv.y;
          acc[r].z += xv * wv.z; acc[r].w += xv * wv.w;
        }
      }
    }
    __syncthreads();
  }
  float4 bv = make_float4(0.f, 0.f, 0.f, 0.f);
  if (flags & 1) bv = ((const float4*)bias)[tx];
  #pragma unroll
  for (int r = 0; r < 8; ++r) {
    float4 v;
    v.x = acc[r].x + bv.x; v.y = acc[r].y + bv.y;
    v.z = acc[r].z + bv.z; v.w = acc[r].w + bv.w;
    if (flags & 2) {
      v.x = fmaxf(v.x, 0.f); v.y = fmaxf(v.y, 0.f);
      v.z = fmaxf(v.z, 0.f); v.w = fmaxf(v.w, 0.f);
    }
    *(float4*)(out + (size_t)(rowbase + ty + 8 * r) * HB + 4 * tx) = v;
  }
}

// ---- fused per-graph CSR build: LDS hist -> dis -> LDS scan -> LDS-cursor scatter ----
__global__ __launch_bounds__(1024) void csr_build_k(const int* __restrict__ row,
    const int* __restrict__ col, const int* __restrict__ goff,
    float* __restrict__ dis, int* __restrict__ off, int* __restrict__ srow,
    float* __restrict__ snorm, int n) {
  extern __shared__ int lds[];
  int* ldeg = lds;
  int* lsa  = lds + n;
  int* lsb  = lds + 2 * n;
  float* ldis = (float*)(lds + 3 * n);
  int g = blockIdx.x, tid = threadIdx.x;
  int e0 = goff[g], e1 = goff[g + 1];
  int base = g * n;
  for (int i = tid; i < n; i += 1024) ldeg[i] = 0;
  __syncthreads();
  for (int e = e0 + tid; e < e1; e += 1024) atomicAdd(&ldeg[col[e] - base], 1);
  __syncthreads();
  for (int i = tid; i < n; i += 1024) {
    int d = ldeg[i];
    ldis[i] = rsqrtf((float)d + 1.f);
    lsa[i] = d;
  }
  __syncthreads();
  int* src = lsa; int* dst = lsb;
  for (int o = 1; o < n; o <<= 1) {
    for (int i = tid; i < n; i += 1024) dst[i] = src[i] + ((i >= o) ? src[i - o] : 0);
    __syncthreads();
    int* t = src; src = dst; dst = t;
  }
  for (int i = tid; i < n; i += 1024) {
    int d = ldeg[i];
    int ex = src[i] - d;
    off[base + i] = e0 + ex;
    ldeg[i] = ex;
    dis[base + i] = ldis[i];
  }
  if (tid == 0) off[base + n] = e1;
  __syncthreads();
  for (int e = e0 + tid; e < e1; e += 1024) {
    int r = row[e], c = col[e];
    int lc = c - base;
    int p = e0 + atomicAdd(&ldeg[lc], 1);
    srow[p] = r;
    snorm[p] = ldis[r - base] * ldis[lc];
  }
}

// ---- layer-0: aggregate raw 7-channel X over CSR + self loop -> aggx[N][8] ----
__global__ __launch_bounds__(256) void agg7_k(const float* __restrict__ x,
    const int* __restrict__ srow, const float* __restrict__ snorm,
    const int* __restrict__ off, const float* __restrict__ dis,
    float* __restrict__ aggx, int N) {
  int gid = blockIdx.x * blockDim.x + threadIdx.x;
  int node = gid >> 3, c = gid & 7;
  if (node >= N) return;
  float acc = 0.f;
  if (c < 7) {
    int s = off[node], e = off[node + 1];
    for (int j = s; j < e; ++j) acc += x[(size_t)srow[j] * 7 + c] * snorm[j];
    float d = dis[node];
    acc += x[(size_t)node * 7 + c] * d * d;
  }
  aggx[(size_t)node * 8 + c] = acc;
}

// ---- CSR gather + self loop + bias (128-ch) ----
__global__ __launch_bounds__(256) void gather_combine_k(const float* __restrict__ hw,
    const int* __restrict__ srow, const float* __restrict__ snorm,
    const int* __restrict__ off, const float* __restrict__ dis,
    const float* __restrict__ bc, float* __restrict__ out, int N) {
  int gid = blockIdx.x * blockDim.x + threadIdx.x;
  int node = gid >> 5;
  if (node >= N) return;
  int ch = (gid & 31) * 4;
  int s = off[node], e = off[node + 1];
  float4 acc = make_float4(0.f, 0.f, 0.f, 0.f);
  for (int j = s; j < e; ++j) {
    int r = srow[j];
    float nm = snorm[j];
    float4 v = *(const float4*)(hw + (size_t)r * HB + ch);
    acc.x += v.x * nm; acc.y += v.y * nm; acc.z += v.z * nm; acc.w += v.w * nm;
  }
  float d = dis[node], d2 = d * d;
  float4 h = *(const float4*)(hw + (size_t)node * HB + ch);
  float4 b = *(const float4*)(bc + ch);
  acc.x += h.x * d2 + b.x; acc.y += h.y * d2 + b.y;
  acc.z += h.z * d2 + b.z; acc.w += h.w * d2 + b.w;
  *(float4*)(out + (size_t)node * HB + ch) = acc;
}

// ---- BN stats: per-channel sum & sumsq ----
__global__ __launch_bounds__(256) void bnstat_k(const float* __restrict__ h,
    float* __restrict__ stat, int N) {
  __shared__ float ls[256], lq[256];
  int tid = threadIdx.x, c = tid & 127;
  float s = 0.f, q = 0.f;
  for (long r = (long)blockIdx.x * 2 + (tid >> 7); r < N; r += (long)gridDim.x * 2) {
    float v = h[r * HB + c];
    s += v; q += v * v;
  }
  ls[tid] = s; lq[tid] = q;
  __syncthreads();
  if (tid < 128) {
    s = ls[tid] + ls[tid + 128];
    q = lq[tid] + lq[tid + 128];
    atomicAdd(&stat[c], s);
    atomicAdd(&stat[128 + c], q);
  }
}

__global__ __launch_bounds__(128) void bnfin_k(const float* __restrict__ stat,
    const float* __restrict__ g, const float* __restrict__ b,
    float* __restrict__ sc, int N) {
  int c = threadIdx.x;
  if (c < 128) {
    float mu = stat[c] / N, ms = stat[128 + c] / N;
    float var = ms - mu * mu;
    float a = g[c] * rsqrtf(var + 1e-5f);
    sc[c] = a;
    sc[128 + c] = b[c] - mu * a;
  }
}

// ---- BN apply (in place) + per-node dots with Ws1/Ws2 ----
__global__ __launch_bounds__(256) void bnapply_score_k(float* __restrict__ h,
    const float* __restrict__ sc, const float* __restrict__ w1,
    const float* __restrict__ w2, float* __restrict__ selfs,
    float* __restrict__ t2, int N) {
  int gid = blockIdx.x * blockDim.x + threadIdx.x;
  int node = gid >> 6;
  if (node >= N) return;
  int lane = gid & 63, c = lane * 2;
  float2 v = *(float2*)(h + (size_t)node * HB + c);
  v.x = v.x * sc[c] + sc[128 + c];
  v.y = v.y * sc[c + 1] + sc[128 + c + 1];
  *(float2*)(h + (size_t)node * HB + c) = v;
  float s1 = v.x * w1[c] + v.y * w1[c + 1];
  float s2 = v.x * w2[c] + v.y * w2[c + 1];
  #pragma unroll
  for (int off = 32; off > 0; off >>= 1) {
    s1 += __shfl_xor(s1, off);
    s2 += __shfl_xor(s2, off);
  }
  if (lane == 0) { selfs[node] = s1; t2[node] = s2; }
}

// ---- SAG score: selfs + CSR gather of t2 + bias ----
__global__ __launch_bounds__(256) void score_k(const float* __restrict__ selfs,
    const float* __restrict__ t2, const int* __restrict__ srow,
    const int* __restrict__ off, const float* __restrict__ bs,
    float* __restrict__ score, int N) {
  int i = blockIdx.x * blockDim.x + threadIdx.x;
  if (i >= N) return;
  float s = selfs[i] + bs[0];
  int e0 = off[i], e1 = off[i + 1];
  for (int j = e0; j < e1; ++j) s += t2[srow[j]];
  score[i] = s;
}

// ---- exact top-k by rank ----
__global__ __launch_bounds__(1024) void rank_topk_k(const float* __restrict__ score,
    int* __restrict__ inv, int* __restrict__ sel, float* __restrict__ scale,
    int n, int k) {
  extern __shared__ float ls[];
  int g = blockIdx.x, tid = threadIdx.x;
  const float* sg = score + (size_t)g * n;
  for (int i = tid; i < n; i += 1024) ls[i] = sg[i];
  __syncthreads();
  int i0 = tid, i1 = tid + 1024;
  bool h0 = i0 < n, h1 = i1 < n;
  float s0 = h0 ? ls[i0] : 0.f, s1 = h1 ? ls[i1] : 0.f;
  int r0 = 0, r1 = 0;
  for (int jb = 0; jb < n; jb += 4) {
    float4 v = *(const float4*)(ls + jb);
    r0 += (v.x > s0) || (v.x == s0 && (jb + 0) < i0);
    r0 += (v.y > s0) || (v.y == s0 && (jb + 1) < i0);
    r0 += (v.z > s0) || (v.z == s0 && (jb + 2) < i0);
    r0 += (v.w > s0) || (v.w == s0 && (jb + 3) < i0);
    r1 += (v.x > s1) || (v.x == s1 && (jb + 0) < i1);
    r1 += (v.y > s1) || (v.y == s1 && (jb + 1) < i1);
    r1 += (v.z > s1) || (v.z == s1 && (jb + 2) < i1);
    r1 += (v.w > s1) || (v.w == s1 && (jb + 3) < i1);
  }
  if (h0) {
    if (r0 < k) {
      inv[(size_t)g * n + i0] = g * k + r0;
      sel[(size_t)g * k + r0] = g * n + i0;
      scale[(size_t)g * k + r0] = tanhf(s0);
    } else inv[(size_t)g * n + i0] = -1;
  }
  if (h1) {
    if (r1 < k) {
      inv[(size_t)g * n + i1] = g * k + r1;
      sel[(size_t)g * k + r1] = g * n + i1;
      scale[(size_t)g * k + r1] = tanhf(s1);
    } else inv[(size_t)g * n + i1] = -1;
  }
}

// ---- gather kept rows ----
__global__ __launch_bounds__(256) void gather_x_k(const float* __restrict__ h,
    const int* __restrict__ sel, const float* __restrict__ scale,
    float* __restrict__ xout, int M) {
  int gid = blockIdx.x * blockDim.x + threadIdx.x;
  int r = gid >> 5;
  if (r >= M) return;
  int ch = (gid & 31) * 4;
  int old = sel[r];
  float sc = scale[r];
  float4 v = *(const float4*)(h + (size_t)old * HB + ch);
  v.x *= sc; v.y *= sc; v.z *= sc; v.w *= sc;
  *(float4*)(xout + (size_t)r * HB + ch) = v;
}

// ---- order-preserving compact: pass A (per-block count) ----
__global__ __launch_bounds__(256) void cmpA_k(const int* __restrict__ row,
    const int* __restrict__ col, const int* __restrict__ inv,
    const int* __restrict__ ecnt, int* __restrict__ bcnt) {
  int e = blockIdx.x * 256 + threadIdx.x;
  bool valid = false;
  if (e < *ecnt) {
    int nr = inv[row[e]], nc = inv[col[e]];
    valid = (nr >= 0) && (nc >= 0);
  }
  unsigned long long mask = __ballot(valid);
  __shared__ int ws[4];
  int lane = threadIdx.x & 63, wid = threadIdx.x >> 6;
  if (lane == 0) ws[wid] = __popcll(mask);
  __syncthreads();
  if (threadIdx.x == 0) bcnt[blockIdx.x] = ws[0] + ws[1] + ws[2] + ws[3];
}

// ---- pass B: exclusive scan of 4096 block counts ----
__global__ __launch_bounds__(1024) void cmpB_k(const int* __restrict__ bcnt,
    int* __restrict__ bbase, int* __restrict__ total) {
  __shared__ int s[1024];
  int tid = threadIdx.x;
  int v0 = bcnt[4 * tid], v1 = bcnt[4 * tid + 1];
  int v2 = bcnt[4 * tid + 2], v3 = bcnt[4 * tid + 3];
  int tsum = v0 + v1 + v2 + v3;
  s[tid] = tsum; __syncthreads();
  for (int o = 1; o < 1024; o <<= 1) {
    int t = (tid >= o) ? s[tid - o] : 0;
    __syncthreads();
    s[tid] += t;
    __syncthreads();
  }
  int base = s[tid] - tsum;
  bbase[4 * tid] = base;
  bbase[4 * tid + 1] = base + v0;
  bbase[4 * tid + 2] = base + v0 + v1;
  bbase[4 * tid + 3] = base + v0 + v1 + v2;
  if (tid == 1023) *total = s[1023];
}

// ---- pass C: scatter + per-graph histogram ----
__global__ __launch_bounds__(256) void cmpC_k(const int* __restrict__ row,
    const int* __restrict__ col, const int* __restrict__ inv,
    const int* __restrict__ ecnt, const int* __restrict__ bbase,
    int* __restrict__ nrow, int* __restrict__ ncol, int* __restrict__ gcnt,
    int khalf) {
  int e = blockIdx.x * 256 + threadIdx.x;
  bool valid = false; int nr = 0, nc = 0;
  if (e < *ecnt) {
    nr = inv[row[e]]; nc = inv[col[e]];
    valid = (nr >= 0) && (nc >= 0);
  }
  unsigned long long mask = __ballot(valid);
  int lane = threadIdx.x & 63, wid = threadIdx.x >> 6;
  __shared__ int ws[4];
  __shared__ int lg[NB];
  if (threadIdx.x < NB) lg[threadIdx.x] = 0;
  if (lane == 0) ws[wid] = __popcll(mask);
  __syncthreads();
  if (threadIdx.x == 0) {
    int a = ws[0], b = ws[1], c2 = ws[2];
    ws[0] = 0; ws[1] = a; ws[2] = a + b; ws[3] = a + b + c2;
  }
  __syncthreads();
  if (valid) {
    unsigned long long lt = ((unsigned long long)1 << lane) - 1;
    int pos = bbase[blockIdx.x] + ws[wid] + (int)__popcll(mask & lt);
    nrow[pos] = nr;
    ncol[pos] = nc;
    atomicAdd(&lg[nc / khalf], 1);
  }
  __syncthreads();
  if (threadIdx.x < NB && lg[threadIdx.x]) atomicAdd(&gcnt[threadIdx.x], lg[threadIdx.x]);
}

__global__ void gscan_k(const int* __restrict__ gcnt, int* __restrict__ goff) {
  if (threadIdx.x == 0) {
    int s = 0;
    for (int g = 0; g < NB; ++g) { goff[g] = s; s += gcnt[g]; }
    goff[NB] = s;
  }
}

// ---- final mean pool ----
__global__ __launch_bounds__(128) void pool_k(const float* __restrict__ x,
    float* __restrict__ out, int n) {
  int g = blockIdx.x, c = threadIdx.x;
  float s = 0.f;
  for (int r = 0; r < n; ++r) s += x[((size_t)g * n + r) * HB + c];
  out[g * HB + c] = s / n;
}

extern "C" void kernel_launch(void* const* d_in, const int* in_sizes, int n_in,
                              void* d_out, int out_size, void* d_ws, size_t ws_size,
                              hipStream_t stream) {
  const float* x_in = (const float*)d_in[0];
  const int*   ei   = (const int*)d_in[1];
  const float* Wc1  = (const float*)d_in[3];
  const float* Wc   = (const float*)d_in[4];
  const float* bc   = (const float*)d_in[5];
  const float* Wf   = (const float*)d_in[6];
  const float* bf   = (const float*)d_in[7];
  const float* bng  = (const float*)d_in[8];
  const float* bnb  = (const float*)d_in[9];
  const float* Ws1  = (const float*)d_in[10];
  const float* Ws2  = (const float*)d_in[11];
  const float* bs   = (const float*)d_in[12];

  const int N0 = 131072, E = NE;
  char* p = (char*)d_ws;
  auto alloc = [&](size_t bytes) -> char* {
    char* r = p; p += (bytes + 255) & ~(size_t)255; return r;
  };
  float* A    = (float*)alloc((size_t)N0 * HB * 4);
  float* Bb   = (float*)alloc((size_t)N0 * HB * 4);
  float* Cc   = (float*)alloc((size_t)(N0 / 2) * HB * 4);
  float* aggx = (float*)alloc((size_t)N0 * 8 * 4);
  int*   rowA = (int*)alloc((size_t)E * 4);
  int*   colA = (int*)alloc((size_t)E * 4);
  int*   rowB = (int*)alloc((size_t)E * 4);
  int*   colB = (int*)alloc((size_t)E * 4);
  float* dis  = (float*)alloc((size_t)N0 * 4);
  float* selfs= (float*)alloc((size_t)N0 * 4);
  float* t2v  = (float*)alloc((size_t)N0 * 4);
  float* score= (float*)alloc((size_t)N0 * 4);
  int*   inv  = (int*)alloc((size_t)N0 * 4);
  int*   off  = (int*)alloc((size_t)(N0 + 1) * 4);
  int*   sel  = (int*)alloc((size_t)(N0 / 2) * 4);
  float* scale= (float*)alloc((size_t)(N0 / 2) * 4);
  int*   bcnt = (int*)alloc((size_t)EG * 4);
  int*   bbase= (int*)alloc((size_t)EG * 4);
  int*   gcnt = (int*)alloc(NB * 4);
  int*   goffA= (int*)alloc((NB + 1) * 4);
  int*   goffB= (int*)alloc((NB + 1) * 4);
  float* stat = (float*)alloc(256 * 4);
  float* bnsc = (float*)alloc(256 * 4);

  init_edges_k<<<E / 256, 256, 0, stream>>>(ei, rowA, colA, E);
  init_goff_k<<<1, 128, 0, stream>>>(goffA, E / NB);

  int* rowCur = rowA; int* colCur = colA;
  int* rowNxt = rowB; int* colNxt = colB;
  int* goffCur = goffA; int* goffNxt = goffB;

  int n = 2048;
  const float* xcur = x_in;
  for (int i = 0; i < 4; ++i) {
    int N = NB * n, khalf = n >> 1;
    // CSR payload aliases the INACTIVE edge double-buffer (rowNxt/colNxt):
    // written by csr_build, read through score_k, then legitimately
    // overwritten by cmpC at layer end — strictly stream-ordered.
    int*   srow  = rowNxt;
    float* snorm = (float*)colNxt;
    // fused per-graph CSR build (LDS-only atomics)
    csr_build_k<<<NB, 1024, (size_t)16 * n, stream>>>(
        rowCur, colCur, goffCur, dis, off, srow, snorm, n);
    if (i == 0) {
      // aggregate raw 7-ch X, then small-K matmul (+conv bias)
      agg7_k<<<N / 32, 256, 0, stream>>>(x_in, srow, snorm, off, dis, aggx, N);
      matmulK_k<<<N / 32, 256, (size_t)7 * HB * 4, stream>>>(
          aggx, Wc1, bc, Bb, N, 7, 8, 1);
    } else {
      const float* W = Wc + (size_t)(i - 1) * HB * HB;
      gemm128_k<<<N / 64, 256, 0, stream>>>(xcur, W, nullptr, A, N, 0);
      gather_combine_k<<<N / 8, 256, 0, stream>>>(A, srow, snorm, off, dis,
                                                  bc + (size_t)i * HB, Bb, N);
    }
    // fc + relu
    gemm128_k<<<N / 64, 256, 0, stream>>>(
        Bb, Wf + (size_t)i * HB * HB, bf + (size_t)i * HB, A, N, 3);
    // batchnorm
    hipMemsetAsync(stat, 0, 256 * 4, stream);
    bnstat_k<<<512, 256, 0, stream>>>(A, stat, N);
    bnfin_k<<<1, 128, 0, stream>>>(stat, bng + (size_t)i * HB, bnb + (size_t)i * HB, bnsc, N);
    bnapply_score_k<<<N / 4, 256, 0, stream>>>(
        A, bnsc, Ws1 + (size_t)i * HB, Ws2 + (size_t)i * HB, selfs, t2v, N);
    score_k<<<(N + 255) / 256, 256, 0, stream>>>(selfs, t2v, srow, off, bs + i, score, N);
    rank_topk_k<<<NB, 1024, (size_t)n * 4, stream>>>(score, inv, sel, scale, n, khalf);
    gather_x_k<<<(NB * khalf) / 8, 256, 0, stream>>>(A, sel, scale, Cc, NB * khalf);
    if (i < 3) {
      cmpA_k<<<EG, 256, 0, stream>>>(rowCur, colCur, inv, goffCur + NB, bcnt);
      cmpB_k<<<1, 1024, 0, stream>>>(bcnt, bbase, goffNxt + NB);
      hipMemsetAsync(gcnt, 0, NB * 4, stream);
      cmpC_k<<<EG, 256, 0, stream>>>(rowCur, colCur, inv, goffCur + NB, bbase,
                                     rowNxt, colNxt, gcnt, khalf);
      gscan_k<<<1, 64, 0, stream>>>(gcnt, goffNxt);
      int* t;
      t = rowCur; rowCur = rowNxt; rowNxt = t;
      t = colCur; colCur = colNxt; colNxt = t;
      t = goffCur; goffCur = goffNxt; goffNxt = t;
    }
    xcur = Cc; n = khalf;
  }
  pool_k<<<NB, 128, 0, stream>>>(Cc, (float*)d_out, n);
}

// Round 7
// 813.442 us; speedup vs baseline: 4.6683x; 1.2059x over previous
//
#include <hip/hip_runtime.h>
#include <cstdint>

#define HB 128   // hidden size
#define NB 64    // graphs per batch
#define NE 1048576
#define EG (NE / 256)   // 4096 blocks for edge-sized kernels

// ---- init edge arrays ----
__global__ __launch_bounds__(256) void init_edges_k(const int* __restrict__ ei,
    int* __restrict__ row, int* __restrict__ col, int E) {
  int e = blockIdx.x * blockDim.x + threadIdx.x;
  if (e < E) { row[e] = ei[e]; col[e] = ei[E + e]; }
}

__global__ __launch_bounds__(128) void init_goff_k(int* __restrict__ goff, int epg) {
  int g = threadIdx.x;
  if (g <= NB) goff[g] = g * epg;
}

// ---- small-K matmul: out[N][128] = X[N][K(stride KS)] @ W[K][128] (+bias) ----
__global__ __launch_bounds__(256) void matmulK_k(const float* __restrict__ X,
    const float* __restrict__ W, const float* __restrict__ bias,
    float* __restrict__ out, int N, int K, int KS, int flags) {
  extern __shared__ float lw[];  // K*128 floats
  int tid = threadIdx.x;
  int nv = K * 32;
  for (int idx = tid; idx < nv; idx += 256)
    ((float4*)lw)[idx] = ((const float4*)W)[idx];
  __syncthreads();
  int tx = tid & 31, ty = tid >> 5;
  long rowbase = (long)blockIdx.x * 32;
  float acc[4][4] = {};
  const float* xp = X + (size_t)(rowbase + ty) * KS;
  for (int k = 0; k < K; ++k) {
    float4 wv = ((float4*)lw)[k * 32 + tx];
    #pragma unroll
    for (int rr = 0; rr < 4; ++rr) {
      float xv = xp[(size_t)rr * 8 * KS + k];
      acc[rr][0] += xv * wv.x; acc[rr][1] += xv * wv.y;
      acc[rr][2] += xv * wv.z; acc[rr][3] += xv * wv.w;
    }
  }
  float4 bv = make_float4(0.f, 0.f, 0.f, 0.f);
  if (flags & 1) bv = ((const float4*)bias)[tx];
  #pragma unroll
  for (int rr = 0; rr < 4; ++rr) {
    long r = rowbase + ty + rr * 8;
    float4 v;
    v.x = acc[rr][0] + bv.x; v.y = acc[rr][1] + bv.y;
    v.z = acc[rr][2] + bv.z; v.w = acc[rr][3] + bv.w;
    if (flags & 2) {
      v.x = fmaxf(v.x, 0.f); v.y = fmaxf(v.y, 0.f);
      v.z = fmaxf(v.z, 0.f); v.w = fmaxf(v.w, 0.f);
    }
    ((float4*)(out + (size_t)r * HB))[tx] = v;
  }
}

// ---- K=128 GEMM: out[N][128] = X[N][128] @ W[128][128] (+bias,relu) ----
__global__ __launch_bounds__(256) void gemm128_k(const float* __restrict__ X,
    const float* __restrict__ W, const float* __restrict__ bias,
    float* __restrict__ out, int N, int flags) {
  __shared__ float Xs[2][64][8];
  int tid = threadIdx.x;
  int tx = tid & 31;   // cols 4*tx .. 4*tx+3
  int ty = tid >> 5;   // rows ty + 8*r, r=0..7
  long rowbase = (long)blockIdx.x * 64;
  float4 acc[8];
  #pragma unroll
  for (int r = 0; r < 8; ++r) acc[r] = make_float4(0.f, 0.f, 0.f, 0.f);
  int lr = tid >> 1, lq = (tid & 1) * 4;
  if (tid < 128)
    *(float4*)&Xs[0][lr][lq] = *(const float4*)(X + (rowbase + lr) * 128 + lq);
  __syncthreads();
  for (int kc = 0; kc < 16; ++kc) {
    int cur = kc & 1;
    if (kc < 15 && tid < 128)
      *(float4*)&Xs[cur ^ 1][lr][lq] =
          *(const float4*)(X + (rowbase + lr) * 128 + (kc + 1) * 8 + lq);
    float4 wreg[8];
    #pragma unroll
    for (int k = 0; k < 8; ++k)
      wreg[k] = *(const float4*)(W + (size_t)(kc * 8 + k) * 128 + 4 * tx);
    #pragma unroll
    for (int kk = 0; kk < 8; kk += 4) {
      float4 xreg[8];
      #pragma unroll
      for (int r = 0; r < 8; ++r)
        xreg[r] = *(const float4*)&Xs[cur][ty + 8 * r][kk];
      #pragma unroll
      for (int k = 0; k < 4; ++k) {
        #pragma unroll
        for (int r = 0; r < 8; ++r) {
          float xv = ((const float*)&xreg[r])[k];
          float4 wv = wreg[kk + k];
          acc[r].x += xv * wv.x; acc[r].y += xv * wv.y;
          acc[r].z += xv * wv.z; acc[r].w += xv * wv.w;
        }
      }
    }
    __syncthreads();
  }
  float4 bv = make_float4(0.f, 0.f, 0.f, 0.f);
  if (flags & 1) bv = ((const float4*)bias)[tx];
  #pragma unroll
  for (int r = 0; r < 8; ++r) {
    float4 v;
    v.x = acc[r].x + bv.x; v.y = acc[r].y + bv.y;
    v.z = acc[r].z + bv.z; v.w = acc[r].w + bv.w;
    if (flags & 2) {
      v.x = fmaxf(v.x, 0.f); v.y = fmaxf(v.y, 0.f);
      v.z = fmaxf(v.z, 0.f); v.w = fmaxf(v.w, 0.f);
    }
    *(float4*)(out + (size_t)(rowbase + ty + 8 * r) * HB + 4 * tx) = v;
  }
}

// ---- fused per-graph CSR build: LDS hist -> dis -> LDS scan -> LDS-cursor scatter ----
__global__ __launch_bounds__(1024) void csr_build_k(const int* __restrict__ row,
    const int* __restrict__ col, const int* __restrict__ goff,
    float* __restrict__ dis, int* __restrict__ off, int* __restrict__ srow,
    float* __restrict__ snorm, int n) {
  extern __shared__ int lds[];
  int* ldeg = lds;
  int* lsa  = lds + n;
  int* lsb  = lds + 2 * n;
  float* ldis = (float*)(lds + 3 * n);
  int g = blockIdx.x, tid = threadIdx.x;
  int e0 = goff[g], e1 = goff[g + 1];
  int base = g * n;
  for (int i = tid; i < n; i += 1024) ldeg[i] = 0;
  __syncthreads();
  for (int e = e0 + tid; e < e1; e += 1024) atomicAdd(&ldeg[col[e] - base], 1);
  __syncthreads();
  for (int i = tid; i < n; i += 1024) {
    int d = ldeg[i];
    ldis[i] = rsqrtf((float)d + 1.f);
    lsa[i] = d;
  }
  __syncthreads();
  int* src = lsa; int* dst = lsb;
  for (int o = 1; o < n; o <<= 1) {
    for (int i = tid; i < n; i += 1024) dst[i] = src[i] + ((i >= o) ? src[i - o] : 0);
    __syncthreads();
    int* t = src; src = dst; dst = t;
  }
  for (int i = tid; i < n; i += 1024) {
    int d = ldeg[i];
    int ex = src[i] - d;
    off[base + i] = e0 + ex;
    ldeg[i] = ex;
    dis[base + i] = ldis[i];
  }
  if (tid == 0) off[base + n] = e1;
  __syncthreads();
  for (int e = e0 + tid; e < e1; e += 1024) {
    int r = row[e], c = col[e];
    int lc = c - base;
    int p = e0 + atomicAdd(&ldeg[lc], 1);
    srow[p] = r;
    snorm[p] = ldis[r - base] * ldis[lc];
  }
}

// ---- layer-0: aggregate raw 7-channel X over CSR + self loop -> aggx[N][8] ----
__global__ __launch_bounds__(256) void agg7_k(const float* __restrict__ x,
    const int* __restrict__ srow, const float* __restrict__ snorm,
    const int* __restrict__ off, const float* __restrict__ dis,
    float* __restrict__ aggx, int N) {
  int gid = blockIdx.x * blockDim.x + threadIdx.x;
  int node = gid >> 3, c = gid & 7;
  if (node >= N) return;
  float acc = 0.f;
  if (c < 7) {
    int s = off[node], e = off[node + 1];
    for (int j = s; j < e; ++j) acc += x[(size_t)srow[j] * 7 + c] * snorm[j];
    float d = dis[node];
    acc += x[(size_t)node * 7 + c] * d * d;
  }
  aggx[(size_t)node * 8 + c] = acc;
}

// ---- CSR gather + self loop + bias (128-ch) ----
__global__ __launch_bounds__(256) void gather_combine_k(const float* __restrict__ hw,
    const int* __restrict__ srow, const float* __restrict__ snorm,
    const int* __restrict__ off, const float* __restrict__ dis,
    const float* __restrict__ bc, float* __restrict__ out, int N) {
  int gid = blockIdx.x * blockDim.x + threadIdx.x;
  int node = gid >> 5;
  if (node >= N) return;
  int ch = (gid & 31) * 4;
  int s = off[node], e = off[node + 1];
  float4 acc = make_float4(0.f, 0.f, 0.f, 0.f);
  for (int j = s; j < e; ++j) {
    int r = srow[j];
    float nm = snorm[j];
    float4 v = *(const float4*)(hw + (size_t)r * HB + ch);
    acc.x += v.x * nm; acc.y += v.y * nm; acc.z += v.z * nm; acc.w += v.w * nm;
  }
  float d = dis[node], d2 = d * d;
  float4 h = *(const float4*)(hw + (size_t)node * HB + ch);
  float4 b = *(const float4*)(bc + ch);
  acc.x += h.x * d2 + b.x; acc.y += h.y * d2 + b.y;
  acc.z += h.z * d2 + b.z; acc.w += h.w * d2 + b.w;
  *(float4*)(out + (size_t)node * HB + ch) = acc;
}

// ---- BN stats: per-channel sum & sumsq ----
__global__ __launch_bounds__(256) void bnstat_k(const float* __restrict__ h,
    float* __restrict__ stat, int N) {
  __shared__ float ls[256], lq[256];
  int tid = threadIdx.x, c = tid & 127;
  float s = 0.f, q = 0.f;
  for (long r = (long)blockIdx.x * 2 + (tid >> 7); r < N; r += (long)gridDim.x * 2) {
    float v = h[r * HB + c];
    s += v; q += v * v;
  }
  ls[tid] = s; lq[tid] = q;
  __syncthreads();
  if (tid < 128) {
    s = ls[tid] + ls[tid + 128];
    q = lq[tid] + lq[tid + 128];
    atomicAdd(&stat[c], s);
    atomicAdd(&stat[128 + c], q);
  }
}

__global__ __launch_bounds__(128) void bnfin_k(const float* __restrict__ stat,
    const float* __restrict__ g, const float* __restrict__ b,
    float* __restrict__ sc, int N) {
  int c = threadIdx.x;
  if (c < 128) {
    float mu = stat[c] / N, ms = stat[128 + c] / N;
    float var = ms - mu * mu;
    float a = g[c] * rsqrtf(var + 1e-5f);
    sc[c] = a;
    sc[128 + c] = b[c] - mu * a;
  }
}

// ---- BN apply (in place) + per-node dots with Ws1/Ws2 ----
__global__ __launch_bounds__(256) void bnapply_score_k(float* __restrict__ h,
    const float* __restrict__ sc, const float* __restrict__ w1,
    const float* __restrict__ w2, float* __restrict__ selfs,
    float* __restrict__ t2, int N) {
  int gid = blockIdx.x * blockDim.x + threadIdx.x;
  int node = gid >> 6;
  if (node >= N) return;
  int lane = gid & 63, c = lane * 2;
  float2 v = *(float2*)(h + (size_t)node * HB + c);
  v.x = v.x * sc[c] + sc[128 + c];
  v.y = v.y * sc[c + 1] + sc[128 + c + 1];
  *(float2*)(h + (size_t)node * HB + c) = v;
  float s1 = v.x * w1[c] + v.y * w1[c + 1];
  float s2 = v.x * w2[c] + v.y * w2[c + 1];
  #pragma unroll
  for (int off = 32; off > 0; off >>= 1) {
    s1 += __shfl_xor(s1, off);
    s2 += __shfl_xor(s2, off);
  }
  if (lane == 0) { selfs[node] = s1; t2[node] = s2; }
}

// ---- SAG score: selfs + CSR gather of t2 + bias ----
__global__ __launch_bounds__(256) void score_k(const float* __restrict__ selfs,
    const float* __restrict__ t2, const int* __restrict__ srow,
    const int* __restrict__ off, const float* __restrict__ bs,
    float* __restrict__ score, int N) {
  int i = blockIdx.x * blockDim.x + threadIdx.x;
  if (i >= N) return;
  float s = selfs[i] + bs[0];
  int e0 = off[i], e1 = off[i + 1];
  for (int j = e0; j < e1; ++j) s += t2[srow[j]];
  score[i] = s;
}

// ---- exact top-k by rank; bpg blocks per graph, 256 threads, 1 elem/thread ----
__global__ __launch_bounds__(256) void rank_topk_k(const float* __restrict__ score,
    int* __restrict__ inv, int* __restrict__ sel, float* __restrict__ scale,
    int n, int k, int bpg) {
  extern __shared__ float ls[];  // n floats
  int g = blockIdx.x / bpg, sub = blockIdx.x % bpg;
  int tid = threadIdx.x;
  const float* sg = score + (size_t)g * n;
  for (int i = tid; i < n; i += 256) ls[i] = sg[i];
  __syncthreads();
  int i0 = sub * 256 + tid;           // this thread's element
  float s0 = ls[i0];
  int r0 = 0;
  for (int jb = 0; jb < n; jb += 4) {
    float4 v = *(const float4*)(ls + jb);
    r0 += (v.x > s0) || (v.x == s0 && (jb + 0) < i0);
    r0 += (v.y > s0) || (v.y == s0 && (jb + 1) < i0);
    r0 += (v.z > s0) || (v.z == s0 && (jb + 2) < i0);
    r0 += (v.w > s0) || (v.w == s0 && (jb + 3) < i0);
  }
  if (r0 < k) {
    inv[(size_t)g * n + i0] = g * k + r0;
    sel[(size_t)g * k + r0] = g * n + i0;
    scale[(size_t)g * k + r0] = tanhf(s0);
  } else inv[(size_t)g * n + i0] = -1;
}

// ---- gather kept rows ----
__global__ __launch_bounds__(256) void gather_x_k(const float* __restrict__ h,
    const int* __restrict__ sel, const float* __restrict__ scale,
    float* __restrict__ xout, int M) {
  int gid = blockIdx.x * blockDim.x + threadIdx.x;
  int r = gid >> 5;
  if (r >= M) return;
  int ch = (gid & 31) * 4;
  int old = sel[r];
  float sc = scale[r];
  float4 v = *(const float4*)(h + (size_t)old * HB + ch);
  v.x *= sc; v.y *= sc; v.z *= sc; v.w *= sc;
  *(float4*)(xout + (size_t)r * HB + ch) = v;
}

// ---- order-preserving compact: pass A (per-block count) ----
__global__ __launch_bounds__(256) void cmpA_k(const int* __restrict__ row,
    const int* __restrict__ col, const int* __restrict__ inv,
    const int* __restrict__ ecnt, int* __restrict__ bcnt) {
  int e = blockIdx.x * 256 + threadIdx.x;
  bool valid = false;
  if (e < *ecnt) {
    int nr = inv[row[e]], nc = inv[col[e]];
    valid = (nr >= 0) && (nc >= 0);
  }
  unsigned long long mask = __ballot(valid);
  __shared__ int ws[4];
  int lane = threadIdx.x & 63, wid = threadIdx.x >> 6;
  if (lane == 0) ws[wid] = __popcll(mask);
  __syncthreads();
  if (threadIdx.x == 0) bcnt[blockIdx.x] = ws[0] + ws[1] + ws[2] + ws[3];
}

// ---- pass B: exclusive scan of 4096 block counts ----
__global__ __launch_bounds__(1024) void cmpB_k(const int* __restrict__ bcnt,
    int* __restrict__ bbase, int* __restrict__ total) {
  __shared__ int s[1024];
  int tid = threadIdx.x;
  int v0 = bcnt[4 * tid], v1 = bcnt[4 * tid + 1];
  int v2 = bcnt[4 * tid + 2], v3 = bcnt[4 * tid + 3];
  int tsum = v0 + v1 + v2 + v3;
  s[tid] = tsum; __syncthreads();
  for (int o = 1; o < 1024; o <<= 1) {
    int t = (tid >= o) ? s[tid - o] : 0;
    __syncthreads();
    s[tid] += t;
    __syncthreads();
  }
  int base = s[tid] - tsum;
  bbase[4 * tid] = base;
  bbase[4 * tid + 1] = base + v0;
  bbase[4 * tid + 2] = base + v0 + v1;
  bbase[4 * tid + 3] = base + v0 + v1 + v2;
  if (tid == 1023) *total = s[1023];
}

// ---- pass C: scatter + per-graph histogram ----
__global__ __launch_bounds__(256) void cmpC_k(const int* __restrict__ row,
    const int* __restrict__ col, const int* __restrict__ inv,
    const int* __restrict__ ecnt, const int* __restrict__ bbase,
    int* __restrict__ nrow, int* __restrict__ ncol, int* __restrict__ gcnt,
    int khalf) {
  int e = blockIdx.x * 256 + threadIdx.x;
  bool valid = false; int nr = 0, nc = 0;
  if (e < *ecnt) {
    nr = inv[row[e]]; nc = inv[col[e]];
    valid = (nr >= 0) && (nc >= 0);
  }
  unsigned long long mask = __ballot(valid);
  int lane = threadIdx.x & 63, wid = threadIdx.x >> 6;
  __shared__ int ws[4];
  __shared__ int lg[NB];
  if (threadIdx.x < NB) lg[threadIdx.x] = 0;
  if (lane == 0) ws[wid] = __popcll(mask);
  __syncthreads();
  if (threadIdx.x == 0) {
    int a = ws[0], b = ws[1], c2 = ws[2];
    ws[0] = 0; ws[1] = a; ws[2] = a + b; ws[3] = a + b + c2;
  }
  __syncthreads();
  if (valid) {
    unsigned long long lt = ((unsigned long long)1 << lane) - 1;
    int pos = bbase[blockIdx.x] + ws[wid] + (int)__popcll(mask & lt);
    nrow[pos] = nr;
    ncol[pos] = nc;
    atomicAdd(&lg[nc / khalf], 1);
  }
  __syncthreads();
  if (threadIdx.x < NB && lg[threadIdx.x]) atomicAdd(&gcnt[threadIdx.x], lg[threadIdx.x]);
}

__global__ void gscan_k(const int* __restrict__ gcnt, int* __restrict__ goff) {
  if (threadIdx.x == 0) {
    int s = 0;
    for (int g = 0; g < NB; ++g) { goff[g] = s; s += gcnt[g]; }
    goff[NB] = s;
  }
}

// ---- final mean pool ----
__global__ __launch_bounds__(128) void pool_k(const float* __restrict__ x,
    float* __restrict__ out, int n) {
  int g = blockIdx.x, c = threadIdx.x;
  float s = 0.f;
  for (int r = 0; r < n; ++r) s += x[((size_t)g * n + r) * HB + c];
  out[g * HB + c] = s / n;
}

extern "C" void kernel_launch(void* const* d_in, const int* in_sizes, int n_in,
                              void* d_out, int out_size, void* d_ws, size_t ws_size,
                              hipStream_t stream) {
  const float* x_in = (const float*)d_in[0];
  const int*   ei   = (const int*)d_in[1];
  const float* Wc1  = (const float*)d_in[3];
  const float* Wc   = (const float*)d_in[4];
  const float* bc   = (const float*)d_in[5];
  const float* Wf   = (const float*)d_in[6];
  const float* bf   = (const float*)d_in[7];
  const float* bng  = (const float*)d_in[8];
  const float* bnb  = (const float*)d_in[9];
  const float* Ws1  = (const float*)d_in[10];
  const float* Ws2  = (const float*)d_in[11];
  const float* bs   = (const float*)d_in[12];

  const int N0 = 131072, E = NE;
  char* p = (char*)d_ws;
  auto alloc = [&](size_t bytes) -> char* {
    char* r = p; p += (bytes + 255) & ~(size_t)255; return r;
  };
  float* A    = (float*)alloc((size_t)N0 * HB * 4);
  float* Bb   = (float*)alloc((size_t)N0 * HB * 4);
  float* Cc   = (float*)alloc((size_t)(N0 / 2) * HB * 4);
  float* aggx = (float*)alloc((size_t)N0 * 8 * 4);
  int*   rowA = (int*)alloc((size_t)E * 4);
  int*   colA = (int*)alloc((size_t)E * 4);
  int*   rowB = (int*)alloc((size_t)E * 4);
  int*   colB = (int*)alloc((size_t)E * 4);
  float* dis  = (float*)alloc((size_t)N0 * 4);
  float* selfs= (float*)alloc((size_t)N0 * 4);
  float* t2v  = (float*)alloc((size_t)N0 * 4);
  float* score= (float*)alloc((size_t)N0 * 4);
  int*   inv  = (int*)alloc((size_t)N0 * 4);
  int*   off  = (int*)alloc((size_t)(N0 + 1) * 4);
  int*   sel  = (int*)alloc((size_t)(N0 / 2) * 4);
  float* scale= (float*)alloc((size_t)(N0 / 2) * 4);
  int*   bcnt = (int*)alloc((size_t)EG * 4);
  int*   bbase= (int*)alloc((size_t)EG * 4);
  int*   gcnt = (int*)alloc(NB * 4);
  int*   goffA= (int*)alloc((NB + 1) * 4);
  int*   goffB= (int*)alloc((NB + 1) * 4);
  float* stat = (float*)alloc(256 * 4);
  float* bnsc = (float*)alloc(256 * 4);

  init_edges_k<<<E / 256, 256, 0, stream>>>(ei, rowA, colA, E);
  init_goff_k<<<1, 128, 0, stream>>>(goffA, E / NB);

  int* rowCur = rowA; int* colCur = colA;
  int* rowNxt = rowB; int* colNxt = colB;
  int* goffCur = goffA; int* goffNxt = goffB;

  int n = 2048;
  const float* xcur = x_in;
  for (int i = 0; i < 4; ++i) {
    int N = NB * n, khalf = n >> 1;
    // CSR payload aliases the INACTIVE edge double-buffer (rowNxt/colNxt):
    // written by csr_build, read through score_k, then legitimately
    // overwritten by cmpC at layer end — strictly stream-ordered.
    int*   srow  = rowNxt;
    float* snorm = (float*)colNxt;
    // fused per-graph CSR build (LDS-only atomics)
    csr_build_k<<<NB, 1024, (size_t)16 * n, stream>>>(
        rowCur, colCur, goffCur, dis, off, srow, snorm, n);
    if (i == 0) {
      // aggregate raw 7-ch X, then small-K matmul (+conv bias)
      agg7_k<<<N / 32, 256, 0, stream>>>(x_in, srow, snorm, off, dis, aggx, N);
      matmulK_k<<<N / 32, 256, (size_t)7 * HB * 4, stream>>>(
          aggx, Wc1, bc, Bb, N, 7, 8, 1);
    } else {
      const float* W = Wc + (size_t)(i - 1) * HB * HB;
      gemm128_k<<<N / 64, 256, 0, stream>>>(xcur, W, nullptr, A, N, 0);
      gather_combine_k<<<N / 8, 256, 0, stream>>>(A, srow, snorm, off, dis,
                                                  bc + (size_t)i * HB, Bb, N);
    }
    // fc + relu
    gemm128_k<<<N / 64, 256, 0, stream>>>(
        Bb, Wf + (size_t)i * HB * HB, bf + (size_t)i * HB, A, N, 3);
    // batchnorm
    hipMemsetAsync(stat, 0, 256 * 4, stream);
    bnstat_k<<<512, 256, 0, stream>>>(A, stat, N);
    bnfin_k<<<1, 128, 0, stream>>>(stat, bng + (size_t)i * HB, bnb + (size_t)i * HB, bnsc, N);
    bnapply_score_k<<<N / 4, 256, 0, stream>>>(
        A, bnsc, Ws1 + (size_t)i * HB, Ws2 + (size_t)i * HB, selfs, t2v, N);
    score_k<<<(N + 255) / 256, 256, 0, stream>>>(selfs, t2v, srow, off, bs + i, score, N);
    // exact top-k by rank: bpg blocks/graph, 256 thr, 1 elem/thread
    int bpg = n / 256;
    rank_topk_k<<<NB * bpg, 256, (size_t)n * 4, stream>>>(
        score, inv, sel, scale, n, khalf, bpg);
    gather_x_k<<<(NB * khalf) / 8, 256, 0, stream>>>(A, sel, scale, Cc, NB * khalf);
    if (i < 3) {
      cmpA_k<<<EG, 256, 0, stream>>>(rowCur, colCur, inv, goffCur + NB, bcnt);
      cmpB_k<<<1, 1024, 0, stream>>>(bcnt, bbase, goffNxt + NB);
      hipMemsetAsync(gcnt, 0, NB * 4, stream);
      cmpC_k<<<EG, 256, 0, stream>>>(rowCur, colCur, inv, goffCur + NB, bbase,
                                     rowNxt, colNxt, gcnt, khalf);
      gscan_k<<<1, 64, 0, stream>>>(gcnt, goffNxt);
      int* t;
      t = rowCur; rowCur = rowNxt; rowNxt = t;
      t = colCur; colCur = colNxt; colNxt = t;
      t = goffCur; goffCur = goffNxt; goffNxt = t;
    }
    xcur = Cc; n = khalf;
  }
  pool_k<<<NB, 128, 0, stream>>>(Cc, (float*)d_out, n);
}

// Round 8
// 803.835 us; speedup vs baseline: 4.7241x; 1.0120x over previous
//
#include <hip/hip_runtime.h>
#include <cstdint>

#define HB 128   // hidden size
#define NB 64    // graphs per batch
#define NE 1048576
#define EG (NE / 256)   // 4096 blocks for edge-sized kernels

// ---- init edge arrays ----
__global__ __launch_bounds__(256) void init_edges_k(const int* __restrict__ ei,
    int* __restrict__ row, int* __restrict__ col, int E) {
  int e = blockIdx.x * blockDim.x + threadIdx.x;
  if (e < E) { row[e] = ei[e]; col[e] = ei[E + e]; }
}

__global__ __launch_bounds__(128) void init_goff_k(int* __restrict__ goff, int epg) {
  int g = threadIdx.x;
  if (g <= NB) goff[g] = g * epg;
}

// ---- small-K matmul: out[N][128] = X[N][K(stride KS)] @ W[K][128] (+bias) ----
__global__ __launch_bounds__(256) void matmulK_k(const float* __restrict__ X,
    const float* __restrict__ W, const float* __restrict__ bias,
    float* __restrict__ out, int N, int K, int KS, int flags) {
  extern __shared__ float lw[];  // K*128 floats
  int tid = threadIdx.x;
  int nv = K * 32;
  for (int idx = tid; idx < nv; idx += 256)
    ((float4*)lw)[idx] = ((const float4*)W)[idx];
  __syncthreads();
  int tx = tid & 31, ty = tid >> 5;
  long rowbase = (long)blockIdx.x * 32;
  float acc[4][4] = {};
  const float* xp = X + (size_t)(rowbase + ty) * KS;
  for (int k = 0; k < K; ++k) {
    float4 wv = ((float4*)lw)[k * 32 + tx];
    #pragma unroll
    for (int rr = 0; rr < 4; ++rr) {
      float xv = xp[(size_t)rr * 8 * KS + k];
      acc[rr][0] += xv * wv.x; acc[rr][1] += xv * wv.y;
      acc[rr][2] += xv * wv.z; acc[rr][3] += xv * wv.w;
    }
  }
  float4 bv = make_float4(0.f, 0.f, 0.f, 0.f);
  if (flags & 1) bv = ((const float4*)bias)[tx];
  #pragma unroll
  for (int rr = 0; rr < 4; ++rr) {
    long r = rowbase + ty + rr * 8;
    float4 v;
    v.x = acc[rr][0] + bv.x; v.y = acc[rr][1] + bv.y;
    v.z = acc[rr][2] + bv.z; v.w = acc[rr][3] + bv.w;
    if (flags & 2) {
      v.x = fmaxf(v.x, 0.f); v.y = fmaxf(v.y, 0.f);
      v.z = fmaxf(v.z, 0.f); v.w = fmaxf(v.w, 0.f);
    }
    ((float4*)(out + (size_t)r * HB))[tx] = v;
  }
}

// ---- K=128 GEMM v2: 128x128 tile, 8x8 per thread, optional fused SAG gather ----
// flags: bit0 bias, bit1 relu, bit2 gather (X row = X[sel[r]] * scale[r])
__global__ __launch_bounds__(256) void gemm128v2_k(const float* __restrict__ X,
    const float* __restrict__ W, const float* __restrict__ bias,
    float* __restrict__ out, int N, int flags,
    const int* __restrict__ sel, const float* __restrict__ scale) {
  __shared__ float Xs[2][128][8];
  int tid = threadIdx.x;
  int tx = tid & 15;          // col octet: cols 8*tx .. 8*tx+7
  int ty = tid >> 4;          // 0..15; rows ty + 16*r
  long rowbase = (long)blockIdx.x * 128;
  // loader thread: one float4 per kc
  int lr = tid >> 1;
  int lq = (tid & 1) * 4;
  long srcrow = rowbase + lr;
  float lsc = 1.f;
  if (flags & 4) { srcrow = sel[rowbase + lr]; lsc = scale[rowbase + lr]; }
  const float* xrow = X + (size_t)srcrow * HB + lq;
  float4 acc[8][2];
  #pragma unroll
  for (int r = 0; r < 8; ++r) {
    acc[r][0] = make_float4(0.f, 0.f, 0.f, 0.f);
    acc[r][1] = make_float4(0.f, 0.f, 0.f, 0.f);
  }
  {
    float4 v = *(const float4*)xrow;
    v.x *= lsc; v.y *= lsc; v.z *= lsc; v.w *= lsc;
    *(float4*)&Xs[0][lr][lq] = v;
  }
  __syncthreads();
  for (int kc = 0; kc < 16; ++kc) {
    int cur = kc & 1;
    if (kc < 15) {
      float4 v = *(const float4*)(xrow + (kc + 1) * 8);
      v.x *= lsc; v.y *= lsc; v.z *= lsc; v.w *= lsc;
      *(float4*)&Xs[cur ^ 1][lr][lq] = v;
    }
    #pragma unroll
    for (int kk = 0; kk < 8; kk += 4) {
      float4 wreg[4][2];
      #pragma unroll
      for (int k2 = 0; k2 < 4; ++k2) {
        const float* wp = W + (size_t)(kc * 8 + kk + k2) * HB + 8 * tx;
        wreg[k2][0] = *(const float4*)wp;
        wreg[k2][1] = *(const float4*)(wp + 4);
      }
      float4 xreg[8];
      #pragma unroll
      for (int r = 0; r < 8; ++r)
        xreg[r] = *(const float4*)&Xs[cur][ty + 16 * r][kk];
      #pragma unroll
      for (int k2 = 0; k2 < 4; ++k2) {
        #pragma unroll
        for (int r = 0; r < 8; ++r) {
          float xv = ((const float*)&xreg[r])[k2];
          acc[r][0].x += xv * wreg[k2][0].x; acc[r][0].y += xv * wreg[k2][0].y;
          acc[r][0].z += xv * wreg[k2][0].z; acc[r][0].w += xv * wreg[k2][0].w;
          acc[r][1].x += xv * wreg[k2][1].x; acc[r][1].y += xv * wreg[k2][1].y;
          acc[r][1].z += xv * wreg[k2][1].z; acc[r][1].w += xv * wreg[k2][1].w;
        }
      }
    }
    __syncthreads();
  }
  float4 bv0 = make_float4(0.f, 0.f, 0.f, 0.f), bv1 = bv0;
  if (flags & 1) {
    bv0 = ((const float4*)bias)[2 * tx];
    bv1 = ((const float4*)bias)[2 * tx + 1];
  }
  #pragma unroll
  for (int r = 0; r < 8; ++r) {
    float4 v0, v1;
    v0.x = acc[r][0].x + bv0.x; v0.y = acc[r][0].y + bv0.y;
    v0.z = acc[r][0].z + bv0.z; v0.w = acc[r][0].w + bv0.w;
    v1.x = acc[r][1].x + bv1.x; v1.y = acc[r][1].y + bv1.y;
    v1.z = acc[r][1].z + bv1.z; v1.w = acc[r][1].w + bv1.w;
    if (flags & 2) {
      v0.x = fmaxf(v0.x, 0.f); v0.y = fmaxf(v0.y, 0.f);
      v0.z = fmaxf(v0.z, 0.f); v0.w = fmaxf(v0.w, 0.f);
      v1.x = fmaxf(v1.x, 0.f); v1.y = fmaxf(v1.y, 0.f);
      v1.z = fmaxf(v1.z, 0.f); v1.w = fmaxf(v1.w, 0.f);
    }
    float* op = out + (size_t)(rowbase + ty + 16 * r) * HB + 8 * tx;
    *(float4*)op = v0;
    *(float4*)(op + 4) = v1;
  }
}

// ---- fused per-graph CSR build: LDS hist -> dis -> LDS scan -> LDS-cursor scatter ----
__global__ __launch_bounds__(1024) void csr_build_k(const int* __restrict__ row,
    const int* __restrict__ col, const int* __restrict__ goff,
    float* __restrict__ dis, int* __restrict__ off, int* __restrict__ srow,
    float* __restrict__ snorm, int n) {
  extern __shared__ int lds[];
  int* ldeg = lds;
  int* lsa  = lds + n;
  int* lsb  = lds + 2 * n;
  float* ldis = (float*)(lds + 3 * n);
  int g = blockIdx.x, tid = threadIdx.x;
  int e0 = goff[g], e1 = goff[g + 1];
  int base = g * n;
  for (int i = tid; i < n; i += 1024) ldeg[i] = 0;
  __syncthreads();
  for (int e = e0 + tid; e < e1; e += 1024) atomicAdd(&ldeg[col[e] - base], 1);
  __syncthreads();
  for (int i = tid; i < n; i += 1024) {
    int d = ldeg[i];
    ldis[i] = rsqrtf((float)d + 1.f);
    lsa[i] = d;
  }
  __syncthreads();
  int* src = lsa; int* dst = lsb;
  for (int o = 1; o < n; o <<= 1) {
    for (int i = tid; i < n; i += 1024) dst[i] = src[i] + ((i >= o) ? src[i - o] : 0);
    __syncthreads();
    int* t = src; src = dst; dst = t;
  }
  for (int i = tid; i < n; i += 1024) {
    int d = ldeg[i];
    int ex = src[i] - d;
    off[base + i] = e0 + ex;
    ldeg[i] = ex;
    dis[base + i] = ldis[i];
  }
  if (tid == 0) off[base + n] = e1;
  __syncthreads();
  for (int e = e0 + tid; e < e1; e += 1024) {
    int r = row[e], c = col[e];
    int lc = c - base;
    int p = e0 + atomicAdd(&ldeg[lc], 1);
    srow[p] = r;
    snorm[p] = ldis[r - base] * ldis[lc];
  }
}

// ---- layer-0: aggregate raw 7-channel X over CSR + self loop -> aggx[N][8] ----
__global__ __launch_bounds__(256) void agg7_k(const float* __restrict__ x,
    const int* __restrict__ srow, const float* __restrict__ snorm,
    const int* __restrict__ off, const float* __restrict__ dis,
    float* __restrict__ aggx, int N) {
  int gid = blockIdx.x * blockDim.x + threadIdx.x;
  int node = gid >> 3, c = gid & 7;
  if (node >= N) return;
  float acc = 0.f;
  if (c < 7) {
    int s = off[node], e = off[node + 1];
    for (int j = s; j < e; ++j) acc += x[(size_t)srow[j] * 7 + c] * snorm[j];
    float d = dis[node];
    acc += x[(size_t)node * 7 + c] * d * d;
  }
  aggx[(size_t)node * 8 + c] = acc;
}

// ---- CSR gather + self loop + bias (128-ch) ----
__global__ __launch_bounds__(256) void gather_combine_k(const float* __restrict__ hw,
    const int* __restrict__ srow, const float* __restrict__ snorm,
    const int* __restrict__ off, const float* __restrict__ dis,
    const float* __restrict__ bc, float* __restrict__ out, int N) {
  int gid = blockIdx.x * blockDim.x + threadIdx.x;
  int node = gid >> 5;
  if (node >= N) return;
  int ch = (gid & 31) * 4;
  int s = off[node], e = off[node + 1];
  float4 acc = make_float4(0.f, 0.f, 0.f, 0.f);
  for (int j = s; j < e; ++j) {
    int r = srow[j];
    float nm = snorm[j];
    float4 v = *(const float4*)(hw + (size_t)r * HB + ch);
    acc.x += v.x * nm; acc.y += v.y * nm; acc.z += v.z * nm; acc.w += v.w * nm;
  }
  float d = dis[node], d2 = d * d;
  float4 h = *(const float4*)(hw + (size_t)node * HB + ch);
  float4 b = *(const float4*)(bc + ch);
  acc.x += h.x * d2 + b.x; acc.y += h.y * d2 + b.y;
  acc.z += h.z * d2 + b.z; acc.w += h.w * d2 + b.w;
  *(float4*)(out + (size_t)node * HB + ch) = acc;
}

// ---- BN stats: per-channel sum & sumsq ----
__global__ __launch_bounds__(256) void bnstat_k(const float* __restrict__ h,
    float* __restrict__ stat, int N) {
  __shared__ float ls[256], lq[256];
  int tid = threadIdx.x, c = tid & 127;
  float s = 0.f, q = 0.f;
  for (long r = (long)blockIdx.x * 2 + (tid >> 7); r < N; r += (long)gridDim.x * 2) {
    float v = h[r * HB + c];
    s += v; q += v * v;
  }
  ls[tid] = s; lq[tid] = q;
  __syncthreads();
  if (tid < 128) {
    s = ls[tid] + ls[tid + 128];
    q = lq[tid] + lq[tid + 128];
    atomicAdd(&stat[c], s);
    atomicAdd(&stat[128 + c], q);
  }
}

// ---- BN finalize (also re-zeros stat for the next layer) ----
__global__ __launch_bounds__(128) void bnfin_k(float* __restrict__ stat,
    const float* __restrict__ g, const float* __restrict__ b,
    float* __restrict__ sc, int N) {
  int c = threadIdx.x;
  if (c < 128) {
    float mu = stat[c] / N, ms = stat[128 + c] / N;
    float var = ms - mu * mu;
    float a = g[c] * rsqrtf(var + 1e-5f);
    sc[c] = a;
    sc[128 + c] = b[c] - mu * a;
    stat[c] = 0.f;
    stat[128 + c] = 0.f;
  }
}

// ---- BN apply (in place) + per-node dots with Ws1/Ws2 ----
__global__ __launch_bounds__(256) void bnapply_score_k(float* __restrict__ h,
    const float* __restrict__ sc, const float* __restrict__ w1,
    const float* __restrict__ w2, float* __restrict__ selfs,
    float* __restrict__ t2, int N) {
  int gid = blockIdx.x * blockDim.x + threadIdx.x;
  int node = gid >> 6;
  if (node >= N) return;
  int lane = gid & 63, c = lane * 2;
  float2 v = *(float2*)(h + (size_t)node * HB + c);
  v.x = v.x * sc[c] + sc[128 + c];
  v.y = v.y * sc[c + 1] + sc[128 + c + 1];
  *(float2*)(h + (size_t)node * HB + c) = v;
  float s1 = v.x * w1[c] + v.y * w1[c + 1];
  float s2 = v.x * w2[c] + v.y * w2[c + 1];
  #pragma unroll
  for (int off = 32; off > 0; off >>= 1) {
    s1 += __shfl_xor(s1, off);
    s2 += __shfl_xor(s2, off);
  }
  if (lane == 0) { selfs[node] = s1; t2[node] = s2; }
}

// ---- SAG score: selfs + CSR gather of t2 + bias ----
__global__ __launch_bounds__(256) void score_k(const float* __restrict__ selfs,
    const float* __restrict__ t2, const int* __restrict__ srow,
    const int* __restrict__ off, const float* __restrict__ bs,
    float* __restrict__ score, int N) {
  int i = blockIdx.x * blockDim.x + threadIdx.x;
  if (i >= N) return;
  float s = selfs[i] + bs[0];
  int e0 = off[i], e1 = off[i + 1];
  for (int j = e0; j < e1; ++j) s += t2[srow[j]];
  score[i] = s;
}

// ---- exact top-k by rank; bpg blocks per graph, 256 threads, 1 elem/thread ----
__global__ __launch_bounds__(256) void rank_topk_k(const float* __restrict__ score,
    int* __restrict__ inv, int* __restrict__ sel, float* __restrict__ scale,
    int n, int k, int bpg) {
  extern __shared__ float ls[];  // n floats
  int g = blockIdx.x / bpg, sub = blockIdx.x % bpg;
  int tid = threadIdx.x;
  const float* sg = score + (size_t)g * n;
  for (int i = tid; i < n; i += 256) ls[i] = sg[i];
  __syncthreads();
  int i0 = sub * 256 + tid;
  float s0 = ls[i0];
  int r0 = 0;
  for (int jb = 0; jb < n; jb += 4) {
    float4 v = *(const float4*)(ls + jb);
    r0 += (v.x > s0) || (v.x == s0 && (jb + 0) < i0);
    r0 += (v.y > s0) || (v.y == s0 && (jb + 1) < i0);
    r0 += (v.z > s0) || (v.z == s0 && (jb + 2) < i0);
    r0 += (v.w > s0) || (v.w == s0 && (jb + 3) < i0);
  }
  if (r0 < k) {
    inv[(size_t)g * n + i0] = g * k + r0;
    sel[(size_t)g * k + r0] = g * n + i0;
    scale[(size_t)g * k + r0] = tanhf(s0);
  } else inv[(size_t)g * n + i0] = -1;
}

// ---- gather kept rows (only used for the final layer -> pool input) ----
__global__ __launch_bounds__(256) void gather_x_k(const float* __restrict__ h,
    const int* __restrict__ sel, const float* __restrict__ scale,
    float* __restrict__ xout, int M) {
  int gid = blockIdx.x * blockDim.x + threadIdx.x;
  int r = gid >> 5;
  if (r >= M) return;
  int ch = (gid & 31) * 4;
  int old = sel[r];
  float sc = scale[r];
  float4 v = *(const float4*)(h + (size_t)old * HB + ch);
  v.x *= sc; v.y *= sc; v.z *= sc; v.w *= sc;
  *(float4*)(xout + (size_t)r * HB + ch) = v;
}

// ---- order-preserving compact: pass A (per-block count) ----
__global__ __launch_bounds__(256) void cmpA_k(const int* __restrict__ row,
    const int* __restrict__ col, const int* __restrict__ inv,
    const int* __restrict__ ecnt, int* __restrict__ bcnt) {
  int e = blockIdx.x * 256 + threadIdx.x;
  bool valid = false;
  if (e < *ecnt) {
    int nr = inv[row[e]], nc = inv[col[e]];
    valid = (nr >= 0) && (nc >= 0);
  }
  unsigned long long mask = __ballot(valid);
  __shared__ int ws[4];
  int lane = threadIdx.x & 63, wid = threadIdx.x >> 6;
  if (lane == 0) ws[wid] = __popcll(mask);
  __syncthreads();
  if (threadIdx.x == 0) bcnt[blockIdx.x] = ws[0] + ws[1] + ws[2] + ws[3];
}

// ---- pass B: exclusive scan of 4096 block counts ----
__global__ __launch_bounds__(1024) void cmpB_k(const int* __restrict__ bcnt,
    int* __restrict__ bbase, int* __restrict__ total) {
  __shared__ int s[1024];
  int tid = threadIdx.x;
  int v0 = bcnt[4 * tid], v1 = bcnt[4 * tid + 1];
  int v2 = bcnt[4 * tid + 2], v3 = bcnt[4 * tid + 3];
  int tsum = v0 + v1 + v2 + v3;
  s[tid] = tsum; __syncthreads();
  for (int o = 1; o < 1024; o <<= 1) {
    int t = (tid >= o) ? s[tid - o] : 0;
    __syncthreads();
    s[tid] += t;
    __syncthreads();
  }
  int base = s[tid] - tsum;
  bbase[4 * tid] = base;
  bbase[4 * tid + 1] = base + v0;
  bbase[4 * tid + 2] = base + v0 + v1;
  bbase[4 * tid + 3] = base + v0 + v1 + v2;
  if (tid == 1023) *total = s[1023];
}

// ---- pass C: scatter + per-graph histogram ----
__global__ __launch_bounds__(256) void cmpC_k(const int* __restrict__ row,
    const int* __restrict__ col, const int* __restrict__ inv,
    const int* __restrict__ ecnt, const int* __restrict__ bbase,
    int* __restrict__ nrow, int* __restrict__ ncol, int* __restrict__ gcnt,
    int khalf) {
  int e = blockIdx.x * 256 + threadIdx.x;
  bool valid = false; int nr = 0, nc = 0;
  if (e < *ecnt) {
    nr = inv[row[e]]; nc = inv[col[e]];
    valid = (nr >= 0) && (nc >= 0);
  }
  unsigned long long mask = __ballot(valid);
  int lane = threadIdx.x & 63, wid = threadIdx.x >> 6;
  __shared__ int ws[4];
  __shared__ int lg[NB];
  if (threadIdx.x < NB) lg[threadIdx.x] = 0;
  if (lane == 0) ws[wid] = __popcll(mask);
  __syncthreads();
  if (threadIdx.x == 0) {
    int a = ws[0], b = ws[1], c2 = ws[2];
    ws[0] = 0; ws[1] = a; ws[2] = a + b; ws[3] = a + b + c2;
  }
  __syncthreads();
  if (valid) {
    unsigned long long lt = ((unsigned long long)1 << lane) - 1;
    int pos = bbase[blockIdx.x] + ws[wid] + (int)__popcll(mask & lt);
    nrow[pos] = nr;
    ncol[pos] = nc;
    atomicAdd(&lg[nc / khalf], 1);
  }
  __syncthreads();
  if (threadIdx.x < NB && lg[threadIdx.x]) atomicAdd(&gcnt[threadIdx.x], lg[threadIdx.x]);
}

// ---- scan 64 graph counts -> goff[65]; re-zeros gcnt for next layer ----
__global__ void gscan_k(int* __restrict__ gcnt, int* __restrict__ goff) {
  if (threadIdx.x == 0) {
    int s = 0;
    for (int g = 0; g < NB; ++g) { goff[g] = s; s += gcnt[g]; gcnt[g] = 0; }
    goff[NB] = s;
  }
}

// ---- final mean pool ----
__global__ __launch_bounds__(128) void pool_k(const float* __restrict__ x,
    float* __restrict__ out, int n) {
  int g = blockIdx.x, c = threadIdx.x;
  float s = 0.f;
  for (int r = 0; r < n; ++r) s += x[((size_t)g * n + r) * HB + c];
  out[g * HB + c] = s / n;
}

extern "C" void kernel_launch(void* const* d_in, const int* in_sizes, int n_in,
                              void* d_out, int out_size, void* d_ws, size_t ws_size,
                              hipStream_t stream) {
  const float* x_in = (const float*)d_in[0];
  const int*   ei   = (const int*)d_in[1];
  const float* Wc1  = (const float*)d_in[3];
  const float* Wc   = (const float*)d_in[4];
  const float* bc   = (const float*)d_in[5];
  const float* Wf   = (const float*)d_in[6];
  const float* bf   = (const float*)d_in[7];
  const float* bng  = (const float*)d_in[8];
  const float* bnb  = (const float*)d_in[9];
  const float* Ws1  = (const float*)d_in[10];
  const float* Ws2  = (const float*)d_in[11];
  const float* bs   = (const float*)d_in[12];

  const int N0 = 131072, E = NE;
  char* p = (char*)d_ws;
  auto alloc = [&](size_t bytes) -> char* {
    char* r = p; p += (bytes + 255) & ~(size_t)255; return r;
  };
  float* A    = (float*)alloc((size_t)N0 * HB * 4);       // BN'd h (gather source)
  float* Bb   = (float*)alloc((size_t)N0 * HB * 4);       // conv result
  float* Cc   = (float*)alloc((size_t)(N0 / 2) * HB * 4); // hw (layers>=1) / pool input
  float* aggx = (float*)alloc((size_t)N0 * 8 * 4);
  int*   rowA = (int*)alloc((size_t)E * 4);
  int*   colA = (int*)alloc((size_t)E * 4);
  int*   rowB = (int*)alloc((size_t)E * 4);
  int*   colB = (int*)alloc((size_t)E * 4);
  float* dis  = (float*)alloc((size_t)N0 * 4);
  float* selfs= (float*)alloc((size_t)N0 * 4);
  float* t2v  = (float*)alloc((size_t)N0 * 4);
  float* score= (float*)alloc((size_t)N0 * 4);
  int*   inv  = (int*)alloc((size_t)N0 * 4);
  int*   off  = (int*)alloc((size_t)(N0 + 1) * 4);
  int*   sel  = (int*)alloc((size_t)(N0 / 2) * 4);
  float* scale= (float*)alloc((size_t)(N0 / 2) * 4);
  int*   bcnt = (int*)alloc((size_t)EG * 4);
  int*   bbase= (int*)alloc((size_t)EG * 4);
  int*   gcnt = (int*)alloc(NB * 4);
  int*   goffA= (int*)alloc((NB + 1) * 4);
  int*   goffB= (int*)alloc((NB + 1) * 4);
  float* stat = (float*)alloc(256 * 4);
  float* bnsc = (float*)alloc(256 * 4);

  // once-per-call zeroing; bnfin/gscan maintain zeros across layers
  hipMemsetAsync(stat, 0, 256 * 4, stream);
  hipMemsetAsync(gcnt, 0, NB * 4, stream);

  init_edges_k<<<E / 256, 256, 0, stream>>>(ei, rowA, colA, E);
  init_goff_k<<<1, 128, 0, stream>>>(goffA, E / NB);

  int* rowCur = rowA; int* colCur = colA;
  int* rowNxt = rowB; int* colNxt = colB;
  int* goffCur = goffA; int* goffNxt = goffB;

  int n = 2048;
  for (int i = 0; i < 4; ++i) {
    int N = NB * n, khalf = n >> 1;
    // CSR payload aliases the INACTIVE edge double-buffer (rowNxt/colNxt):
    // written by csr_build, read through score_k, then legitimately
    // overwritten by cmpC at layer end — strictly stream-ordered.
    int*   srow  = rowNxt;
    float* snorm = (float*)colNxt;
    csr_build_k<<<NB, 1024, (size_t)16 * n, stream>>>(
        rowCur, colCur, goffCur, dis, off, srow, snorm, n);
    if (i == 0) {
      agg7_k<<<N / 32, 256, 0, stream>>>(x_in, srow, snorm, off, dis, aggx, N);
      matmulK_k<<<N / 32, 256, (size_t)7 * HB * 4, stream>>>(
          aggx, Wc1, bc, Bb, N, 7, 8, 1);
    } else {
      const float* W = Wc + (size_t)(i - 1) * HB * HB;
      // conv gemm with fused SAG gather: reads A[sel[r]] * scale[r] -> Cc (hw)
      gemm128v2_k<<<N / 128, 256, 0, stream>>>(A, W, nullptr, Cc, N, 4, sel, scale);
      gather_combine_k<<<N / 8, 256, 0, stream>>>(Cc, srow, snorm, off, dis,
                                                  bc + (size_t)i * HB, Bb, N);
    }
    // fc + relu (overwrites A; its old rows were consumed by the conv gemm)
    gemm128v2_k<<<N / 128, 256, 0, stream>>>(
        Bb, Wf + (size_t)i * HB * HB, bf + (size_t)i * HB, A, N, 3, nullptr, nullptr);
    // batchnorm
    bnstat_k<<<512, 256, 0, stream>>>(A, stat, N);
    bnfin_k<<<1, 128, 0, stream>>>(stat, bng + (size_t)i * HB, bnb + (size_t)i * HB, bnsc, N);
    bnapply_score_k<<<N / 4, 256, 0, stream>>>(
        A, bnsc, Ws1 + (size_t)i * HB, Ws2 + (size_t)i * HB, selfs, t2v, N);
    score_k<<<(N + 255) / 256, 256, 0, stream>>>(selfs, t2v, srow, off, bs + i, score, N);
    int bpg = n / 256;
    rank_topk_k<<<NB * bpg, 256, (size_t)n * 4, stream>>>(
        score, inv, sel, scale, n, khalf, bpg);
    if (i < 3) {
      cmpA_k<<<EG, 256, 0, stream>>>(rowCur, colCur, inv, goffCur + NB, bcnt);
      cmpB_k<<<1, 1024, 0, stream>>>(bcnt, bbase, goffNxt + NB);
      cmpC_k<<<EG, 256, 0, stream>>>(rowCur, colCur, inv, goffCur + NB, bbase,
                                     rowNxt, colNxt, gcnt, khalf);
      gscan_k<<<1, 64, 0, stream>>>(gcnt, goffNxt);
      int* t;
      t = rowCur; rowCur = rowNxt; rowNxt = t;
      t = colCur; colCur = colNxt; colNxt = t;
      t = goffCur; goffCur = goffNxt; goffNxt = t;
    } else {
      // final layer: materialize pooled rows for mean pool
      gather_x_k<<<(NB * khalf) / 8, 256, 0, stream>>>(A, sel, scale, Cc, NB * khalf);
    }
    n = khalf;
  }
  pool_k<<<NB, 128, 0, stream>>>(Cc, (float*)d_out, n);
}

// Round 9
// 693.826 us; speedup vs baseline: 5.4731x; 1.1586x over previous
//
#include <hip/hip_runtime.h>
#include <cstdint>

#define HB 128   // hidden size
#define NB 64    // graphs per batch
#define NE 1048576
#define EG (NE / 256)   // 4096 blocks for edge-sized kernels

// ---- init edge arrays ----
__global__ __launch_bounds__(256) void init_edges_k(const int* __restrict__ ei,
    int* __restrict__ row, int* __restrict__ col, int E) {
  int e = blockIdx.x * blockDim.x + threadIdx.x;
  if (e < E) { row[e] = ei[e]; col[e] = ei[E + e]; }
}

__global__ __launch_bounds__(128) void init_goff_k(int* __restrict__ goff, int epg) {
  int g = threadIdx.x;
  if (g <= NB) goff[g] = g * epg;
}

// ---- small-K matmul: out[N][128] = X[N][K(stride KS)] @ W[K][128] (+bias) ----
__global__ __launch_bounds__(256) void matmulK_k(const float* __restrict__ X,
    const float* __restrict__ W, const float* __restrict__ bias,
    float* __restrict__ out, int N, int K, int KS, int flags) {
  extern __shared__ float lw[];  // K*128 floats
  int tid = threadIdx.x;
  int nv = K * 32;
  for (int idx = tid; idx < nv; idx += 256)
    ((float4*)lw)[idx] = ((const float4*)W)[idx];
  __syncthreads();
  int tx = tid & 31, ty = tid >> 5;
  long rowbase = (long)blockIdx.x * 32;
  float acc[4][4] = {};
  const float* xp = X + (size_t)(rowbase + ty) * KS;
  for (int k = 0; k < K; ++k) {
    float4 wv = ((float4*)lw)[k * 32 + tx];
    #pragma unroll
    for (int rr = 0; rr < 4; ++rr) {
      float xv = xp[(size_t)rr * 8 * KS + k];
      acc[rr][0] += xv * wv.x; acc[rr][1] += xv * wv.y;
      acc[rr][2] += xv * wv.z; acc[rr][3] += xv * wv.w;
    }
  }
  float4 bv = make_float4(0.f, 0.f, 0.f, 0.f);
  if (flags & 1) bv = ((const float4*)bias)[tx];
  #pragma unroll
  for (int rr = 0; rr < 4; ++rr) {
    long r = rowbase + ty + rr * 8;
    float4 v;
    v.x = acc[rr][0] + bv.x; v.y = acc[rr][1] + bv.y;
    v.z = acc[rr][2] + bv.z; v.w = acc[rr][3] + bv.w;
    if (flags & 2) {
      v.x = fmaxf(v.x, 0.f); v.y = fmaxf(v.y, 0.f);
      v.z = fmaxf(v.z, 0.f); v.w = fmaxf(v.w, 0.f);
    }
    ((float4*)(out + (size_t)r * HB))[tx] = v;
  }
}

// ---- K=128 GEMM (64-row tile, v1 structure) ----
// flags: bit0 bias, bit1 relu, bit2 gather+BN-affine loader
//        (X row = (X[sel[r]]*a + b) * scale[r], a/b from bnsc), bit3 bnstat epilogue
__global__ __launch_bounds__(256) void gemm128_k(const float* __restrict__ X,
    const float* __restrict__ W, const float* __restrict__ bias,
    float* __restrict__ out, int N, int flags,
    const int* __restrict__ sel, const float* __restrict__ scale,
    const float* __restrict__ bnsc, float* __restrict__ stat) {
  __shared__ float Xs[2][64][8];
  __shared__ float2 red[8][128];   // bnstat partials
  int tid = threadIdx.x;
  int tx = tid & 31;   // cols 4*tx .. 4*tx+3
  int ty = tid >> 5;   // rows ty + 8*r
  long rowbase = (long)blockIdx.x * 64;
  float4 acc[8];
  #pragma unroll
  for (int r = 0; r < 8; ++r) acc[r] = make_float4(0.f, 0.f, 0.f, 0.f);
  int lr = tid >> 1, lq = (tid & 1) * 4;
  const float* xrow = nullptr;
  float lsc = 1.f;
  bool gmode = (flags & 4) != 0;
  if (tid < 128) {
    long srcrow = rowbase + lr;
    if (gmode) { srcrow = sel[rowbase + lr]; lsc = scale[rowbase + lr]; }
    xrow = X + (size_t)srcrow * HB + lq;
  }
  auto loadx = [&](int kc) -> float4 {
    float4 v = *(const float4*)(xrow + kc * 8);
    if (gmode) {
      int ch = kc * 8 + lq;
      float4 a = *(const float4*)(bnsc + ch);
      float4 b = *(const float4*)(bnsc + 128 + ch);
      v.x = (v.x * a.x + b.x) * lsc; v.y = (v.y * a.y + b.y) * lsc;
      v.z = (v.z * a.z + b.z) * lsc; v.w = (v.w * a.w + b.w) * lsc;
    } else {
      v.x *= lsc; v.y *= lsc; v.z *= lsc; v.w *= lsc;
    }
    return v;
  };
  if (tid < 128) *(float4*)&Xs[0][lr][lq] = loadx(0);
  __syncthreads();
  for (int kc = 0; kc < 16; ++kc) {
    int cur = kc & 1;
    if (kc < 15 && tid < 128)
      *(float4*)&Xs[cur ^ 1][lr][lq] = loadx(kc + 1);
    float4 wreg[8];
    #pragma unroll
    for (int k = 0; k < 8; ++k)
      wreg[k] = *(const float4*)(W + (size_t)(kc * 8 + k) * HB + 4 * tx);
    #pragma unroll
    for (int kk = 0; kk < 8; kk += 4) {
      float4 xreg[8];
      #pragma unroll
      for (int r = 0; r < 8; ++r)
        xreg[r] = *(const float4*)&Xs[cur][ty + 8 * r][kk];
      #pragma unroll
      for (int k = 0; k < 4; ++k) {
        #pragma unroll
        for (int r = 0; r < 8; ++r) {
          float xv = ((const float*)&xreg[r])[k];
          float4 wv = wreg[kk + k];
          acc[r].x += xv * wv.x; acc[r].y += xv * wv.y;
          acc[r].z += xv * wv.z; acc[r].w += xv * wv.w;
        }
      }
    }
    __syncthreads();
  }
  float4 bv = make_float4(0.f, 0.f, 0.f, 0.f);
  if (flags & 1) bv = ((const float4*)bias)[tx];
  float4 psum = make_float4(0.f, 0.f, 0.f, 0.f);
  float4 psq  = make_float4(0.f, 0.f, 0.f, 0.f);
  #pragma unroll
  for (int r = 0; r < 8; ++r) {
    float4 v;
    v.x = acc[r].x + bv.x; v.y = acc[r].y + bv.y;
    v.z = acc[r].z + bv.z; v.w = acc[r].w + bv.w;
    if (flags & 2) {
      v.x = fmaxf(v.x, 0.f); v.y = fmaxf(v.y, 0.f);
      v.z = fmaxf(v.z, 0.f); v.w = fmaxf(v.w, 0.f);
    }
    if (flags & 8) {
      psum.x += v.x; psum.y += v.y; psum.z += v.z; psum.w += v.w;
      psq.x += v.x * v.x; psq.y += v.y * v.y;
      psq.z += v.z * v.z; psq.w += v.w * v.w;
    }
    *(float4*)(out + (size_t)(rowbase + ty + 8 * r) * HB + 4 * tx) = v;
  }
  if (flags & 8) {
    red[ty][4 * tx + 0] = make_float2(psum.x, psq.x);
    red[ty][4 * tx + 1] = make_float2(psum.y, psq.y);
    red[ty][4 * tx + 2] = make_float2(psum.z, psq.z);
    red[ty][4 * tx + 3] = make_float2(psum.w, psq.w);
    __syncthreads();
    if (tid < 128) {
      float s = 0.f, q = 0.f;
      #pragma unroll
      for (int t = 0; t < 8; ++t) { s += red[t][tid].x; q += red[t][tid].y; }
      atomicAdd(&stat[tid], s);
      atomicAdd(&stat[128 + tid], q);
    }
  }
}

// ---- fused per-graph CSR build: LDS hist -> dis -> LDS scan -> LDS-cursor scatter ----
__global__ __launch_bounds__(1024) void csr_build_k(const int* __restrict__ row,
    const int* __restrict__ col, const int* __restrict__ goff,
    float* __restrict__ dis, int* __restrict__ off, int* __restrict__ srow,
    float* __restrict__ snorm, int n) {
  extern __shared__ int lds[];
  int* ldeg = lds;
  int* lsa  = lds + n;
  int* lsb  = lds + 2 * n;
  float* ldis = (float*)(lds + 3 * n);
  int g = blockIdx.x, tid = threadIdx.x;
  int e0 = goff[g], e1 = goff[g + 1];
  int base = g * n;
  for (int i = tid; i < n; i += 1024) ldeg[i] = 0;
  __syncthreads();
  for (int e = e0 + tid; e < e1; e += 1024) atomicAdd(&ldeg[col[e] - base], 1);
  __syncthreads();
  for (int i = tid; i < n; i += 1024) {
    int d = ldeg[i];
    ldis[i] = rsqrtf((float)d + 1.f);
    lsa[i] = d;
  }
  __syncthreads();
  int* src = lsa; int* dst = lsb;
  for (int o = 1; o < n; o <<= 1) {
    for (int i = tid; i < n; i += 1024) dst[i] = src[i] + ((i >= o) ? src[i - o] : 0);
    __syncthreads();
    int* t = src; src = dst; dst = t;
  }
  for (int i = tid; i < n; i += 1024) {
    int d = ldeg[i];
    int ex = src[i] - d;
    off[base + i] = e0 + ex;
    ldeg[i] = ex;
    dis[base + i] = ldis[i];
  }
  if (tid == 0) off[base + n] = e1;
  __syncthreads();
  for (int e = e0 + tid; e < e1; e += 1024) {
    int r = row[e], c = col[e];
    int lc = c - base;
    int p = e0 + atomicAdd(&ldeg[lc], 1);
    srow[p] = r;
    snorm[p] = ldis[r - base] * ldis[lc];
  }
}

// ---- layer-0: aggregate raw 7-channel X over CSR + self loop -> aggx[N][8] ----
__global__ __launch_bounds__(256) void agg7_k(const float* __restrict__ x,
    const int* __restrict__ srow, const float* __restrict__ snorm,
    const int* __restrict__ off, const float* __restrict__ dis,
    float* __restrict__ aggx, int N) {
  int gid = blockIdx.x * blockDim.x + threadIdx.x;
  int node = gid >> 3, c = gid & 7;
  if (node >= N) return;
  float acc = 0.f;
  if (c < 7) {
    int s = off[node], e = off[node + 1];
    for (int j = s; j < e; ++j) acc += x[(size_t)srow[j] * 7 + c] * snorm[j];
    float d = dis[node];
    acc += x[(size_t)node * 7 + c] * d * d;
  }
  aggx[(size_t)node * 8 + c] = acc;
}

// ---- CSR gather + self loop + bias (128-ch) ----
__global__ __launch_bounds__(256) void gather_combine_k(const float* __restrict__ hw,
    const int* __restrict__ srow, const float* __restrict__ snorm,
    const int* __restrict__ off, const float* __restrict__ dis,
    const float* __restrict__ bc, float* __restrict__ out, int N) {
  int gid = blockIdx.x * blockDim.x + threadIdx.x;
  int node = gid >> 5;
  if (node >= N) return;
  int ch = (gid & 31) * 4;
  int s = off[node], e = off[node + 1];
  float4 acc = make_float4(0.f, 0.f, 0.f, 0.f);
  for (int j = s; j < e; ++j) {
    int r = srow[j];
    float nm = snorm[j];
    float4 v = *(const float4*)(hw + (size_t)r * HB + ch);
    acc.x += v.x * nm; acc.y += v.y * nm; acc.z += v.z * nm; acc.w += v.w * nm;
  }
  float d = dis[node], d2 = d * d;
  float4 h = *(const float4*)(hw + (size_t)node * HB + ch);
  float4 b = *(const float4*)(bc + ch);
  acc.x += h.x * d2 + b.x; acc.y += h.y * d2 + b.y;
  acc.z += h.z * d2 + b.z; acc.w += h.w * d2 + b.w;
  *(float4*)(out + (size_t)node * HB + ch) = acc;
}

// ---- BN finalize from stat (re-zeros stat for the next layer) ----
__global__ __launch_bounds__(128) void bnfin_k(float* __restrict__ stat,
    const float* __restrict__ g, const float* __restrict__ b,
    float* __restrict__ sc, int N) {
  int c = threadIdx.x;
  if (c < 128) {
    float mu = stat[c] / N, ms = stat[128 + c] / N;
    float var = ms - mu * mu;
    float a = g[c] * rsqrtf(var + 1e-5f);
    sc[c] = a;
    sc[128 + c] = b[c] - mu * a;
    stat[c] = 0.f;
    stat[128 + c] = 0.f;
  }
}

// ---- score prep: read pre-BN h, apply affine in registers, dot with Ws1/Ws2 ----
__global__ __launch_bounds__(256) void score_prep_k(const float* __restrict__ h,
    const float* __restrict__ sc, const float* __restrict__ w1,
    const float* __restrict__ w2, float* __restrict__ selfs,
    float* __restrict__ t2, int N) {
  int gid = blockIdx.x * blockDim.x + threadIdx.x;
  int node = gid >> 6;
  if (node >= N) return;
  int lane = gid & 63, c = lane * 2;
  float2 v = *(const float2*)(h + (size_t)node * HB + c);
  v.x = v.x * sc[c] + sc[128 + c];
  v.y = v.y * sc[c + 1] + sc[128 + c + 1];
  float s1 = v.x * w1[c] + v.y * w1[c + 1];
  float s2 = v.x * w2[c] + v.y * w2[c + 1];
  #pragma unroll
  for (int off = 32; off > 0; off >>= 1) {
    s1 += __shfl_xor(s1, off);
    s2 += __shfl_xor(s2, off);
  }
  if (lane == 0) { selfs[node] = s1; t2[node] = s2; }
}

// ---- SAG score: selfs + CSR gather of t2 + bias ----
__global__ __launch_bounds__(256) void score_k(const float* __restrict__ selfs,
    const float* __restrict__ t2, const int* __restrict__ srow,
    const int* __restrict__ off, const float* __restrict__ bs,
    float* __restrict__ score, int N) {
  int i = blockIdx.x * blockDim.x + threadIdx.x;
  if (i >= N) return;
  float s = selfs[i] + bs[0];
  int e0 = off[i], e1 = off[i + 1];
  for (int j = e0; j < e1; ++j) s += t2[srow[j]];
  score[i] = s;
}

// ---- exact top-k by rank; bpg blocks per graph, 256 threads, 1 elem/thread ----
__global__ __launch_bounds__(256) void rank_topk_k(const float* __restrict__ score,
    int* __restrict__ inv, int* __restrict__ sel, float* __restrict__ scale,
    int n, int k, int bpg) {
  extern __shared__ float ls[];  // n floats
  int g = blockIdx.x / bpg, sub = blockIdx.x % bpg;
  int tid = threadIdx.x;
  const float* sg = score + (size_t)g * n;
  for (int i = tid; i < n; i += 256) ls[i] = sg[i];
  __syncthreads();
  int i0 = sub * 256 + tid;
  float s0 = ls[i0];
  int r0 = 0;
  for (int jb = 0; jb < n; jb += 4) {
    float4 v = *(const float4*)(ls + jb);
    r0 += (v.x > s0) || (v.x == s0 && (jb + 0) < i0);
    r0 += (v.y > s0) || (v.y == s0 && (jb + 1) < i0);
    r0 += (v.z > s0) || (v.z == s0 && (jb + 2) < i0);
    r0 += (v.w > s0) || (v.w == s0 && (jb + 3) < i0);
  }
  if (r0 < k) {
    inv[(size_t)g * n + i0] = g * k + r0;
    sel[(size_t)g * k + r0] = g * n + i0;
    scale[(size_t)g * k + r0] = tanhf(s0);
  } else inv[(size_t)g * n + i0] = -1;
}

// ---- gather kept rows with BN affine (final layer -> pool input) ----
__global__ __launch_bounds__(256) void gather_x_k(const float* __restrict__ h,
    const float* __restrict__ bnsc, const int* __restrict__ sel,
    const float* __restrict__ scale, float* __restrict__ xout, int M) {
  int gid = blockIdx.x * blockDim.x + threadIdx.x;
  int r = gid >> 5;
  if (r >= M) return;
  int ch = (gid & 31) * 4;
  int old = sel[r];
  float sc = scale[r];
  float4 v = *(const float4*)(h + (size_t)old * HB + ch);
  float4 a = *(const float4*)(bnsc + ch);
  float4 b = *(const float4*)(bnsc + 128 + ch);
  v.x = (v.x * a.x + b.x) * sc; v.y = (v.y * a.y + b.y) * sc;
  v.z = (v.z * a.z + b.z) * sc; v.w = (v.w * a.w + b.w) * sc;
  *(float4*)(xout + (size_t)r * HB + ch) = v;
}

// ---- order-preserving compact: pass A (per-block count) ----
__global__ __launch_bounds__(256) void cmpA_k(const int* __restrict__ row,
    const int* __restrict__ col, const int* __restrict__ inv,
    const int* __restrict__ ecnt, int* __restrict__ bcnt) {
  int e = blockIdx.x * 256 + threadIdx.x;
  bool valid = false;
  if (e < *ecnt) {
    int nr = inv[row[e]], nc = inv[col[e]];
    valid = (nr >= 0) && (nc >= 0);
  }
  unsigned long long mask = __ballot(valid);
  __shared__ int ws[4];
  int lane = threadIdx.x & 63, wid = threadIdx.x >> 6;
  if (lane == 0) ws[wid] = __popcll(mask);
  __syncthreads();
  if (threadIdx.x == 0) bcnt[blockIdx.x] = ws[0] + ws[1] + ws[2] + ws[3];
}

// ---- pass B: exclusive scan of 4096 block counts ----
__global__ __launch_bounds__(1024) void cmpB_k(const int* __restrict__ bcnt,
    int* __restrict__ bbase, int* __restrict__ total) {
  __shared__ int s[1024];
  int tid = threadIdx.x;
  int v0 = bcnt[4 * tid], v1 = bcnt[4 * tid + 1];
  int v2 = bcnt[4 * tid + 2], v3 = bcnt[4 * tid + 3];
  int tsum = v0 + v1 + v2 + v3;
  s[tid] = tsum; __syncthreads();
  for (int o = 1; o < 1024; o <<= 1) {
    int t = (tid >= o) ? s[tid - o] : 0;
    __syncthreads();
    s[tid] += t;
    __syncthreads();
  }
  int base = s[tid] - tsum;
  bbase[4 * tid] = base;
  bbase[4 * tid + 1] = base + v0;
  bbase[4 * tid + 2] = base + v0 + v1;
  bbase[4 * tid + 3] = base + v0 + v1 + v2;
  if (tid == 1023) *total = s[1023];
}

// ---- pass C: scatter + per-graph histogram ----
__global__ __launch_bounds__(256) void cmpC_k(const int* __restrict__ row,
    const int* __restrict__ col, const int* __restrict__ inv,
    const int* __restrict__ ecnt, const int* __restrict__ bbase,
    int* __restrict__ nrow, int* __restrict__ ncol, int* __restrict__ gcnt,
    int khalf) {
  int e = blockIdx.x * 256 + threadIdx.x;
  bool valid = false; int nr = 0, nc = 0;
  if (e < *ecnt) {
    nr = inv[row[e]]; nc = inv[col[e]];
    valid = (nr >= 0) && (nc >= 0);
  }
  unsigned long long mask = __ballot(valid);
  int lane = threadIdx.x & 63, wid = threadIdx.x >> 6;
  __shared__ int ws[4];
  __shared__ int lg[NB];
  if (threadIdx.x < NB) lg[threadIdx.x] = 0;
  if (lane == 0) ws[wid] = __popcll(mask);
  __syncthreads();
  if (threadIdx.x == 0) {
    int a = ws[0], b = ws[1], c2 = ws[2];
    ws[0] = 0; ws[1] = a; ws[2] = a + b; ws[3] = a + b + c2;
  }
  __syncthreads();
  if (valid) {
    unsigned long long lt = ((unsigned long long)1 << lane) - 1;
    int pos = bbase[blockIdx.x] + ws[wid] + (int)__popcll(mask & lt);
    nrow[pos] = nr;
    ncol[pos] = nc;
    atomicAdd(&lg[nc / khalf], 1);
  }
  __syncthreads();
  if (threadIdx.x < NB && lg[threadIdx.x]) atomicAdd(&gcnt[threadIdx.x], lg[threadIdx.x]);
}

// ---- scan 64 graph counts -> goff[65]; re-zeros gcnt for next layer ----
__global__ void gscan_k(int* __restrict__ gcnt, int* __restrict__ goff) {
  if (threadIdx.x == 0) {
    int s = 0;
    for (int g = 0; g < NB; ++g) { goff[g] = s; s += gcnt[g]; gcnt[g] = 0; }
    goff[NB] = s;
  }
}

// ---- final mean pool ----
__global__ __launch_bounds__(128) void pool_k(const float* __restrict__ x,
    float* __restrict__ out, int n) {
  int g = blockIdx.x, c = threadIdx.x;
  float s = 0.f;
  for (int r = 0; r < n; ++r) s += x[((size_t)g * n + r) * HB + c];
  out[g * HB + c] = s / n;
}

extern "C" void kernel_launch(void* const* d_in, const int* in_sizes, int n_in,
                              void* d_out, int out_size, void* d_ws, size_t ws_size,
                              hipStream_t stream) {
  const float* x_in = (const float*)d_in[0];
  const int*   ei   = (const int*)d_in[1];
  const float* Wc1  = (const float*)d_in[3];
  const float* Wc   = (const float*)d_in[4];
  const float* bc   = (const float*)d_in[5];
  const float* Wf   = (const float*)d_in[6];
  const float* bf   = (const float*)d_in[7];
  const float* bng  = (const float*)d_in[8];
  const float* bnb  = (const float*)d_in[9];
  const float* Ws1  = (const float*)d_in[10];
  const float* Ws2  = (const float*)d_in[11];
  const float* bs   = (const float*)d_in[12];

  const int N0 = 131072, E = NE;
  char* p = (char*)d_ws;
  auto alloc = [&](size_t bytes) -> char* {
    char* r = p; p += (bytes + 255) & ~(size_t)255; return r;
  };
  float* A    = (float*)alloc((size_t)N0 * HB * 4);       // pre-BN fc output
  float* Bb   = (float*)alloc((size_t)N0 * HB * 4);       // conv result
  float* Cc   = (float*)alloc((size_t)(N0 / 2) * HB * 4); // hw / pool input
  float* aggx = (float*)alloc((size_t)N0 * 8 * 4);
  int*   rowA = (int*)alloc((size_t)E * 4);
  int*   colA = (int*)alloc((size_t)E * 4);
  int*   rowB = (int*)alloc((size_t)E * 4);
  int*   colB = (int*)alloc((size_t)E * 4);
  float* dis  = (float*)alloc((size_t)N0 * 4);
  float* selfs= (float*)alloc((size_t)N0 * 4);
  float* t2v  = (float*)alloc((size_t)N0 * 4);
  float* score= (float*)alloc((size_t)N0 * 4);
  int*   inv  = (int*)alloc((size_t)N0 * 4);
  int*   off  = (int*)alloc((size_t)(N0 + 1) * 4);
  int*   sel  = (int*)alloc((size_t)(N0 / 2) * 4);
  float* scale= (float*)alloc((size_t)(N0 / 2) * 4);
  int*   bcnt = (int*)alloc((size_t)EG * 4);
  int*   bbase= (int*)alloc((size_t)EG * 4);
  int*   gcnt = (int*)alloc(NB * 4);
  int*   goffA= (int*)alloc((NB + 1) * 4);
  int*   goffB= (int*)alloc((NB + 1) * 4);
  float* stat = (float*)alloc(256 * 4);
  float* bnsc = (float*)alloc(256 * 4);

  // once-per-call zeroing; bnfin/gscan maintain zeros across layers
  hipMemsetAsync(stat, 0, 256 * 4, stream);
  hipMemsetAsync(gcnt, 0, NB * 4, stream);

  init_edges_k<<<E / 256, 256, 0, stream>>>(ei, rowA, colA, E);
  init_goff_k<<<1, 128, 0, stream>>>(goffA, E / NB);

  int* rowCur = rowA; int* colCur = colA;
  int* rowNxt = rowB; int* colNxt = colB;
  int* goffCur = goffA; int* goffNxt = goffB;

  int n = 2048;
  for (int i = 0; i < 4; ++i) {
    int N = NB * n, khalf = n >> 1;
    // CSR payload aliases the INACTIVE edge double-buffer (rowNxt/colNxt):
    // written by csr_build, read through score_k, overwritten by cmpC at
    // layer end — strictly stream-ordered.
    int*   srow  = rowNxt;
    float* snorm = (float*)colNxt;
    csr_build_k<<<NB, 1024, (size_t)16 * n, stream>>>(
        rowCur, colCur, goffCur, dis, off, srow, snorm, n);
    if (i == 0) {
      agg7_k<<<N / 32, 256, 0, stream>>>(x_in, srow, snorm, off, dis, aggx, N);
      matmulK_k<<<N / 32, 256, (size_t)7 * HB * 4, stream>>>(
          aggx, Wc1, bc, Bb, N, 7, 8, 1);
    } else {
      const float* W = Wc + (size_t)(i - 1) * HB * HB;
      // conv gemm, loader fuses SAG gather + prev layer's BN affine: -> Cc (hw)
      gemm128_k<<<N / 64, 256, 0, stream>>>(A, W, nullptr, Cc, N, 4,
                                            sel, scale, bnsc, nullptr);
      gather_combine_k<<<N / 8, 256, 0, stream>>>(Cc, srow, snorm, off, dis,
                                                  bc + (size_t)i * HB, Bb, N);
    }
    // fc + relu + fused bnstat (pre-BN output kept in A)
    gemm128_k<<<N / 64, 256, 0, stream>>>(
        Bb, Wf + (size_t)i * HB * HB, bf + (size_t)i * HB, A, N, 1 | 2 | 8,
        nullptr, nullptr, nullptr, stat);
    bnfin_k<<<1, 128, 0, stream>>>(stat, bng + (size_t)i * HB, bnb + (size_t)i * HB, bnsc, N);
    score_prep_k<<<N / 4, 256, 0, stream>>>(
        A, bnsc, Ws1 + (size_t)i * HB, Ws2 + (size_t)i * HB, selfs, t2v, N);
    score_k<<<(N + 255) / 256, 256, 0, stream>>>(selfs, t2v, srow, off, bs + i, score, N);
    int bpg = n / 256;
    rank_topk_k<<<NB * bpg, 256, (size_t)n * 4, stream>>>(
        score, inv, sel, scale, n, khalf, bpg);
    if (i < 3) {
      cmpA_k<<<EG, 256, 0, stream>>>(rowCur, colCur, inv, goffCur + NB, bcnt);
      cmpB_k<<<1, 1024, 0, stream>>>(bcnt, bbase, goffNxt + NB);
      cmpC_k<<<EG, 256, 0, stream>>>(rowCur, colCur, inv, goffCur + NB, bbase,
                                     rowNxt, colNxt, gcnt, khalf);
      gscan_k<<<1, 64, 0, stream>>>(gcnt, goffNxt);
      int* t;
      t = rowCur; rowCur = rowNxt; rowNxt = t;
      t = colCur; colCur = colNxt; colNxt = t;
      t = goffCur; goffCur = goffNxt; goffNxt = t;
    } else {
      // final layer: materialize pooled rows (BN affine + tanh scale) for pool
      gather_x_k<<<(NB * khalf) / 8, 256, 0, stream>>>(
          A, bnsc, sel, scale, Cc, NB * khalf);
    }
    n = khalf;
  }
  pool_k<<<NB, 128, 0, stream>>>(Cc, (float*)d_out, n);
}

// Round 10
// 635.779 us; speedup vs baseline: 5.9728x; 1.0913x over previous
//
#include <hip/hip_runtime.h>
#include <cstdint>

#define HB 128   // hidden size
#define NB 64    // graphs per batch
#define NE 1048576
#define EG (NE / 256)   // 4096 blocks for edge-sized kernels

// ---- init edge arrays + layer-0 edge-count metadata ----
__global__ __launch_bounds__(256) void init_edges_k(const int* __restrict__ ei,
    int* __restrict__ row, int* __restrict__ col, int* __restrict__ gcnt0,
    int* __restrict__ ecnt0, int E) {
  int e = blockIdx.x * blockDim.x + threadIdx.x;
  if (e < E) { row[e] = ei[e]; col[e] = ei[E + e]; }
  if (blockIdx.x == 0) {
    if (threadIdx.x < NB) gcnt0[threadIdx.x] = E / NB;
    if (threadIdx.x == 0) *ecnt0 = E;
  }
}

// ---- fused layer-0 dense chain: out = relu((aggx@Wc1 + bc) @ Wf + bf) ----
// 64-row tile; t staged in LDS; bnstat epilogue into 8-sharded stat.
__global__ __launch_bounds__(256) void conv_fc0_k(const float* __restrict__ aggx,
    const float* __restrict__ Wc1, const float* __restrict__ bc0,
    const float* __restrict__ Wf, const float* __restrict__ bf0,
    float* __restrict__ out, int N, float* __restrict__ stat) {
  __shared__ float lt[64][128];      // 32KB; red aliases front 8KB after final sync
  __shared__ float laggx[64][8];
  __shared__ float lwc1[7 * 128];
  float2 (*red)[128] = (float2(*)[128])lt;
  int tid = threadIdx.x;
  int tx = tid & 31, ty = tid >> 5;
  long rowbase = (long)blockIdx.x * 64;
  for (int i = tid; i < 7 * 32; i += 256)
    ((float4*)lwc1)[i] = ((const float4*)Wc1)[i];
  if (tid < 128) {
    int lr = tid >> 1, lq = (tid & 1) * 4;
    *(float4*)&laggx[lr][lq] = *(const float4*)(aggx + (rowbase + lr) * 8 + lq);
  }
  __syncthreads();
  // t = aggx @ Wc1 + bc
  float4 tacc[8];
  float4 bcv = ((const float4*)bc0)[tx];
  #pragma unroll
  for (int r = 0; r < 8; ++r) tacc[r] = bcv;
  #pragma unroll
  for (int k = 0; k < 7; ++k) {
    float4 wv = ((float4*)lwc1)[k * 32 + tx];
    #pragma unroll
    for (int r = 0; r < 8; ++r) {
      float xv = laggx[ty + 8 * r][k];
      tacc[r].x += xv * wv.x; tacc[r].y += xv * wv.y;
      tacc[r].z += xv * wv.z; tacc[r].w += xv * wv.w;
    }
  }
  #pragma unroll
  for (int r = 0; r < 8; ++r)
    *(float4*)&lt[ty + 8 * r][4 * tx] = tacc[r];
  __syncthreads();
  // out = relu(t @ Wf + bf); t read-only in LDS -> no in-loop barriers
  float4 acc[8];
  #pragma unroll
  for (int r = 0; r < 8; ++r) acc[r] = make_float4(0.f, 0.f, 0.f, 0.f);
  for (int kc = 0; kc < 16; ++kc) {
    float4 wreg[8];
    #pragma unroll
    for (int k = 0; k < 8; ++k)
      wreg[k] = *(const float4*)(Wf + (size_t)(kc * 8 + k) * HB + 4 * tx);
    #pragma unroll
    for (int kk = 0; kk < 8; kk += 4) {
      float4 xreg[8];
      #pragma unroll
      for (int r = 0; r < 8; ++r)
        xreg[r] = *(const float4*)&lt[ty + 8 * r][kc * 8 + kk];
      #pragma unroll
      for (int k2 = 0; k2 < 4; ++k2) {
        #pragma unroll
        for (int r = 0; r < 8; ++r) {
          float xv = ((const float*)&xreg[r])[k2];
          float4 wv = wreg[kk + k2];
          acc[r].x += xv * wv.x; acc[r].y += xv * wv.y;
          acc[r].z += xv * wv.z; acc[r].w += xv * wv.w;
        }
      }
    }
  }
  float4 bv = ((const float4*)bf0)[tx];
  float4 psum = make_float4(0.f, 0.f, 0.f, 0.f);
  float4 psq  = make_float4(0.f, 0.f, 0.f, 0.f);
  __syncthreads();   // all lt reads done before red overwrites it
  #pragma unroll
  for (int r = 0; r < 8; ++r) {
    float4 v;
    v.x = fmaxf(acc[r].x + bv.x, 0.f); v.y = fmaxf(acc[r].y + bv.y, 0.f);
    v.z = fmaxf(acc[r].z + bv.z, 0.f); v.w = fmaxf(acc[r].w + bv.w, 0.f);
    psum.x += v.x; psum.y += v.y; psum.z += v.z; psum.w += v.w;
    psq.x += v.x * v.x; psq.y += v.y * v.y;
    psq.z += v.z * v.z; psq.w += v.w * v.w;
    *(float4*)(out + (size_t)(rowbase + ty + 8 * r) * HB + 4 * tx) = v;
  }
  red[ty][4 * tx + 0] = make_float2(psum.x, psq.x);
  red[ty][4 * tx + 1] = make_float2(psum.y, psq.y);
  red[ty][4 * tx + 2] = make_float2(psum.z, psq.z);
  red[ty][4 * tx + 3] = make_float2(psum.w, psq.w);
  __syncthreads();
  if (tid < 128) {
    float s = 0.f, q = 0.f;
    #pragma unroll
    for (int t = 0; t < 8; ++t) { s += red[t][tid].x; q += red[t][tid].y; }
    float* st = stat + ((blockIdx.x & 7) << 8);
    atomicAdd(&st[tid], s);
    atomicAdd(&st[128 + tid], q);
  }
}

// ---- K=128 GEMM (64-row tile) ----
// flags: bit0 bias, bit1 relu, bit2 gather+BN-affine loader, bit3 bnstat epilogue
__global__ __launch_bounds__(256) void gemm128_k(const float* __restrict__ X,
    const float* __restrict__ W, const float* __restrict__ bias,
    float* __restrict__ out, int N, int flags,
    const int* __restrict__ sel, const float* __restrict__ scale,
    const float* __restrict__ bnsc, float* __restrict__ stat) {
  __shared__ float2 red[8][128];   // 8KB; Xs aliases front 4KB
  float (*Xs)[64][8] = (float(*)[64][8])red;
  int tid = threadIdx.x;
  int tx = tid & 31;
  int ty = tid >> 5;
  long rowbase = (long)blockIdx.x * 64;
  float4 acc[8];
  #pragma unroll
  for (int r = 0; r < 8; ++r) acc[r] = make_float4(0.f, 0.f, 0.f, 0.f);
  int lr = tid >> 1, lq = (tid & 1) * 4;
  const float* xrow = nullptr;
  float lsc = 1.f;
  bool gmode = (flags & 4) != 0;
  if (tid < 128) {
    long srcrow = rowbase + lr;
    if (gmode) { srcrow = sel[rowbase + lr]; lsc = scale[rowbase + lr]; }
    xrow = X + (size_t)srcrow * HB + lq;
  }
  auto loadx = [&](int kc) -> float4 {
    float4 v = *(const float4*)(xrow + kc * 8);
    if (gmode) {
      int ch = kc * 8 + lq;
      float4 a = *(const float4*)(bnsc + ch);
      float4 b = *(const float4*)(bnsc + 128 + ch);
      v.x = (v.x * a.x + b.x) * lsc; v.y = (v.y * a.y + b.y) * lsc;
      v.z = (v.z * a.z + b.z) * lsc; v.w = (v.w * a.w + b.w) * lsc;
    }
    return v;
  };
  if (tid < 128) *(float4*)&Xs[0][lr][lq] = loadx(0);
  __syncthreads();
  for (int kc = 0; kc < 16; ++kc) {
    int cur = kc & 1;
    if (kc < 15 && tid < 128)
      *(float4*)&Xs[cur ^ 1][lr][lq] = loadx(kc + 1);
    float4 wreg[8];
    #pragma unroll
    for (int k = 0; k < 8; ++k)
      wreg[k] = *(const float4*)(W + (size_t)(kc * 8 + k) * HB + 4 * tx);
    #pragma unroll
    for (int kk = 0; kk < 8; kk += 4) {
      float4 xreg[8];
      #pragma unroll
      for (int r = 0; r < 8; ++r)
        xreg[r] = *(const float4*)&Xs[cur][ty + 8 * r][kk];
      #pragma unroll
      for (int k = 0; k < 4; ++k) {
        #pragma unroll
        for (int r = 0; r < 8; ++r) {
          float xv = ((const float*)&xreg[r])[k];
          float4 wv = wreg[kk + k];
          acc[r].x += xv * wv.x; acc[r].y += xv * wv.y;
          acc[r].z += xv * wv.z; acc[r].w += xv * wv.w;
        }
      }
    }
    __syncthreads();
  }
  float4 bv = make_float4(0.f, 0.f, 0.f, 0.f);
  if (flags & 1) bv = ((const float4*)bias)[tx];
  float4 psum = make_float4(0.f, 0.f, 0.f, 0.f);
  float4 psq  = make_float4(0.f, 0.f, 0.f, 0.f);
  #pragma unroll
  for (int r = 0; r < 8; ++r) {
    float4 v;
    v.x = acc[r].x + bv.x; v.y = acc[r].y + bv.y;
    v.z = acc[r].z + bv.z; v.w = acc[r].w + bv.w;
    if (flags & 2) {
      v.x = fmaxf(v.x, 0.f); v.y = fmaxf(v.y, 0.f);
      v.z = fmaxf(v.z, 0.f); v.w = fmaxf(v.w, 0.f);
    }
    if (flags & 8) {
      psum.x += v.x; psum.y += v.y; psum.z += v.z; psum.w += v.w;
      psq.x += v.x * v.x; psq.y += v.y * v.y;
      psq.z += v.z * v.z; psq.w += v.w * v.w;
    }
    *(float4*)(out + (size_t)(rowbase + ty + 8 * r) * HB + 4 * tx) = v;
  }
  if (flags & 8) {
    red[ty][4 * tx + 0] = make_float2(psum.x, psq.x);
    red[ty][4 * tx + 1] = make_float2(psum.y, psq.y);
    red[ty][4 * tx + 2] = make_float2(psum.z, psq.z);
    red[ty][4 * tx + 3] = make_float2(psum.w, psq.w);
    __syncthreads();
    if (tid < 128) {
      float s = 0.f, q = 0.f;
      #pragma unroll
      for (int t = 0; t < 8; ++t) { s += red[t][tid].x; q += red[t][tid].y; }
      float* st = stat + ((blockIdx.x & 7) << 8);
      atomicAdd(&st[tid], s);
      atomicAdd(&st[128 + tid], q);
    }
  }
}

// ---- fused per-graph CSR build (per-graph range from gcnt prefix) ----
__global__ __launch_bounds__(1024) void csr_build_k(const int* __restrict__ row,
    const int* __restrict__ col, const int* __restrict__ gcnt,
    float* __restrict__ dis, int* __restrict__ off, int* __restrict__ srow,
    float* __restrict__ snorm, int n) {
  extern __shared__ int lds[];
  int* ldeg = lds;
  int* lsa  = lds + n;
  int* lsb  = lds + 2 * n;
  float* ldis = (float*)(lds + 3 * n);
  __shared__ int e01[2];
  int g = blockIdx.x, tid = threadIdx.x;
  if (tid == 0) {
    int s = 0;
    for (int gg = 0; gg < g; ++gg) s += gcnt[gg];
    e01[0] = s; e01[1] = s + gcnt[g];
  }
  int base = g * n;
  for (int i = tid; i < n; i += 1024) ldeg[i] = 0;
  __syncthreads();
  int e0 = e01[0], e1 = e01[1];
  for (int e = e0 + tid; e < e1; e += 1024) atomicAdd(&ldeg[col[e] - base], 1);
  __syncthreads();
  for (int i = tid; i < n; i += 1024) {
    int d = ldeg[i];
    ldis[i] = rsqrtf((float)d + 1.f);
    lsa[i] = d;
  }
  __syncthreads();
  int* src = lsa; int* dst = lsb;
  for (int o = 1; o < n; o <<= 1) {
    for (int i = tid; i < n; i += 1024) dst[i] = src[i] + ((i >= o) ? src[i - o] : 0);
    __syncthreads();
    int* t = src; src = dst; dst = t;
  }
  for (int i = tid; i < n; i += 1024) {
    int d = ldeg[i];
    int ex = src[i] - d;
    off[base + i] = e0 + ex;
    ldeg[i] = ex;
    dis[base + i] = ldis[i];
  }
  if (tid == 0) off[base + n] = e1;
  __syncthreads();
  for (int e = e0 + tid; e < e1; e += 1024) {
    int r = row[e], c = col[e];
    int lc = c - base;
    int p = e0 + atomicAdd(&ldeg[lc], 1);
    srow[p] = r;
    snorm[p] = ldis[r - base] * ldis[lc];
  }
}

// ---- layer-0: aggregate raw 7-channel X over CSR + self loop -> aggx[N][8] ----
__global__ __launch_bounds__(256) void agg7_k(const float* __restrict__ x,
    const int* __restrict__ srow, const float* __restrict__ snorm,
    const int* __restrict__ off, const float* __restrict__ dis,
    float* __restrict__ aggx, int N) {
  int gid = blockIdx.x * blockDim.x + threadIdx.x;
  int node = gid >> 3, c = gid & 7;
  if (node >= N) return;
  float acc = 0.f;
  if (c < 7) {
    int s = off[node], e = off[node + 1];
    for (int j = s; j < e; ++j) acc += x[(size_t)srow[j] * 7 + c] * snorm[j];
    float d = dis[node];
    acc += x[(size_t)node * 7 + c] * d * d;
  }
  aggx[(size_t)node * 8 + c] = acc;
}

// ---- CSR gather + self loop + bias (128-ch) ----
__global__ __launch_bounds__(256) void gather_combine_k(const float* __restrict__ hw,
    const int* __restrict__ srow, const float* __restrict__ snorm,
    const int* __restrict__ off, const float* __restrict__ dis,
    const float* __restrict__ bc, float* __restrict__ out, int N) {
  int gid = blockIdx.x * blockDim.x + threadIdx.x;
  int node = gid >> 5;
  if (node >= N) return;
  int ch = (gid & 31) * 4;
  int s = off[node], e = off[node + 1];
  float4 acc = make_float4(0.f, 0.f, 0.f, 0.f);
  for (int j = s; j < e; ++j) {
    int r = srow[j];
    float nm = snorm[j];
    float4 v = *(const float4*)(hw + (size_t)r * HB + ch);
    acc.x += v.x * nm; acc.y += v.y * nm; acc.z += v.z * nm; acc.w += v.w * nm;
  }
  float d = dis[node], d2 = d * d;
  float4 h = *(const float4*)(hw + (size_t)node * HB + ch);
  float4 b = *(const float4*)(bc + ch);
  acc.x += h.x * d2 + b.x; acc.y += h.y * d2 + b.y;
  acc.z += h.z * d2 + b.z; acc.w += h.w * d2 + b.w;
  *(float4*)(out + (size_t)node * HB + ch) = acc;
}

// ---- BN finalize from 8-sharded stat ----
__global__ __launch_bounds__(128) void bnfin_k(const float* __restrict__ stat8,
    const float* __restrict__ g, const float* __restrict__ b,
    float* __restrict__ sc, int N) {
  int c = threadIdx.x;
  if (c < 128) {
    float s = 0.f, q = 0.f;
    #pragma unroll
    for (int sh = 0; sh < 8; ++sh) {
      s += stat8[sh * 256 + c];
      q += stat8[sh * 256 + 128 + c];
    }
    float mu = s / N;
    float var = q / N - mu * mu;
    float a = g[c] * rsqrtf(var + 1e-5f);
    sc[c] = a;
    sc[128 + c] = b[c] - mu * a;
  }
}

// ---- score prep: read pre-BN h, apply affine in registers, dot with Ws1/Ws2 ----
__global__ __launch_bounds__(256) void score_prep_k(const float* __restrict__ h,
    const float* __restrict__ sc, const float* __restrict__ w1,
    const float* __restrict__ w2, float* __restrict__ selfs,
    float* __restrict__ t2, int N) {
  int gid = blockIdx.x * blockDim.x + threadIdx.x;
  int node = gid >> 6;
  if (node >= N) return;
  int lane = gid & 63, c = lane * 2;
  float2 v = *(const float2*)(h + (size_t)node * HB + c);
  v.x = v.x * sc[c] + sc[128 + c];
  v.y = v.y * sc[c + 1] + sc[128 + c + 1];
  float s1 = v.x * w1[c] + v.y * w1[c + 1];
  float s2 = v.x * w2[c] + v.y * w2[c + 1];
  #pragma unroll
  for (int off = 32; off > 0; off >>= 1) {
    s1 += __shfl_xor(s1, off);
    s2 += __shfl_xor(s2, off);
  }
  if (lane == 0) { selfs[node] = s1; t2[node] = s2; }
}

// ---- SAG score: selfs + CSR gather of t2 + bias ----
__global__ __launch_bounds__(256) void score_k(const float* __restrict__ selfs,
    const float* __restrict__ t2, const int* __restrict__ srow,
    const int* __restrict__ off, const float* __restrict__ bs,
    float* __restrict__ score, int N) {
  int i = blockIdx.x * blockDim.x + threadIdx.x;
  if (i >= N) return;
  float s = selfs[i] + bs[0];
  int e0 = off[i], e1 = off[i + 1];
  for (int j = e0; j < e1; ++j) s += t2[srow[j]];
  score[i] = s;
}

// ---- exact top-k by rank; bpg blocks per graph, 256 threads, 1 elem/thread ----
__global__ __launch_bounds__(256) void rank_topk_k(const float* __restrict__ score,
    int* __restrict__ inv, int* __restrict__ sel, float* __restrict__ scale,
    int n, int k, int bpg) {
  extern __shared__ float ls[];  // n floats
  int g = blockIdx.x / bpg, sub = blockIdx.x % bpg;
  int tid = threadIdx.x;
  const float* sg = score + (size_t)g * n;
  for (int i = tid; i < n; i += 256) ls[i] = sg[i];
  __syncthreads();
  int i0 = sub * 256 + tid;
  float s0 = ls[i0];
  int r0 = 0;
  for (int jb = 0; jb < n; jb += 4) {
    float4 v = *(const float4*)(ls + jb);
    r0 += (v.x > s0) || (v.x == s0 && (jb + 0) < i0);
    r0 += (v.y > s0) || (v.y == s0 && (jb + 1) < i0);
    r0 += (v.z > s0) || (v.z == s0 && (jb + 2) < i0);
    r0 += (v.w > s0) || (v.w == s0 && (jb + 3) < i0);
  }
  if (r0 < k) {
    inv[(size_t)g * n + i0] = g * k + r0;
    sel[(size_t)g * k + r0] = g * n + i0;
    scale[(size_t)g * k + r0] = tanhf(s0);
  } else inv[(size_t)g * n + i0] = -1;
}

// ---- gather kept rows with BN affine (final layer -> pool input) ----
__global__ __launch_bounds__(256) void gather_x_k(const float* __restrict__ h,
    const float* __restrict__ bnsc, const int* __restrict__ sel,
    const float* __restrict__ scale, float* __restrict__ xout, int M) {
  int gid = blockIdx.x * blockDim.x + threadIdx.x;
  int r = gid >> 5;
  if (r >= M) return;
  int ch = (gid & 31) * 4;
  int old = sel[r];
  float sc = scale[r];
  float4 v = *(const float4*)(h + (size_t)old * HB + ch);
  float4 a = *(const float4*)(bnsc + ch);
  float4 b = *(const float4*)(bnsc + 128 + ch);
  v.x = (v.x * a.x + b.x) * sc; v.y = (v.y * a.y + b.y) * sc;
  v.z = (v.z * a.z + b.z) * sc; v.w = (v.w * a.w + b.w) * sc;
  *(float4*)(xout + (size_t)r * HB + ch) = v;
}

// ---- order-preserving compact: pass A (per-block count) ----
__global__ __launch_bounds__(256) void cmpA_k(const int* __restrict__ row,
    const int* __restrict__ col, const int* __restrict__ inv,
    const int* __restrict__ ecnt, int* __restrict__ bcnt) {
  int e = blockIdx.x * 256 + threadIdx.x;
  bool valid = false;
  if (e < *ecnt) {
    int nr = inv[row[e]], nc = inv[col[e]];
    valid = (nr >= 0) && (nc >= 0);
  }
  unsigned long long mask = __ballot(valid);
  __shared__ int ws[4];
  int lane = threadIdx.x & 63, wid = threadIdx.x >> 6;
  if (lane == 0) ws[wid] = __popcll(mask);
  __syncthreads();
  if (threadIdx.x == 0) bcnt[blockIdx.x] = ws[0] + ws[1] + ws[2] + ws[3];
}

// ---- pass B: exclusive scan of 4096 block counts; writes total -> next ecnt ----
__global__ __launch_bounds__(1024) void cmpB_k(const int* __restrict__ bcnt,
    int* __restrict__ bbase, int* __restrict__ total) {
  __shared__ int s[1024];
  int tid = threadIdx.x;
  int v0 = bcnt[4 * tid], v1 = bcnt[4 * tid + 1];
  int v2 = bcnt[4 * tid + 2], v3 = bcnt[4 * tid + 3];
  int tsum = v0 + v1 + v2 + v3;
  s[tid] = tsum; __syncthreads();
  for (int o = 1; o < 1024; o <<= 1) {
    int t = (tid >= o) ? s[tid - o] : 0;
    __syncthreads();
    s[tid] += t;
    __syncthreads();
  }
  int base = s[tid] - tsum;
  bbase[4 * tid] = base;
  bbase[4 * tid + 1] = base + v0;
  bbase[4 * tid + 2] = base + v0 + v1;
  bbase[4 * tid + 3] = base + v0 + v1 + v2;
  if (tid == 1023) *total = s[1023];
}

// ---- pass C: scatter + per-graph histogram into next layer's gcnt slice ----
__global__ __launch_bounds__(256) void cmpC_k(const int* __restrict__ row,
    const int* __restrict__ col, const int* __restrict__ inv,
    const int* __restrict__ ecnt, const int* __restrict__ bbase,
    int* __restrict__ nrow, int* __restrict__ ncol, int* __restrict__ gcnt,
    int khalf) {
  int e = blockIdx.x * 256 + threadIdx.x;
  bool valid = false; int nr = 0, nc = 0;
  if (e < *ecnt) {
    nr = inv[row[e]]; nc = inv[col[e]];
    valid = (nr >= 0) && (nc >= 0);
  }
  unsigned long long mask = __ballot(valid);
  int lane = threadIdx.x & 63, wid = threadIdx.x >> 6;
  __shared__ int ws[4];
  __shared__ int lg[NB];
  if (threadIdx.x < NB) lg[threadIdx.x] = 0;
  if (lane == 0) ws[wid] = __popcll(mask);
  __syncthreads();
  if (threadIdx.x == 0) {
    int a = ws[0], b = ws[1], c2 = ws[2];
    ws[0] = 0; ws[1] = a; ws[2] = a + b; ws[3] = a + b + c2;
  }
  __syncthreads();
  if (valid) {
    unsigned long long lt = ((unsigned long long)1 << lane) - 1;
    int pos = bbase[blockIdx.x] + ws[wid] + (int)__popcll(mask & lt);
    nrow[pos] = nr;
    ncol[pos] = nc;
    atomicAdd(&lg[nc / khalf], 1);
  }
  __syncthreads();
  if (threadIdx.x < NB && lg[threadIdx.x]) atomicAdd(&gcnt[threadIdx.x], lg[threadIdx.x]);
}

// ---- final mean pool ----
__global__ __launch_bounds__(128) void pool_k(const float* __restrict__ x,
    float* __restrict__ out, int n) {
  int g = blockIdx.x, c = threadIdx.x;
  float s = 0.f;
  for (int r = 0; r < n; ++r) s += x[((size_t)g * n + r) * HB + c];
  out[g * HB + c] = s / n;
}

extern "C" void kernel_launch(void* const* d_in, const int* in_sizes, int n_in,
                              void* d_out, int out_size, void* d_ws, size_t ws_size,
                              hipStream_t stream) {
  const float* x_in = (const float*)d_in[0];
  const int*   ei   = (const int*)d_in[1];
  const float* Wc1  = (const float*)d_in[3];
  const float* Wc   = (const float*)d_in[4];
  const float* bc   = (const float*)d_in[5];
  const float* Wf   = (const float*)d_in[6];
  const float* bf   = (const float*)d_in[7];
  const float* bng  = (const float*)d_in[8];
  const float* bnb  = (const float*)d_in[9];
  const float* Ws1  = (const float*)d_in[10];
  const float* Ws2  = (const float*)d_in[11];
  const float* bs   = (const float*)d_in[12];

  const int N0 = 131072, E = NE;
  char* p = (char*)d_ws;
  auto alloc = [&](size_t bytes) -> char* {
    char* r = p; p += (bytes + 255) & ~(size_t)255; return r;
  };
  float* A    = (float*)alloc((size_t)N0 * HB * 4);       // pre-BN fc output
  float* Bb   = (float*)alloc((size_t)N0 * HB * 4);       // conv result (layers>=1)
  float* Cc   = (float*)alloc((size_t)(N0 / 2) * HB * 4); // hw / pool input
  float* aggx = (float*)alloc((size_t)N0 * 8 * 4);
  int*   rowA = (int*)alloc((size_t)E * 4);
  int*   colA = (int*)alloc((size_t)E * 4);
  int*   rowB = (int*)alloc((size_t)E * 4);
  int*   colB = (int*)alloc((size_t)E * 4);
  float* dis  = (float*)alloc((size_t)N0 * 4);
  float* selfs= (float*)alloc((size_t)N0 * 4);
  float* t2v  = (float*)alloc((size_t)N0 * 4);
  float* score= (float*)alloc((size_t)N0 * 4);
  int*   inv  = (int*)alloc((size_t)N0 * 4);
  int*   off  = (int*)alloc((size_t)(N0 + 1) * 4);
  int*   sel  = (int*)alloc((size_t)(N0 / 2) * 4);
  float* scale= (float*)alloc((size_t)(N0 / 2) * 4);
  int*   bcnt = (int*)alloc((size_t)EG * 4);
  int*   bbase= (int*)alloc((size_t)EG * 4);
  int*   gcntL= (int*)alloc(4 * NB * 4);     // per-layer graph edge counts
  float* stat8= (float*)alloc(4 * 8 * 256 * 4);  // per-layer 8-sharded BN stats
  float* bnsc = (float*)alloc(256 * 4);
  int*   ecnt = (int*)alloc(2 * 4);

  // once-per-call zeroing (slices are single-use per call)
  hipMemsetAsync(stat8, 0, 4 * 8 * 256 * 4, stream);
  hipMemsetAsync(gcntL, 0, 4 * NB * 4, stream);

  init_edges_k<<<E / 256, 256, 0, stream>>>(ei, rowA, colA, gcntL, ecnt, E);

  int* rowCur = rowA; int* colCur = colA;
  int* rowNxt = rowB; int* colNxt = colB;
  int* ecntCur = ecnt; int* ecntNxt = ecnt + 1;

  int n = 2048;
  for (int i = 0; i < 4; ++i) {
    int N = NB * n, khalf = n >> 1;
    float* statL = stat8 + (size_t)i * 8 * 256;
    // CSR payload aliases the INACTIVE edge double-buffer (rowNxt/colNxt):
    // written by csr_build, read through score_k, overwritten by cmpC at
    // layer end — strictly stream-ordered.
    int*   srow  = rowNxt;
    float* snorm = (float*)colNxt;
    csr_build_k<<<NB, 1024, (size_t)16 * n, stream>>>(
        rowCur, colCur, gcntL + i * NB, dis, off, srow, snorm, n);
    if (i == 0) {
      agg7_k<<<N / 32, 256, 0, stream>>>(x_in, srow, snorm, off, dis, aggx, N);
      // fused: (aggx@Wc1+bc) @ Wf + bf, relu, bnstat
      conv_fc0_k<<<N / 64, 256, 0, stream>>>(aggx, Wc1, bc, Wf, bf, A, N, statL);
    } else {
      const float* W = Wc + (size_t)(i - 1) * HB * HB;
      // conv gemm, loader fuses SAG gather + prev layer's BN affine: -> Cc (hw)
      gemm128_k<<<N / 64, 256, 0, stream>>>(A, W, nullptr, Cc, N, 4,
                                            sel, scale, bnsc, nullptr);
      gather_combine_k<<<N / 8, 256, 0, stream>>>(Cc, srow, snorm, off, dis,
                                                  bc + (size_t)i * HB, Bb, N);
      // fc + relu + fused sharded bnstat (pre-BN output kept in A)
      gemm128_k<<<N / 64, 256, 0, stream>>>(
          Bb, Wf + (size_t)i * HB * HB, bf + (size_t)i * HB, A, N, 1 | 2 | 8,
          nullptr, nullptr, nullptr, statL);
    }
    bnfin_k<<<1, 128, 0, stream>>>(statL, bng + (size_t)i * HB, bnb + (size_t)i * HB, bnsc, N);
    score_prep_k<<<N / 4, 256, 0, stream>>>(
        A, bnsc, Ws1 + (size_t)i * HB, Ws2 + (size_t)i * HB, selfs, t2v, N);
    score_k<<<(N + 255) / 256, 256, 0, stream>>>(selfs, t2v, srow, off, bs + i, score, N);
    int bpg = n / 256;
    rank_topk_k<<<NB * bpg, 256, (size_t)n * 4, stream>>>(
        score, inv, sel, scale, n, khalf, bpg);
    if (i < 3) {
      cmpA_k<<<EG, 256, 0, stream>>>(rowCur, colCur, inv, ecntCur, bcnt);
      cmpB_k<<<1, 1024, 0, stream>>>(bcnt, bbase, ecntNxt);
      cmpC_k<<<EG, 256, 0, stream>>>(rowCur, colCur, inv, ecntCur, bbase,
                                     rowNxt, colNxt, gcntL + (i + 1) * NB, khalf);
      int* t;
      t = rowCur; rowCur = rowNxt; rowNxt = t;
      t = colCur; colCur = colNxt; colNxt = t;
      t = ecntCur; ecntCur = ecntNxt; ecntNxt = t;
    } else {
      gather_x_k<<<(NB * khalf) / 8, 256, 0, stream>>>(
          A, bnsc, sel, scale, Cc, NB * khalf);
    }
    n = khalf;
  }
  pool_k<<<NB, 128, 0, stream>>>(Cc, (float*)d_out, n);
}